// Round 1
// baseline (5327.654 us; speedup 1.0000x reference)
//
#include <hip/hip_runtime.h>
#include <math.h>

#define TT 8192
#define DZ 32

// ---------------- workspace layout (floats) ----------------
#define OFF_QINV   0
#define OFF_Q0INV  1024
#define OFF_AQA    2048
#define OFF_B      3072
#define OFF_P0     4096
#define OFF_PMID   5120
#define OFF_PLAST  6144
#define OFF_LOGSUM 7168
#define OFF_CONST_END 8192
#define SZ_BIG (TT*1024)
#define OFF_HA   (OFF_CONST_END)            // later reused as L
#define OFF_HB   (OFF_HA + SZ_BIG)          // later reused as C
#define OFF_COV  (OFF_HB + SZ_BIG)          // cov -> AA in place
#define OFF_MEAN (OFF_COV + SZ_BIG)
#define OFF_LAMMU (OFF_MEAN + TT*DZ)
#define OFF_IB    (OFF_LAMMU + TT*DZ)

// ---------------- setup: Qinv, Q0inv, AQA, B, priors ----------------
__global__ __launch_bounds__(1024)
void setup_kernel(const float* __restrict__ A, const float* __restrict__ QinvChol,
                  const float* __restrict__ Q0invChol, float* __restrict__ cw)
{
    __shared__ float As[DZ*33], Qc[DZ*33], Q0c[DZ*33], Qi[DZ*33], T1[DZ*33];
    const int tid = threadIdx.x;
    const int i = tid >> 5, j = tid & 31;
    As[i*33+j]  = A[tid];
    Qc[i*33+j]  = QinvChol[tid];
    Q0c[i*33+j] = Q0invChol[tid];
    __syncthreads();
    float qi = 0.f, q0 = 0.f;
    for (int k = 0; k < DZ; ++k) { qi += Qc[i*33+k]*Qc[j*33+k]; q0 += Q0c[i*33+k]*Q0c[j*33+k]; }
    Qi[i*33+j] = qi;
    __syncthreads();
    float t1 = 0.f;                       // (Qinv*A)[i][j]
    for (int k = 0; k < DZ; ++k) t1 += Qi[i*33+k]*As[k*33+j];
    T1[i*33+j] = t1;
    __syncthreads();
    float aqa = 0.f, bm = 0.f;
    for (int k = 0; k < DZ; ++k) { aqa += As[k*33+i]*T1[k*33+j]; bm += As[k*33+i]*Qi[k*33+j]; }
    cw[OFF_QINV  + tid] = qi;
    cw[OFF_Q0INV + tid] = q0;
    cw[OFF_AQA   + tid] = aqa;
    cw[OFF_B     + tid] = -bm;            // BB block = -(A^T Qinv)
    cw[OFF_P0    + tid] = q0 + aqa;
    cw[OFF_PMID  + tid] = qi + aqa;
    cw[OFF_PLAST + tid] = qi;
    if (tid == 0) cw[OFF_LOGSUM] = 0.f;   // zero every launch (graph-replay safe)
}

// ---------------- f32 GEMM: C[M,N] = act(A[M,K] @ W[N,K]^T + bias) ----------------
template<int BN, int TN>
__global__ __launch_bounds__(256)
void gemm_kernel(const float* __restrict__ A, const float* __restrict__ Wt,
                 const float* __restrict__ bias, float* __restrict__ Cout,
                 int M, int N, int Kd, int doRelu)
{
    constexpr int BM = 128, BK = 16, TM = 8;
    constexpr int AP = BM + 4, WP = BN + 4;
    __shared__ float As[BK * AP];
    __shared__ float Ws[BK * WP];
    const int tid = threadIdx.x;
    const int bn = blockIdx.x, bm = blockIdx.y;
    const int lm = tid >> 2;              // 0..63
    const int lk = (tid & 3) << 2;        // 0,4,8,12
    const int tn = tid & 15;
    const int tm = tid >> 4;              // 0..15 -> rows tm*8
    const int cA = tn * (TN/2);
    const int cB = BN/2 + tn * (TN/2);

    float acc[TM][TN];
    #pragma unroll
    for (int i = 0; i < TM; ++i)
        #pragma unroll
        for (int j = 0; j < TN; ++j) acc[i][j] = 0.f;

    const float* Ar0 = A + (size_t)(bm*BM + lm) * Kd;
    const float* Ar1 = A + (size_t)(bm*BM + lm + 64) * Kd;

    for (int k0 = 0; k0 < Kd; k0 += BK) {
        float4 a0 = *(const float4*)(Ar0 + k0 + lk);
        float4 a1 = *(const float4*)(Ar1 + k0 + lk);
        float4 w0, w1;
        if (BN == 128) {
            w0 = *(const float4*)(Wt + (size_t)(bn*BN + lm) * Kd + k0 + lk);
            w1 = *(const float4*)(Wt + (size_t)(bn*BN + lm + 64) * Kd + k0 + lk);
        } else {
            if (tid < 128) {
                int n = tid >> 2;
                w0 = *(const float4*)(Wt + (size_t)(bn*BN + n) * Kd + k0 + lk);
            }
        }
        __syncthreads();
        As[(lk+0)*AP + lm] = a0.x; As[(lk+1)*AP + lm] = a0.y;
        As[(lk+2)*AP + lm] = a0.z; As[(lk+3)*AP + lm] = a0.w;
        As[(lk+0)*AP + lm+64] = a1.x; As[(lk+1)*AP + lm+64] = a1.y;
        As[(lk+2)*AP + lm+64] = a1.z; As[(lk+3)*AP + lm+64] = a1.w;
        if (BN == 128) {
            Ws[(lk+0)*WP + lm] = w0.x; Ws[(lk+1)*WP + lm] = w0.y;
            Ws[(lk+2)*WP + lm] = w0.z; Ws[(lk+3)*WP + lm] = w0.w;
            Ws[(lk+0)*WP + lm+64] = w1.x; Ws[(lk+1)*WP + lm+64] = w1.y;
            Ws[(lk+2)*WP + lm+64] = w1.z; Ws[(lk+3)*WP + lm+64] = w1.w;
        } else if (tid < 128) {
            int n = tid >> 2;
            Ws[(lk+0)*WP + n] = w0.x; Ws[(lk+1)*WP + n] = w0.y;
            Ws[(lk+2)*WP + n] = w0.z; Ws[(lk+3)*WP + n] = w0.w;
        }
        __syncthreads();
        #pragma unroll
        for (int kk = 0; kk < BK; ++kk) {
            float ar[TM], brA[TN/2], brB[TN/2];
            #pragma unroll
            for (int i = 0; i < TM; ++i) ar[i] = As[kk*AP + tm*TM + i];
            #pragma unroll
            for (int j = 0; j < TN/2; ++j) { brA[j] = Ws[kk*WP + cA + j]; brB[j] = Ws[kk*WP + cB + j]; }
            #pragma unroll
            for (int i = 0; i < TM; ++i)
                #pragma unroll
                for (int j = 0; j < TN/2; ++j) {
                    acc[i][j]        += ar[i] * brA[j];
                    acc[i][j+TN/2]   += ar[i] * brB[j];
                }
        }
    }
    #pragma unroll
    for (int i = 0; i < TM; ++i) {
        const int row = bm*BM + tm*TM + i;
        #pragma unroll
        for (int j = 0; j < TN/2; ++j) {
            float v = acc[i][j] + bias[bn*BN + cA + j];
            if (doRelu) v = fmaxf(v, 0.f);
            Cout[(size_t)row * N + bn*BN + cA + j] = v;
        }
        #pragma unroll
        for (int j = 0; j < TN/2; ++j) {
            float v = acc[i][j+TN/2] + bias[bn*BN + cB + j];
            if (doRelu) v = fmaxf(v, 0.f);
            Cout[(size_t)row * N + bn*BN + cB + j] = v;
        }
    }
}

// ---------------- build Lam, AA (in place over cov), lamMu ----------------
__global__ __launch_bounds__(256)
void build_blocks_kernel(float* __restrict__ cov, const float* __restrict__ mean,
                         float* __restrict__ lamMu, const float* __restrict__ cw)
{
    const int t = blockIdx.x, tid = threadIdx.x;
    __shared__ float R[DZ*33];
    __shared__ float Lam[DZ*33];
    __shared__ float mn[DZ];
    float* blk = cov + (size_t)t * 1024;
    {
        float4 v = ((const float4*)blk)[tid];
        const int base = tid * 4;
        const int row = base >> 5, col = base & 31;
        R[row*33 + col + 0] = v.x; R[row*33 + col + 1] = v.y;
        R[row*33 + col + 2] = v.z; R[row*33 + col + 3] = v.w;
    }
    if (tid < DZ) mn[tid] = mean[t*DZ + tid];
    __syncthreads();
    const float* P = cw + (t == 0 ? OFF_P0 : (t == TT-1 ? OFF_PLAST : OFF_PMID));
    #pragma unroll
    for (int q = 0; q < 4; ++q) {
        const int idx = tid + 256*q;
        const int i = idx >> 5, j = idx & 31;
        float s = 0.f;
        #pragma unroll
        for (int k = 0; k < DZ; ++k) s += R[i*33+k] * R[j*33+k];
        Lam[i*33+j] = s;
        blk[idx] = s + P[idx];            // AA block (in place)
    }
    __syncthreads();
    if (tid < DZ) {
        float s = 0.f;
        #pragma unroll
        for (int k = 0; k < DZ; ++k) s += Lam[tid*33+k] * mn[k];
        lamMu[t*DZ + tid] = s;
    }
}

// ---------------- chunked block-tridiagonal Cholesky scan ----------------
// One wave per chunk. Warm-up exploits exponential forgetting of the
// Riccati recursion S_t = AA_t - B^T S_{t-1}^{-1} B.
// Lane layout: c = lane&31 (column), h = lane>>5 (row half, rows 16h..16h+15).
__global__ __launch_bounds__(64)
void chol_scan_kernel(const float* __restrict__ AA, float* __restrict__ Lg,
                      float* __restrict__ Cg, const float* __restrict__ cw,
                      float* __restrict__ logsum, int K, int W)
{
    const int lane = threadIdx.x;
    const int c = lane & 31, h = lane >> 5;
    const int rbase = 16 * h;
    const int own0 = blockIdx.x * K;
    const int own1 = min(TT, own0 + K);
    const int t0 = max(0, own0 - W);

    __shared__ float Lp[DZ][DZ];      // previous L, column-major: Lp[col][row]
    __shared__ float invd[DZ];        // 1/diag(Lprev)
    __shared__ float xrow[2][DZ];     // row broadcast buffer (parity)
    __shared__ float Bs[DZ][DZ];      // B row-major

    for (int idx = lane; idx < DZ*DZ; idx += 64) Bs[idx>>5][idx&31] = cw[OFF_B + idx];
    __syncthreads();

    float logacc = 0.f;
    float Apre[16];
    {
        const float* aat = AA + (size_t)t0 * 1024;
        #pragma unroll
        for (int i = 0; i < 16; ++i) Apre[i] = aat[(rbase+i)*DZ + c];
    }

    for (int t = t0; t < own1; ++t) {
        float Sacc[16];
        #pragma unroll
        for (int i = 0; i < 16; ++i) Sacc[i] = Apre[i];
        if (t + 1 < own1) {           // prefetch next AA block
            const float* aat = AA + (size_t)(t+1) * 1024;
            #pragma unroll
            for (int i = 0; i < 16; ++i) Apre[i] = aat[(rbase+i)*DZ + c];
        }

        float xkeep[16];              // X[r][c] for r in my half == C_t[c][16h..]
        if (t > t0) {
            // Phase A: X = Lprev^{-1} B (forward subst), fused S -= X^T X.
            // Unpredicated updates only touch provably-dead slots (bounded garbage).
            float acc[16];
            #pragma unroll
            for (int i = 0; i < 16; ++i) acc[i] = Bs[rbase+i][c];
            #pragma unroll
            for (int r = 0; r < DZ; ++r) {
                const int hr = r >> 4, ir = r & 15;
                float x = acc[ir] * invd[r];
                float xo = __shfl_xor(x, 32);
                float xc = (h == hr) ? x : xo;       // X[r][c] in every lane
                if (h == hr) { xrow[r & 1][c] = xc; xkeep[ir] = xc; }
                __syncthreads();
                float xa[16];
                #pragma unroll
                for (int i = 0; i < 16; ++i) xa[i] = xrow[r & 1][rbase + i];
                #pragma unroll
                for (int i = 0; i < 16; ++i) acc[i]  -= Lp[r][rbase+i] * xc;
                #pragma unroll
                for (int i = 0; i < 16; ++i) Sacc[i] -= xa[i] * xc;
            }
        }

        // Phase B: Cholesky of S (column j sweep); writes new Lp in place.
        float Lcolkeep[16];
        #pragma unroll
        for (int j = 0; j < DZ; ++j) {
            const int hd = j >> 4, jr = j & 15;
            float sj  = Sacc[jr];
            float sjo = __shfl_xor(sj, 32);
            float sjj = (h == hd) ? sj : sjo;        // valid where c==j
            float dj  = sqrtf(sjj);
            float inv = 1.0f / dj;
            if (c == j) {
                #pragma unroll
                for (int i = 0; i < 16; ++i) {
                    float lv = Sacc[i] * inv;
                    Lcolkeep[i] = lv;
                    Lp[j][rbase + i] = lv;           // diag row lands as dj automatically
                }
                if (h == hd) {
                    invd[j] = inv;
                    if (t >= own0) logacc += __logf(dj);
                }
            }
            __syncthreads();
            float lja[16];
            #pragma unroll
            for (int i = 0; i < 16; ++i) lja[i] = Lp[j][rbase + i];
            const float ljc = Lp[j][c];
            #pragma unroll
            for (int i = 0; i < 16; ++i) Sacc[i] -= lja[i] * ljc;
            __syncthreads();
        }

        if (t >= own0) {
            float* lt = Lg + (size_t)t * 1024;       // row-major (upper junk, never read)
            #pragma unroll
            for (int i = 0; i < 16; ++i) lt[(rbase+i)*DZ + c] = Lcolkeep[i];
            if (t > t0) {
                float* ct = Cg + (size_t)t * 1024;   // row-major C_t = X^T
                #pragma unroll
                for (int i = 0; i < 16; i += 4) {
                    float4 v = make_float4(xkeep[i], xkeep[i+1], xkeep[i+2], xkeep[i+3]);
                    *(float4*)(ct + c*DZ + rbase + i) = v;
                }
            }
        }
    }

    #pragma unroll
    for (int s = 32; s > 0; s >>= 1) logacc += __shfl_xor(logacc, s);
    if (lane == 0) atomicAdd(logsum, logacc);
}

// ---------------- chunked forward bidiagonal solve: x_t = L_t^{-1}(b_t - C_t x_{t-1}) ----------------
__global__ __launch_bounds__(64)
void fwd_solve_kernel(const float* __restrict__ Lg, const float* __restrict__ Cg,
                      const float* __restrict__ bv, float* __restrict__ xout,
                      int K, int W)
{
    const int lane = threadIdx.x;
    const int r = lane & 31, h = lane >> 5;
    const int own0 = blockIdx.x * K;
    const int own1 = min(TT, own0 + K);
    const int t0 = max(0, own0 - W);
    float xprev = 0.f;
    for (int t = t0; t < own1; ++t) {
        const float* lt = Lg + (size_t)t * 1024;
        float Lr[32];
        #pragma unroll
        for (int q = 0; q < 8; ++q) {
            float4 v = *(const float4*)(lt + r*DZ + q*4);
            Lr[4*q] = v.x; Lr[4*q+1] = v.y; Lr[4*q+2] = v.z; Lr[4*q+3] = v.w;
        }
        const float inv = 1.0f / lt[33*r];
        float v = bv[t*DZ + r];
        if (t > t0) {
            const float* ct = Cg + (size_t)t * 1024;
            float Cr[32];
            #pragma unroll
            for (int q = 0; q < 8; ++q) {
                float4 w = *(const float4*)(ct + r*DZ + q*4);
                Cr[4*q] = w.x; Cr[4*q+1] = w.y; Cr[4*q+2] = w.z; Cr[4*q+3] = w.w;
            }
            #pragma unroll
            for (int cc = 0; cc < DZ; ++cc) v -= Cr[cc] * __shfl(xprev, cc);
        }
        float xv = 0.f;
        #pragma unroll
        for (int rr = 0; rr < DZ; ++rr) {
            float cand = v * inv;
            float xb = __shfl(cand, rr);
            if (r == rr) xv = cand;
            if (r > rr) v -= Lr[rr] * xb;
        }
        xprev = xv;
        if (t >= own0 && h == 0) xout[t*DZ + r] = xv;
    }
}

// ---------------- chunked backward solve (two RHS) + sample output ----------------
// x_t = L_t^{-T}(b_t - C_{t+1}^T x_{t+1});  sample = x(ib) + x(norm)
__global__ __launch_bounds__(64)
void bwd_solve_kernel(const float* __restrict__ Lg, const float* __restrict__ Cg,
                      const float* __restrict__ b1, const float* __restrict__ b2,
                      float* __restrict__ outSample, int K, int W)
{
    const int lane = threadIdx.x;
    const int k = lane & 31, h = lane >> 5;
    const int own0 = blockIdx.x * K;
    const int own1 = min(TT, own0 + K);
    const int tS = min(TT - 1, own1 - 1 + W);
    float x1p = 0.f, x2p = 0.f;
    for (int t = tS; t >= own0; --t) {
        const float* lt = Lg + (size_t)t * 1024;
        float Lc[32];
        #pragma unroll
        for (int j = 0; j < DZ; ++j) Lc[j] = lt[j*DZ + k];   // column k (coalesced)
        const float inv = 1.0f / lt[33*k];
        float v1 = b1[t*DZ + k], v2 = b2[t*DZ + k];
        if (t < tS) {
            const float* ct = Cg + (size_t)(t+1) * 1024;
            float Cc[32];
            #pragma unroll
            for (int j = 0; j < DZ; ++j) Cc[j] = ct[j*DZ + k];
            #pragma unroll
            for (int cc = 0; cc < DZ; ++cc) {
                float a1 = __shfl(x1p, cc), a2 = __shfl(x2p, cc);
                v1 -= Cc[cc] * a1; v2 -= Cc[cc] * a2;
            }
        }
        float x1 = 0.f, x2 = 0.f;
        #pragma unroll
        for (int rr = DZ-1; rr >= 0; --rr) {
            float c1 = v1 * inv, c2 = v2 * inv;
            float xb1 = __shfl(c1, rr), xb2 = __shfl(c2, rr);
            if (k == rr) { x1 = c1; x2 = c2; }
            if (k < rr) { v1 -= Lc[rr] * xb1; v2 -= Lc[rr] * xb2; }
        }
        x1p = x1; x2p = x2;
        if (t >= own0 && h == 0) outSample[t*DZ + k] = x1 + x2;
    }
}

// ---------------- entropy ----------------
__global__ void finalize_kernel(const float* __restrict__ logsum, float* __restrict__ out)
{
    if (threadIdx.x == 0) {
        // entropy = (sum_log_diag - (DZ*50/2)*(1+ln(2pi))) / (50*T)
        out[TT*DZ] = (logsum[0] - 2270.3016531274763f) / 409600.0f;
    }
}

// ---------------- launch ----------------
extern "C" void kernel_launch(void* const* d_in, const int* in_sizes, int n_in,
                              void* d_out, int out_size, void* d_ws, size_t ws_size,
                              hipStream_t stream)
{
    (void)in_sizes; (void)n_in; (void)out_size; (void)ws_size;
    const float* x        = (const float*)d_in[0];
    const float* norm     = (const float*)d_in[1];
    const float* A        = (const float*)d_in[2];
    const float* QinvChol = (const float*)d_in[3];
    const float* Q0invChol= (const float*)d_in[4];
    const float* Wm_in = (const float*)d_in[5];  const float* bm_in = (const float*)d_in[6];
    const float* Wm_h1 = (const float*)d_in[7];  const float* bm_h1 = (const float*)d_in[8];
    const float* Wm_h3 = (const float*)d_in[9];  const float* bm_h3 = (const float*)d_in[10];
    const float* Wm_out= (const float*)d_in[11]; const float* bm_out= (const float*)d_in[12];
    const float* Wc_in = (const float*)d_in[13]; const float* bc_in = (const float*)d_in[14];
    const float* Wc_h1 = (const float*)d_in[15]; const float* bc_h1 = (const float*)d_in[16];
    const float* Wc_h3 = (const float*)d_in[17]; const float* bc_h3 = (const float*)d_in[18];
    const float* Wc_out= (const float*)d_in[19]; const float* bc_out= (const float*)d_in[20];

    float* ws    = (float*)d_ws;
    float* out   = (float*)d_out;
    float* cw    = ws;
    float* hA    = ws + OFF_HA;     // reused as L
    float* hB    = ws + OFF_HB;     // reused as C
    float* covb  = ws + OFF_COV;    // cov -> AA
    float* meanb = ws + OFF_MEAN;
    float* lamMu = ws + OFF_LAMMU;
    float* ib    = ws + OFF_IB;
    float* logsum = ws + OFF_LOGSUM;

    setup_kernel<<<dim3(1), dim3(1024), 0, stream>>>(A, QinvChol, Q0invChol, cw);

    // mean MLP
    gemm_kernel<128,8><<<dim3(1024/128, TT/128), 256, 0, stream>>>(x,  Wm_in, bm_in, hA, TT, 1024, 256, 1);
    gemm_kernel<128,8><<<dim3(1024/128, TT/128), 256, 0, stream>>>(hA, Wm_h1, bm_h1, hB, TT, 1024, 1024, 1);
    gemm_kernel<128,8><<<dim3(1024/128, TT/128), 256, 0, stream>>>(hB, Wm_h3, bm_h3, hA, TT, 1024, 1024, 1);
    gemm_kernel<32,2> <<<dim3(1,        TT/128), 256, 0, stream>>>(hA, Wm_out, bm_out, meanb, TT, 32, 1024, 0);
    // cov MLP
    gemm_kernel<128,8><<<dim3(1024/128, TT/128), 256, 0, stream>>>(x,  Wc_in, bc_in, hB, TT, 1024, 256, 1);
    gemm_kernel<128,8><<<dim3(1024/128, TT/128), 256, 0, stream>>>(hB, Wc_h1, bc_h1, hA, TT, 1024, 1024, 1);
    gemm_kernel<128,8><<<dim3(1024/128, TT/128), 256, 0, stream>>>(hA, Wc_h3, bc_h3, hB, TT, 1024, 1024, 1);
    gemm_kernel<128,8><<<dim3(1024/128, TT/128), 256, 0, stream>>>(hB, Wc_out, bc_out, covb, TT, 1024, 1024, 0);

    build_blocks_kernel<<<dim3(TT), dim3(256), 0, stream>>>(covb, meanb, lamMu, cw);

    // chunked scan phases (K = chunk len, W = warm-up len)
    chol_scan_kernel<<<dim3(TT/4),  dim3(64), 0, stream>>>(covb, hA, hB, cw, logsum, 4, 64);
    fwd_solve_kernel<<<dim3(TT/16), dim3(64), 0, stream>>>(hA, hB, lamMu, ib, 16, 96);
    bwd_solve_kernel<<<dim3(TT/16), dim3(64), 0, stream>>>(hA, hB, ib, norm, out, 16, 96);

    finalize_kernel<<<dim3(1), dim3(64), 0, stream>>>(logsum, out);
}

// Round 2
// 1569.178 us; speedup vs baseline: 3.3952x; 3.3952x over previous
//
#include <hip/hip_runtime.h>
#include <math.h>

#define TT 8192
#define DZ 32

typedef short bf16x8 __attribute__((ext_vector_type(8)));
typedef float f32x4 __attribute__((ext_vector_type(4)));
#define MFMA16(a,b,c) __builtin_amdgcn_mfma_f32_16x16x32_bf16(a,b,c,0,0,0)

// ---------------- workspace layout (float units) ----------------
#define OFF_QINV   0
#define OFF_Q0INV  1024
#define OFF_AQA    2048
#define OFF_B      3072
#define OFF_P0     4096
#define OFF_PMID   5120
#define OFF_PLAST  6144
#define OFF_LOGSUM 7168
#define OFF_ACT0   8192                     // act slot0 (bf16 hi+lo) -> later L (f32)
#define OFF_ACT1   (OFF_ACT0 + 8388608)     // act slot1 (bf16 hi+lo) -> later C (f32)
#define OFF_AAB    (OFF_ACT1 + 8388608)     // cov f32 -> AA in place
#define OFF_XB     (OFF_AAB + 8388608)      // x hi/lo bf16
#define OFF_WB     (OFF_XB + 2097152)       // weights bf16 hi/lo
#define OFF_MEANB  (OFF_WB + 5799936)
#define OFF_LAMMU  (OFF_MEANB + 262144)
#define OFF_IBV    (OFF_LAMMU + 262144)

__device__ __forceinline__ unsigned short f2bf(float f) {
    unsigned int u = __float_as_uint(f);
    u += 0x7FFFu + ((u >> 16) & 1u);
    return (unsigned short)(u >> 16);
}
__device__ __forceinline__ float bf2f(unsigned short h) {
    return __uint_as_float(((unsigned int)h) << 16);
}

// ---------------- f32 -> (hi,lo) bf16 split ----------------
__global__ __launch_bounds__(256)
void split_kernel(const float* __restrict__ in, unsigned short* __restrict__ hi,
                  unsigned short* __restrict__ lo, int n4)
{
    int i = blockIdx.x * 256 + threadIdx.x;
    if (i >= n4) return;
    float4 v = ((const float4*)in)[i];
    ushort4 h, l;
    h.x = f2bf(v.x); l.x = f2bf(v.x - bf2f(h.x));
    h.y = f2bf(v.y); l.y = f2bf(v.y - bf2f(h.y));
    h.z = f2bf(v.z); l.z = f2bf(v.z - bf2f(h.z));
    h.w = f2bf(v.w); l.w = f2bf(v.w - bf2f(h.w));
    ((ushort4*)hi)[i] = h;
    ((ushort4*)lo)[i] = l;
}

// ---------------- setup: Qinv, Q0inv, AQA, B, priors ----------------
__global__ __launch_bounds__(1024)
void setup_kernel(const float* __restrict__ A, const float* __restrict__ QinvChol,
                  const float* __restrict__ Q0invChol, float* __restrict__ cw)
{
    __shared__ float As[DZ*33], Qc[DZ*33], Q0c[DZ*33], Qi[DZ*33], T1[DZ*33];
    const int tid = threadIdx.x;
    const int i = tid >> 5, j = tid & 31;
    As[i*33+j]  = A[tid];
    Qc[i*33+j]  = QinvChol[tid];
    Q0c[i*33+j] = Q0invChol[tid];
    __syncthreads();
    float qi = 0.f, q0 = 0.f;
    for (int k = 0; k < DZ; ++k) { qi += Qc[i*33+k]*Qc[j*33+k]; q0 += Q0c[i*33+k]*Q0c[j*33+k]; }
    Qi[i*33+j] = qi;
    __syncthreads();
    float t1 = 0.f;
    for (int k = 0; k < DZ; ++k) t1 += Qi[i*33+k]*As[k*33+j];
    T1[i*33+j] = t1;
    __syncthreads();
    float aqa = 0.f, bm = 0.f;
    for (int k = 0; k < DZ; ++k) { aqa += As[k*33+i]*T1[k*33+j]; bm += As[k*33+i]*Qi[k*33+j]; }
    cw[OFF_QINV  + tid] = qi;
    cw[OFF_Q0INV + tid] = q0;
    cw[OFF_AQA   + tid] = aqa;
    cw[OFF_B     + tid] = -bm;
    cw[OFF_P0    + tid] = q0 + aqa;
    cw[OFF_PMID  + tid] = qi + aqa;
    cw[OFF_PLAST + tid] = qi;
    if (tid == 0) cw[OFF_LOGSUM] = 0.f;
}

// ---------------- split-bf16 MFMA GEMM ----------------
// C[M,N] = act(A @ W^T + bias), A as (Ah,Al), W as (Wh,Wl) row-major bf16 [.,Kd].
// a*w ~= ah*wh + ah*wl + al*wh  (3 MFMAs -> ~f32 accuracy)
// 128x128 tile, BK=32, 4 waves (2x2 of 64x64). LDS slot-swizzle: slot = g ^ ((row>>1)&3).
__device__ __forceinline__ void stage_tile(const unsigned short* src, int rowbase, int Kd,
                                           int k0, unsigned short* ldsbase, int w, int lane)
{
#pragma unroll
    for (int inst = 0; inst < 2; ++inst) {
        const int r0  = w * 32 + inst * 16;
        const int row = r0 + (lane >> 2);
        const int g   = (lane & 3) ^ ((row >> 1) & 3);
        const unsigned short* gp = src + (size_t)(rowbase + row) * Kd + k0 + g * 8;
        __builtin_amdgcn_global_load_lds(
            (const __attribute__((address_space(1))) void*)gp,
            (__attribute__((address_space(3))) void*)(ldsbase + r0 * 32),
            16, 0, 0);
    }
}

template<int OM>   // 0: f32 out, 1: (hi,lo) bf16 out
__global__ __launch_bounds__(256)
void mgemm(const unsigned short* __restrict__ Ah, const unsigned short* __restrict__ Al,
           const unsigned short* __restrict__ Wh, const unsigned short* __restrict__ Wl,
           const float* __restrict__ bias, float* __restrict__ outF,
           unsigned short* __restrict__ outH, unsigned short* __restrict__ outL,
           int N, int Kd, int relu)
{
    __shared__ unsigned short lds[2][4][4096];   // [buf][Ah,Al,Wh,Wl][128*32]
    const int tid = threadIdx.x;
    const int lane = tid & 63, w = tid >> 6;
    const int wm = w >> 1, wn = w & 1;
    const int bn = blockIdx.x, bm = blockIdx.y;
    const int ln15 = lane & 15, g4 = lane >> 4;

    f32x4 acc[4][4];
#pragma unroll
    for (int i = 0; i < 4; ++i)
#pragma unroll
        for (int j = 0; j < 4; ++j) acc[i][j] = f32x4{0.f,0.f,0.f,0.f};

    const int nt = Kd >> 5;
    // prologue stage
    stage_tile(Ah, bm*128, Kd, 0, &lds[0][0][0], w, lane);
    stage_tile(Al, bm*128, Kd, 0, &lds[0][1][0], w, lane);
    stage_tile(Wh, bn*128, Kd, 0, &lds[0][2][0], w, lane);
    stage_tile(Wl, bn*128, Kd, 0, &lds[0][3][0], w, lane);
    __syncthreads();

    int cur = 0;
    for (int t = 0; t < nt; ++t) {
        if (t + 1 < nt) {
            const int k0 = (t + 1) << 5;
            stage_tile(Ah, bm*128, Kd, k0, &lds[cur^1][0][0], w, lane);
            stage_tile(Al, bm*128, Kd, k0, &lds[cur^1][1][0], w, lane);
            stage_tile(Wh, bn*128, Kd, k0, &lds[cur^1][2][0], w, lane);
            stage_tile(Wl, bn*128, Kd, k0, &lds[cur^1][3][0], w, lane);
        }
        bf16x8 fa[4], fal[4], fwh[4], fwl[4];
#pragma unroll
        for (int fm = 0; fm < 4; ++fm) {
            const int lr = wm*64 + fm*16 + ln15;
            const int off = lr*32 + ((g4 ^ ((lr >> 1) & 3)) << 3);
            fa[fm]  = *(const bf16x8*)(&lds[cur][0][0] + off);
            fal[fm] = *(const bf16x8*)(&lds[cur][1][0] + off);
        }
#pragma unroll
        for (int fn = 0; fn < 4; ++fn) {
            const int lr = wn*64 + fn*16 + ln15;
            const int off = lr*32 + ((g4 ^ ((lr >> 1) & 3)) << 3);
            fwh[fn] = *(const bf16x8*)(&lds[cur][2][0] + off);
            fwl[fn] = *(const bf16x8*)(&lds[cur][3][0] + off);
        }
#pragma unroll
        for (int fm = 0; fm < 4; ++fm)
#pragma unroll
            for (int fn = 0; fn < 4; ++fn) {
                acc[fm][fn] = MFMA16(fa[fm],  fwh[fn], acc[fm][fn]);
                acc[fm][fn] = MFMA16(fa[fm],  fwl[fn], acc[fm][fn]);
                acc[fm][fn] = MFMA16(fal[fm], fwh[fn], acc[fm][fn]);
            }
        __syncthreads();
        cur ^= 1;
    }

    // epilogue: C/D layout col=lane&15, row=(lane>>4)*4+q  [m89-verified]
#pragma unroll
    for (int fm = 0; fm < 4; ++fm)
#pragma unroll
        for (int fn = 0; fn < 4; ++fn) {
            const int col = bn*128 + wn*64 + fn*16 + ln15;
            const float bv = bias[col];
#pragma unroll
            for (int q = 0; q < 4; ++q) {
                const int row = bm*128 + wm*64 + fm*16 + g4*4 + q;
                float v = acc[fm][fn][q] + bv;
                if (relu) v = fmaxf(v, 0.f);
                if (OM == 0) {
                    outF[(size_t)row * N + col] = v;
                } else {
                    unsigned short hv = f2bf(v);
                    outH[(size_t)row * N + col] = hv;
                    outL[(size_t)row * N + col] = f2bf(v - bf2f(hv));
                }
            }
        }
}

// ---------------- small GEMM (N=32): mean = h3 @ Wm_out^T + b ----------------
__global__ __launch_bounds__(64)
void mgemm_small(const unsigned short* __restrict__ Ah, const unsigned short* __restrict__ Al,
                 const unsigned short* __restrict__ Wh, const unsigned short* __restrict__ Wl,
                 const float* __restrict__ bias, float* __restrict__ out, int Kd)
{
    const int lane = threadIdx.x;
    const int rm = blockIdx.x * 16;
    const int ln15 = lane & 15, g = lane >> 4;
    const int row = rm + ln15;
    f32x4 acc0 = {0.f,0.f,0.f,0.f}, acc1 = {0.f,0.f,0.f,0.f};
    for (int k0 = 0; k0 < Kd; k0 += 32) {
        const int k = k0 + g*8;
        bf16x8 a_h = *(const bf16x8*)(Ah + (size_t)row*Kd + k);
        bf16x8 a_l = *(const bf16x8*)(Al + (size_t)row*Kd + k);
        bf16x8 w0h = *(const bf16x8*)(Wh + (size_t)ln15*Kd + k);
        bf16x8 w0l = *(const bf16x8*)(Wl + (size_t)ln15*Kd + k);
        bf16x8 w1h = *(const bf16x8*)(Wh + (size_t)(16+ln15)*Kd + k);
        bf16x8 w1l = *(const bf16x8*)(Wl + (size_t)(16+ln15)*Kd + k);
        acc0 = MFMA16(a_h, w0h, acc0); acc0 = MFMA16(a_h, w0l, acc0); acc0 = MFMA16(a_l, w0h, acc0);
        acc1 = MFMA16(a_h, w1h, acc1); acc1 = MFMA16(a_h, w1l, acc1); acc1 = MFMA16(a_l, w1h, acc1);
    }
#pragma unroll
    for (int q = 0; q < 4; ++q) {
        const int r = rm + g*4 + q;
        out[r*DZ + ln15]      = acc0[q] + bias[ln15];
        out[r*DZ + 16 + ln15] = acc1[q] + bias[16 + ln15];
    }
}

// ---------------- build Lam, AA (in place over cov), lamMu ----------------
__global__ __launch_bounds__(256)
void build_blocks_kernel(float* __restrict__ cov, const float* __restrict__ mean,
                         float* __restrict__ lamMu, const float* __restrict__ cw)
{
    const int t = blockIdx.x, tid = threadIdx.x;
    __shared__ float R[DZ*33];
    __shared__ float Lam[DZ*33];
    __shared__ float mn[DZ];
    float* blk = cov + (size_t)t * 1024;
    {
        float4 v = ((const float4*)blk)[tid];
        const int base = tid * 4;
        const int row = base >> 5, col = base & 31;
        R[row*33 + col + 0] = v.x; R[row*33 + col + 1] = v.y;
        R[row*33 + col + 2] = v.z; R[row*33 + col + 3] = v.w;
    }
    if (tid < DZ) mn[tid] = mean[t*DZ + tid];
    __syncthreads();
    const float* P = cw + (t == 0 ? OFF_P0 : (t == TT-1 ? OFF_PLAST : OFF_PMID));
#pragma unroll
    for (int q = 0; q < 4; ++q) {
        const int idx = tid + 256*q;
        const int i = idx >> 5, j = idx & 31;
        float s = 0.f;
#pragma unroll
        for (int k = 0; k < DZ; ++k) s += R[i*33+k] * R[j*33+k];
        Lam[i*33+j] = s;
        blk[idx] = s + P[idx];
    }
    __syncthreads();
    if (tid < DZ) {
        float s = 0.f;
#pragma unroll
        for (int k = 0; k < DZ; ++k) s += Lam[tid*33+k] * mn[k];
        lamMu[t*DZ + tid] = s;
    }
}

// ---------------- chunked block-tridiagonal Cholesky (LDS-X, spill-free) ----------------
#define UPD16(arr, base, coef) { \
    float4 u0 = *(const float4*)((base));      \
    float4 u1 = *(const float4*)((base)+4);    \
    float4 u2 = *(const float4*)((base)+8);    \
    float4 u3 = *(const float4*)((base)+12);   \
    arr[0]-=u0.x*(coef);  arr[1]-=u0.y*(coef);  arr[2]-=u0.z*(coef);  arr[3]-=u0.w*(coef);  \
    arr[4]-=u1.x*(coef);  arr[5]-=u1.y*(coef);  arr[6]-=u1.z*(coef);  arr[7]-=u1.w*(coef);  \
    arr[8]-=u2.x*(coef);  arr[9]-=u2.y*(coef);  arr[10]-=u2.z*(coef); arr[11]-=u2.w*(coef); \
    arr[12]-=u3.x*(coef); arr[13]-=u3.y*(coef); arr[14]-=u3.z*(coef); arr[15]-=u3.w*(coef); }

__global__ __launch_bounds__(64)
void chol_scan2(const float* __restrict__ AA, float* __restrict__ Lg,
                float* __restrict__ Cg, const float* __restrict__ cw,
                float* __restrict__ logsum, int K, int W)
{
    const int lane = threadIdx.x;
    const int c = lane & 31, h = lane >> 5;
    const int rbase = 16 * h;
    const int own0 = blockIdx.x * K;
    const int own1 = min(TT, own0 + K);
    const int t0 = max(0, own0 - W);

    __shared__ float Lp[DZ][36];    // Lp[col][row], rows<col zeroed; pad 36 keeps 16B align
    __shared__ float invd_s[DZ];
    __shared__ float Xs[DZ][36];    // Xs[r][c]
    __shared__ float Bs[DZ][DZ];

    for (int idx = lane; idx < DZ*DZ; idx += 64) Bs[idx>>5][idx&31] = cw[OFF_B + idx];
    __syncthreads();

    float logacc = 0.f;

    for (int t = t0; t < own1; ++t) {
        const float* aat = AA + (size_t)t * 1024;
        float Sacc[16];
#pragma unroll
        for (int i = 0; i < 16; ++i) Sacc[i] = aat[(rbase+i)*DZ + c];

        if (t > t0) {
            // Phase A: X = Lprev^{-1} B  (forward substitution, no barriers needed)
            float acc[16];
#pragma unroll
            for (int i = 0; i < 16; ++i) acc[i] = Bs[rbase+i][c];
#pragma unroll
            for (int hh = 0; hh < 2; ++hh) {
#pragma unroll
                for (int ir = 0; ir < 16; ++ir) {
                    const int r = hh*16 + ir;
                    float x = acc[ir] * invd_s[r];
                    float xo = __shfl_xor(x, 32);
                    float xc = (h == hh) ? x : xo;
                    if (h == hh) Xs[r][c] = xc;
                    const float* lcol = &Lp[r][rbase];   // upper zeros make this safe
                    UPD16(acc, lcol, xc);
                }
            }
            __syncthreads();
            // S -= X^T X
#pragma unroll 4
            for (int r = 0; r < DZ; ++r) {
                const float xc2 = Xs[r][c];
                const float* xrow = &Xs[r][rbase];
                UPD16(Sacc, xrow, xc2);
            }
        }

        // Phase B: Cholesky of S -> Lp (zeros above diag), invd_s
        float Lcolkeep[16];
#pragma unroll
        for (int hd = 0; hd < 2; ++hd) {
#pragma unroll
            for (int jr = 0; jr < 16; ++jr) {
                const int j = hd*16 + jr;
                float sj = Sacc[jr];
                float sjo = __shfl_xor(sj, 32);
                float sjj = (h == hd) ? sj : sjo;     // valid in lanes c==j
                float dj = sqrtf(sjj);
                float inv = 1.0f / dj;
                if (c == j) {
#pragma unroll
                    for (int i = 0; i < 16; ++i) {
                        float lv = (rbase + i >= j) ? Sacc[i] * inv : 0.f;
                        Lcolkeep[i] = lv;
                        Lp[j][rbase + i] = lv;
                    }
                    if (h == hd) {
                        invd_s[j] = inv;
                        if (t >= own0) logacc += __logf(dj);
                    }
                }
                __syncthreads();
                const float ljc = Lp[j][c];
                const float* lcol = &Lp[j][rbase];
                UPD16(Sacc, lcol, ljc);
            }
        }

        if (t >= own0) {
            float* lt = Lg + (size_t)t * 1024;
#pragma unroll
            for (int i = 0; i < 16; ++i) lt[(rbase+i)*DZ + c] = Lcolkeep[i];
            if (t > t0) {
                float* ct = Cg + (size_t)t * 1024;
#pragma unroll
                for (int i = 0; i < 16; ++i) ct[(rbase+i)*DZ + c] = Xs[c][rbase+i];
            }
        }
        __syncthreads();   // Lp/invd_s/Xs handoff to next iteration
    }

#pragma unroll
    for (int s = 32; s > 0; s >>= 1) logacc += __shfl_xor(logacc, s);
    if (lane == 0) atomicAdd(logsum, logacc);
}

// ---------------- chunked forward bidiagonal solve ----------------
__global__ __launch_bounds__(64)
void fwd_solve_kernel(const float* __restrict__ Lg, const float* __restrict__ Cg,
                      const float* __restrict__ bv, float* __restrict__ xout,
                      int K, int W)
{
    const int lane = threadIdx.x;
    const int r = lane & 31, h = lane >> 5;
    const int own0 = blockIdx.x * K;
    const int own1 = min(TT, own0 + K);
    const int t0 = max(0, own0 - W);
    float xprev = 0.f;
    for (int t = t0; t < own1; ++t) {
        const float* lt = Lg + (size_t)t * 1024;
        float Lr[32];
#pragma unroll
        for (int q = 0; q < 8; ++q) {
            float4 v = *(const float4*)(lt + r*DZ + q*4);
            Lr[4*q] = v.x; Lr[4*q+1] = v.y; Lr[4*q+2] = v.z; Lr[4*q+3] = v.w;
        }
        const float inv = 1.0f / lt[33*r];
        float v = bv[t*DZ + r];
        if (t > t0) {
            const float* ct = Cg + (size_t)t * 1024;
            float Cr[32];
#pragma unroll
            for (int q = 0; q < 8; ++q) {
                float4 w2 = *(const float4*)(ct + r*DZ + q*4);
                Cr[4*q] = w2.x; Cr[4*q+1] = w2.y; Cr[4*q+2] = w2.z; Cr[4*q+3] = w2.w;
            }
#pragma unroll
            for (int cc = 0; cc < DZ; ++cc) v -= Cr[cc] * __shfl(xprev, cc);
        }
        float xv = 0.f;
#pragma unroll
        for (int rr = 0; rr < DZ; ++rr) {
            float cand = v * inv;
            float xb = __shfl(cand, rr);
            if (r == rr) xv = cand;
            if (r > rr) v -= Lr[rr] * xb;
        }
        xprev = xv;
        if (t >= own0 && h == 0) xout[t*DZ + r] = xv;
    }
}

// ---------------- chunked backward solve (two RHS) + sample ----------------
__global__ __launch_bounds__(64)
void bwd_solve_kernel(const float* __restrict__ Lg, const float* __restrict__ Cg,
                      const float* __restrict__ b1, const float* __restrict__ b2,
                      float* __restrict__ outSample, int K, int W)
{
    const int lane = threadIdx.x;
    const int k = lane & 31, h = lane >> 5;
    const int own0 = blockIdx.x * K;
    const int own1 = min(TT, own0 + K);
    const int tS = min(TT - 1, own1 - 1 + W);
    float x1p = 0.f, x2p = 0.f;
    for (int t = tS; t >= own0; --t) {
        const float* lt = Lg + (size_t)t * 1024;
        float Lc[32];
#pragma unroll
        for (int j = 0; j < DZ; ++j) Lc[j] = lt[j*DZ + k];
        const float inv = 1.0f / lt[33*k];
        float v1 = b1[t*DZ + k], v2 = b2[t*DZ + k];
        if (t < tS) {
            const float* ct = Cg + (size_t)(t+1) * 1024;
            float Cc[32];
#pragma unroll
            for (int j = 0; j < DZ; ++j) Cc[j] = ct[j*DZ + k];
#pragma unroll
            for (int cc = 0; cc < DZ; ++cc) {
                float a1 = __shfl(x1p, cc), a2 = __shfl(x2p, cc);
                v1 -= Cc[cc] * a1; v2 -= Cc[cc] * a2;
            }
        }
        float x1 = 0.f, x2 = 0.f;
#pragma unroll
        for (int rr = DZ-1; rr >= 0; --rr) {
            float c1 = v1 * inv, c2 = v2 * inv;
            float xb1 = __shfl(c1, rr), xb2 = __shfl(c2, rr);
            if (k == rr) { x1 = c1; x2 = c2; }
            if (k < rr) { v1 -= Lc[rr] * xb1; v2 -= Lc[rr] * xb2; }
        }
        x1p = x1; x2p = x2;
        if (t >= own0 && h == 0) outSample[t*DZ + k] = x1 + x2;
    }
}

// ---------------- entropy ----------------
__global__ void finalize_kernel(const float* __restrict__ logsum, float* __restrict__ out)
{
    if (threadIdx.x == 0) {
        out[TT*DZ] = (logsum[0] - 2270.3016531274763f) / 409600.0f;
    }
}

// ---------------- launch ----------------
extern "C" void kernel_launch(void* const* d_in, const int* in_sizes, int n_in,
                              void* d_out, int out_size, void* d_ws, size_t ws_size,
                              hipStream_t stream)
{
    (void)in_sizes; (void)n_in; (void)out_size; (void)ws_size;
    const float* x        = (const float*)d_in[0];
    const float* norm     = (const float*)d_in[1];
    const float* A        = (const float*)d_in[2];
    const float* QinvChol = (const float*)d_in[3];
    const float* Q0invChol= (const float*)d_in[4];
    const float* Wm_in = (const float*)d_in[5];  const float* bm_in = (const float*)d_in[6];
    const float* Wm_h1 = (const float*)d_in[7];  const float* bm_h1 = (const float*)d_in[8];
    const float* Wm_h3 = (const float*)d_in[9];  const float* bm_h3 = (const float*)d_in[10];
    const float* Wm_out= (const float*)d_in[11]; const float* bm_out= (const float*)d_in[12];
    const float* Wc_in = (const float*)d_in[13]; const float* bc_in = (const float*)d_in[14];
    const float* Wc_h1 = (const float*)d_in[15]; const float* bc_h1 = (const float*)d_in[16];
    const float* Wc_h3 = (const float*)d_in[17]; const float* bc_h3 = (const float*)d_in[18];
    const float* Wc_out= (const float*)d_in[19]; const float* bc_out= (const float*)d_in[20];

    float* ws    = (float*)d_ws;
    float* out   = (float*)d_out;
    float* cw    = ws;
    float* Lbuf  = ws + OFF_ACT0;
    float* Cbuf  = ws + OFF_ACT1;
    float* covb  = ws + OFF_AAB;
    float* meanb = ws + OFF_MEANB;
    float* lamMu = ws + OFF_LAMMU;
    float* ib    = ws + OFF_IBV;
    float* logsum = ws + OFF_LOGSUM;

    unsigned short* a0h = (unsigned short*)(ws + OFF_ACT0); unsigned short* a0l = a0h + 8388608;
    unsigned short* a1h = (unsigned short*)(ws + OFF_ACT1); unsigned short* a1l = a1h + 8388608;
    unsigned short* xh  = (unsigned short*)(ws + OFF_XB);   unsigned short* xl  = xh + 2097152;

    const long OWmi = OFF_WB;
    const long OWm1 = OWmi + 262144;
    const long OWm3 = OWm1 + 1048576;
    const long OWmo = OWm3 + 1048576;
    const long OWci = OWmo + 32768;
    const long OWc1 = OWci + 262144;
    const long OWc3 = OWc1 + 1048576;
    const long OWco = OWc3 + 1048576;
    #define WH(o) ((unsigned short*)(ws + (o)))
    #define WL(o, n) (((unsigned short*)(ws + (o))) + (n))

    setup_kernel<<<dim3(1), dim3(1024), 0, stream>>>(A, QinvChol, Q0invChol, cw);

    // f32 -> bf16 hi/lo conversions
    auto splitLaunch = [&](const float* src, long off, int n) {
        int n4 = n >> 2;
        split_kernel<<<dim3((n4 + 255) / 256), dim3(256), 0, stream>>>(
            src, (unsigned short*)(ws + off), (unsigned short*)(ws + off) + n, n4);
    };
    splitLaunch(x,      OFF_XB, 2097152);
    splitLaunch(Wm_in,  OWmi,   262144);
    splitLaunch(Wm_h1,  OWm1,   1048576);
    splitLaunch(Wm_h3,  OWm3,   1048576);
    splitLaunch(Wm_out, OWmo,   32768);
    splitLaunch(Wc_in,  OWci,   262144);
    splitLaunch(Wc_h1,  OWc1,   1048576);
    splitLaunch(Wc_h3,  OWc3,   1048576);
    splitLaunch(Wc_out, OWco,   1048576);

    const dim3 gBig(8, 64), blk(256);
    // mean MLP
    mgemm<1><<<gBig, blk, 0, stream>>>(xh, xl,  WH(OWmi), WL(OWmi,262144), bm_in, nullptr, a0h, a0l, 1024, 256, 1);
    mgemm<1><<<gBig, blk, 0, stream>>>(a0h, a0l, WH(OWm1), WL(OWm1,1048576), bm_h1, nullptr, a1h, a1l, 1024, 1024, 1);
    mgemm<1><<<gBig, blk, 0, stream>>>(a1h, a1l, WH(OWm3), WL(OWm3,1048576), bm_h3, nullptr, a0h, a0l, 1024, 1024, 1);
    mgemm_small<<<dim3(512), dim3(64), 0, stream>>>(a0h, a0l, WH(OWmo), WL(OWmo,32768), bm_out, meanb, 1024);
    // cov MLP
    mgemm<1><<<gBig, blk, 0, stream>>>(xh, xl,  WH(OWci), WL(OWci,262144), bc_in, nullptr, a1h, a1l, 1024, 256, 1);
    mgemm<1><<<gBig, blk, 0, stream>>>(a1h, a1l, WH(OWc1), WL(OWc1,1048576), bc_h1, nullptr, a0h, a0l, 1024, 1024, 1);
    mgemm<1><<<gBig, blk, 0, stream>>>(a0h, a0l, WH(OWc3), WL(OWc3,1048576), bc_h3, nullptr, a1h, a1l, 1024, 1024, 1);
    mgemm<0><<<gBig, blk, 0, stream>>>(a1h, a1l, WH(OWco), WL(OWco,1048576), bc_out, covb, nullptr, nullptr, 1024, 1024, 0);

    build_blocks_kernel<<<dim3(TT), dim3(256), 0, stream>>>(covb, meanb, lamMu, cw);

    chol_scan2<<<dim3(TT/8),  dim3(64), 0, stream>>>(covb, Lbuf, Cbuf, cw, logsum, 8, 48);
    fwd_solve_kernel<<<dim3(TT/16), dim3(64), 0, stream>>>(Lbuf, Cbuf, lamMu, ib, 16, 64);
    bwd_solve_kernel<<<dim3(TT/16), dim3(64), 0, stream>>>(Lbuf, Cbuf, ib, norm, out, 16, 64);

    finalize_kernel<<<dim3(1), dim3(64), 0, stream>>>(logsum, out);
}

// Round 3
// 1557.787 us; speedup vs baseline: 3.4200x; 1.0073x over previous
//
#include <hip/hip_runtime.h>
#include <math.h>

#define TT 8192
#define DZ 32

typedef short bf16x8 __attribute__((ext_vector_type(8)));
typedef float f32x4 __attribute__((ext_vector_type(4)));
#define MFMA16(a,b,c) __builtin_amdgcn_mfma_f32_16x16x32_bf16(a,b,c,0,0,0)

// ---------------- workspace layout (float units) ----------------
#define OFF_QINV   0
#define OFF_Q0INV  1024
#define OFF_AQA    2048
#define OFF_B      3072
#define OFF_P0     4096
#define OFF_PMID   5120
#define OFF_PLAST  6144
#define OFF_LOGSUM 7168
#define OFF_ACT0   8192                     // act slot0 (bf16 hi+lo) -> later L (f32, col-major per t)
#define OFF_ACT1   (OFF_ACT0 + 8388608)     // act slot1 (bf16 hi+lo) -> later C (f32, X row-major per t)
#define OFF_AAB    (OFF_ACT1 + 8388608)     // cov f32 -> AA in place
#define OFF_XB     (OFF_AAB + 8388608)      // x hi/lo bf16
#define OFF_WB     (OFF_XB + 2097152)       // weights bf16 hi/lo
#define OFF_MEANB  (OFF_WB + 5799936)
#define OFF_LAMMU  (OFF_MEANB + 262144)
#define OFF_IBV    (OFF_LAMMU + 262144)

__device__ __forceinline__ unsigned short f2bf(float f) {
    unsigned int u = __float_as_uint(f);
    u += 0x7FFFu + ((u >> 16) & 1u);
    return (unsigned short)(u >> 16);
}
__device__ __forceinline__ float bf2f(unsigned short h) {
    return __uint_as_float(((unsigned int)h) << 16);
}
__device__ __forceinline__ float rlane(float v, int l) {
    return __uint_as_float(__builtin_amdgcn_readlane(__float_as_uint(v), l));
}

// ---------------- fused f32 -> (hi,lo) bf16 split (all tensors, 1 launch) ----------------
struct SplitSeg { const float* src; unsigned short* hi; int n; };
struct SplitArgs { SplitSeg seg[9]; };

__global__ __launch_bounds__(256)
void split_all(SplitArgs a)
{
    const SplitSeg sg = a.seg[blockIdx.y];
    const int n4 = sg.n >> 2;
    int i = blockIdx.x * 256 + threadIdx.x;
    if (i >= n4) return;
    float4 v = ((const float4*)sg.src)[i];
    ushort4 hh, ll;
    hh.x = f2bf(v.x); ll.x = f2bf(v.x - bf2f(hh.x));
    hh.y = f2bf(v.y); ll.y = f2bf(v.y - bf2f(hh.y));
    hh.z = f2bf(v.z); ll.z = f2bf(v.z - bf2f(hh.z));
    hh.w = f2bf(v.w); ll.w = f2bf(v.w - bf2f(hh.w));
    ((ushort4*)sg.hi)[i] = hh;
    ((ushort4*)(sg.hi + sg.n))[i] = ll;
}

// ---------------- setup: Qinv, Q0inv, AQA, B, priors ----------------
__global__ __launch_bounds__(1024)
void setup_kernel(const float* __restrict__ A, const float* __restrict__ QinvChol,
                  const float* __restrict__ Q0invChol, float* __restrict__ cw)
{
    __shared__ float As[DZ*33], Qc[DZ*33], Q0c[DZ*33], Qi[DZ*33], T1[DZ*33];
    const int tid = threadIdx.x;
    const int i = tid >> 5, j = tid & 31;
    As[i*33+j]  = A[tid];
    Qc[i*33+j]  = QinvChol[tid];
    Q0c[i*33+j] = Q0invChol[tid];
    __syncthreads();
    float qi = 0.f, q0 = 0.f;
    for (int k = 0; k < DZ; ++k) { qi += Qc[i*33+k]*Qc[j*33+k]; q0 += Q0c[i*33+k]*Q0c[j*33+k]; }
    Qi[i*33+j] = qi;
    __syncthreads();
    float t1 = 0.f;
    for (int k = 0; k < DZ; ++k) t1 += Qi[i*33+k]*As[k*33+j];
    T1[i*33+j] = t1;
    __syncthreads();
    float aqa = 0.f, bm = 0.f;
    for (int k = 0; k < DZ; ++k) { aqa += As[k*33+i]*T1[k*33+j]; bm += As[k*33+i]*Qi[k*33+j]; }
    cw[OFF_QINV  + tid] = qi;
    cw[OFF_Q0INV + tid] = q0;
    cw[OFF_AQA   + tid] = aqa;
    cw[OFF_B     + tid] = -bm;
    cw[OFF_P0    + tid] = q0 + aqa;
    cw[OFF_PMID  + tid] = qi + aqa;
    cw[OFF_PLAST + tid] = qi;
    if (tid == 0) cw[OFF_LOGSUM] = 0.f;
}

// ---------------- split-bf16 MFMA GEMM (unchanged from round 2) ----------------
__device__ __forceinline__ void stage_tile(const unsigned short* src, int rowbase, int Kd,
                                           int k0, unsigned short* ldsbase, int w, int lane)
{
#pragma unroll
    for (int inst = 0; inst < 2; ++inst) {
        const int r0  = w * 32 + inst * 16;
        const int row = r0 + (lane >> 2);
        const int g   = (lane & 3) ^ ((row >> 1) & 3);
        const unsigned short* gp = src + (size_t)(rowbase + row) * Kd + k0 + g * 8;
        __builtin_amdgcn_global_load_lds(
            (const __attribute__((address_space(1))) void*)gp,
            (__attribute__((address_space(3))) void*)(ldsbase + r0 * 32),
            16, 0, 0);
    }
}

template<int OM>   // 0: f32 out, 1: (hi,lo) bf16 out
__global__ __launch_bounds__(256)
void mgemm(const unsigned short* __restrict__ Ah, const unsigned short* __restrict__ Al,
           const unsigned short* __restrict__ Wh, const unsigned short* __restrict__ Wl,
           const float* __restrict__ bias, float* __restrict__ outF,
           unsigned short* __restrict__ outH, unsigned short* __restrict__ outL,
           int N, int Kd, int relu)
{
    __shared__ unsigned short lds[2][4][4096];   // [buf][Ah,Al,Wh,Wl][128*32]
    const int tid = threadIdx.x;
    const int lane = tid & 63, w = tid >> 6;
    const int wm = w >> 1, wn = w & 1;
    const int bn = blockIdx.x, bm = blockIdx.y;
    const int ln15 = lane & 15, g4 = lane >> 4;

    f32x4 acc[4][4];
#pragma unroll
    for (int i = 0; i < 4; ++i)
#pragma unroll
        for (int j = 0; j < 4; ++j) acc[i][j] = f32x4{0.f,0.f,0.f,0.f};

    const int nt = Kd >> 5;
    stage_tile(Ah, bm*128, Kd, 0, &lds[0][0][0], w, lane);
    stage_tile(Al, bm*128, Kd, 0, &lds[0][1][0], w, lane);
    stage_tile(Wh, bn*128, Kd, 0, &lds[0][2][0], w, lane);
    stage_tile(Wl, bn*128, Kd, 0, &lds[0][3][0], w, lane);
    __syncthreads();

    int cur = 0;
    for (int t = 0; t < nt; ++t) {
        if (t + 1 < nt) {
            const int k0 = (t + 1) << 5;
            stage_tile(Ah, bm*128, Kd, k0, &lds[cur^1][0][0], w, lane);
            stage_tile(Al, bm*128, Kd, k0, &lds[cur^1][1][0], w, lane);
            stage_tile(Wh, bn*128, Kd, k0, &lds[cur^1][2][0], w, lane);
            stage_tile(Wl, bn*128, Kd, k0, &lds[cur^1][3][0], w, lane);
        }
        bf16x8 fa[4], fal[4], fwh[4], fwl[4];
#pragma unroll
        for (int fm = 0; fm < 4; ++fm) {
            const int lr = wm*64 + fm*16 + ln15;
            const int off = lr*32 + ((g4 ^ ((lr >> 1) & 3)) << 3);
            fa[fm]  = *(const bf16x8*)(&lds[cur][0][0] + off);
            fal[fm] = *(const bf16x8*)(&lds[cur][1][0] + off);
        }
#pragma unroll
        for (int fn = 0; fn < 4; ++fn) {
            const int lr = wn*64 + fn*16 + ln15;
            const int off = lr*32 + ((g4 ^ ((lr >> 1) & 3)) << 3);
            fwh[fn] = *(const bf16x8*)(&lds[cur][2][0] + off);
            fwl[fn] = *(const bf16x8*)(&lds[cur][3][0] + off);
        }
#pragma unroll
        for (int fm = 0; fm < 4; ++fm)
#pragma unroll
            for (int fn = 0; fn < 4; ++fn) {
                acc[fm][fn] = MFMA16(fa[fm],  fwh[fn], acc[fm][fn]);
                acc[fm][fn] = MFMA16(fa[fm],  fwl[fn], acc[fm][fn]);
                acc[fm][fn] = MFMA16(fal[fm], fwh[fn], acc[fm][fn]);
            }
        __syncthreads();
        cur ^= 1;
    }

#pragma unroll
    for (int fm = 0; fm < 4; ++fm)
#pragma unroll
        for (int fn = 0; fn < 4; ++fn) {
            const int col = bn*128 + wn*64 + fn*16 + ln15;
            const float bv = bias[col];
#pragma unroll
            for (int q = 0; q < 4; ++q) {
                const int row = bm*128 + wm*64 + fm*16 + g4*4 + q;
                float v = acc[fm][fn][q] + bv;
                if (relu) v = fmaxf(v, 0.f);
                if (OM == 0) {
                    outF[(size_t)row * N + col] = v;
                } else {
                    unsigned short hv = f2bf(v);
                    outH[(size_t)row * N + col] = hv;
                    outL[(size_t)row * N + col] = f2bf(v - bf2f(hv));
                }
            }
        }
}

// ---------------- small GEMM (N=32): mean = h3 @ Wm_out^T + b ----------------
__global__ __launch_bounds__(64)
void mgemm_small(const unsigned short* __restrict__ Ah, const unsigned short* __restrict__ Al,
                 const unsigned short* __restrict__ Wh, const unsigned short* __restrict__ Wl,
                 const float* __restrict__ bias, float* __restrict__ out, int Kd)
{
    const int lane = threadIdx.x;
    const int rm = blockIdx.x * 16;
    const int ln15 = lane & 15, g = lane >> 4;
    const int row = rm + ln15;
    f32x4 acc0 = {0.f,0.f,0.f,0.f}, acc1 = {0.f,0.f,0.f,0.f};
    for (int k0 = 0; k0 < Kd; k0 += 32) {
        const int k = k0 + g*8;
        bf16x8 a_h = *(const bf16x8*)(Ah + (size_t)row*Kd + k);
        bf16x8 a_l = *(const bf16x8*)(Al + (size_t)row*Kd + k);
        bf16x8 w0h = *(const bf16x8*)(Wh + (size_t)ln15*Kd + k);
        bf16x8 w0l = *(const bf16x8*)(Wl + (size_t)ln15*Kd + k);
        bf16x8 w1h = *(const bf16x8*)(Wh + (size_t)(16+ln15)*Kd + k);
        bf16x8 w1l = *(const bf16x8*)(Wl + (size_t)(16+ln15)*Kd + k);
        acc0 = MFMA16(a_h, w0h, acc0); acc0 = MFMA16(a_h, w0l, acc0); acc0 = MFMA16(a_l, w0h, acc0);
        acc1 = MFMA16(a_h, w1h, acc1); acc1 = MFMA16(a_h, w1l, acc1); acc1 = MFMA16(a_l, w1h, acc1);
    }
#pragma unroll
    for (int q = 0; q < 4; ++q) {
        const int r = rm + g*4 + q;
        out[r*DZ + ln15]      = acc0[q] + bias[ln15];
        out[r*DZ + 16 + ln15] = acc1[q] + bias[16 + ln15];
    }
}

// ---------------- build Lam, AA (in place over cov), lamMu ----------------
__global__ __launch_bounds__(256)
void build_blocks_kernel(float* __restrict__ cov, const float* __restrict__ mean,
                         float* __restrict__ lamMu, const float* __restrict__ cw)
{
    const int t = blockIdx.x, tid = threadIdx.x;
    __shared__ float R[DZ*33];
    __shared__ float Lam[DZ*33];
    __shared__ float mn[DZ];
    float* blk = cov + (size_t)t * 1024;
    {
        float4 v = ((const float4*)blk)[tid];
        const int base = tid * 4;
        const int row = base >> 5, col = base & 31;
        R[row*33 + col + 0] = v.x; R[row*33 + col + 1] = v.y;
        R[row*33 + col + 2] = v.z; R[row*33 + col + 3] = v.w;
    }
    if (tid < DZ) mn[tid] = mean[t*DZ + tid];
    __syncthreads();
    const float* P = cw + (t == 0 ? OFF_P0 : (t == TT-1 ? OFF_PLAST : OFF_PMID));
#pragma unroll
    for (int q = 0; q < 4; ++q) {
        const int idx = tid + 256*q;
        const int i = idx >> 5, j = idx & 31;
        float s = 0.f;
#pragma unroll
        for (int k = 0; k < DZ; ++k) s += R[i*33+k] * R[j*33+k];
        Lam[i*33+j] = s;
        blk[idx] = s + P[idx];
    }
    __syncthreads();
    if (tid < DZ) {
        float s = 0.f;
#pragma unroll
        for (int k = 0; k < DZ; ++k) s += Lam[tid*33+k] * mn[k];
        lamMu[t*DZ + tid] = s;
    }
}

// ---------------- chol scan v3: all-register, readlane broadcasts, zero LDS/barriers ----
// Lane c (both halves duplicate) owns column c of all 32x32 blocks.
// Outputs: Lg col-major per t (lt[col*32+row]); Cg = X row-major per t (ct[r*32+c], C=X^T).
__global__ __launch_bounds__(64)
void chol_scan3(const float* __restrict__ AA, float* __restrict__ Lg,
                float* __restrict__ Cg, const float* __restrict__ cw,
                float* __restrict__ logsum, int K, int W)
{
    const int lane = threadIdx.x;
    const int c = lane & 31;
    const int h = lane >> 5;
    const int own0 = blockIdx.x * K;
    const int own1 = min(TT, own0 + K);
    const int t0 = max(0, own0 - W);

    float Breg[32], Lcol[32], s[32], u[32], Apre[32];
    float invd_own = 0.f, logacc = 0.f;

#pragma unroll
    for (int i = 0; i < 32; ++i) Breg[i] = cw[OFF_B + i*32 + c];
#pragma unroll
    for (int i = 0; i < 32; ++i) Apre[i] = AA[(size_t)t0*1024 + i*32 + c];

    for (int t = t0; t < own1; ++t) {
#pragma unroll
        for (int i = 0; i < 32; ++i) s[i] = Apre[i];
        if (t + 1 < own1) {
            const float* an = AA + (size_t)(t+1)*1024;
#pragma unroll
            for (int i = 0; i < 32; ++i) Apre[i] = an[i*32 + c];
        }
        const bool doX = (t > t0);
        if (doX) {
            // u := column c of B; forward-substitute X = Lprev^{-1} B; fuse S -= X^T X
#pragma unroll
            for (int i = 0; i < 32; ++i) u[i] = Breg[i];
#pragma unroll
            for (int r = 0; r < 32; ++r) {
                float x = u[r] * rlane(invd_own, r);
                u[r] = x;                               // keep X[r][c]
#pragma unroll
                for (int i = r+1; i < 32; ++i) u[i] -= rlane(Lcol[i], r) * x;
#pragma unroll
                for (int i = 0; i < 32; ++i) s[i] -= rlane(x, i) * x;   // S[i][c] -= X[r][i]*X[r][c]
            }
        }

        // Cholesky sweep; lane c's column freezes at j==c (ljc=0 for c<=j keeps it intact)
        float stepLog = 0.f;
#pragma unroll
        for (int j = 0; j < 32; ++j) {
            float sjj = rlane(s[j], j);
            float dj  = sqrtf(sjj);
            float inv = 1.0f / dj;
            stepLog += __logf(sjj);
            float inv2 = inv * inv;
            float ljc = (c > j) ? s[j] * inv2 : 0.f;    // L[c][j] (symmetry: S[j][c]=S[c][j]=s[j])
            invd_own = (c == j) ? inv : invd_own;
#pragma unroll
            for (int i = j; i < 32; ++i) s[i] -= rlane(s[i], j) * ljc;
        }
#pragma unroll
        for (int i = 0; i < 32; ++i) Lcol[i] = s[i] * invd_own;   // valid for i>=c (upper junk unread)

        if (t >= own0) {
            logacc += stepLog;
            if (h == 0) {
                float* lt = Lg + (size_t)t*1024 + c*32;
#pragma unroll
                for (int q = 0; q < 8; ++q)
                    *(float4*)(lt + 4*q) = make_float4(Lcol[4*q], Lcol[4*q+1], Lcol[4*q+2], Lcol[4*q+3]);
                if (doX) {
                    float* ct = Cg + (size_t)t*1024;
#pragma unroll
                    for (int r = 0; r < 32; ++r) ct[r*32 + c] = u[r];
                }
            }
        }
    }
    if (lane == 0) atomicAdd(logsum, logacc * 0.5f);   // logs accumulated as log(d^2)
}

// ---------------- chunked forward bidiagonal solve (L col-major, C = X row-major) -------
__global__ __launch_bounds__(64)
void fwd_solve_kernel(const float* __restrict__ Lg, const float* __restrict__ Cg,
                      const float* __restrict__ bv, float* __restrict__ xout,
                      int K, int W)
{
    const int lane = threadIdx.x;
    const int r = lane & 31, h = lane >> 5;
    const int own0 = blockIdx.x * K;
    const int own1 = min(TT, own0 + K);
    const int t0 = max(0, own0 - W);
    float xprev = 0.f;
    for (int t = t0; t < own1; ++t) {
        const float* lt = Lg + (size_t)t * 1024;
        float Lr[32];                         // row r of L: L[r][j] = lt[j*32+r]
#pragma unroll
        for (int j = 0; j < DZ; ++j) Lr[j] = lt[j*32 + r];
        const float inv = 1.0f / Lr[r];
        float v = bv[t*DZ + r];
        if (t > t0) {
            const float* ct = Cg + (size_t)t * 1024;
            float Cr[32];                     // C[r][cc] = X[cc][r] = ct[cc*32+r]
#pragma unroll
            for (int cc = 0; cc < DZ; ++cc) Cr[cc] = ct[cc*32 + r];
#pragma unroll
            for (int cc = 0; cc < DZ; ++cc) v -= Cr[cc] * __shfl(xprev, cc);
        }
        float xv = 0.f;
#pragma unroll
        for (int rr = 0; rr < DZ; ++rr) {
            float cand = v * inv;
            float xb = __shfl(cand, rr);
            if (r == rr) xv = cand;
            if (r > rr) v -= Lr[rr] * xb;
        }
        xprev = xv;
        if (t >= own0 && h == 0) xout[t*DZ + r] = xv;
    }
}

// ---------------- chunked backward solve (two RHS) + sample -----------------------------
__global__ __launch_bounds__(64)
void bwd_solve_kernel(const float* __restrict__ Lg, const float* __restrict__ Cg,
                      const float* __restrict__ b1, const float* __restrict__ b2,
                      float* __restrict__ outSample, int K, int W)
{
    const int lane = threadIdx.x;
    const int k = lane & 31, h = lane >> 5;
    const int own0 = blockIdx.x * K;
    const int own1 = min(TT, own0 + K);
    const int tS = min(TT - 1, own1 - 1 + W);
    float x1p = 0.f, x2p = 0.f;
    for (int t = tS; t >= own0; --t) {
        const float* lt = Lg + (size_t)t * 1024;
        float Lc[32];                         // column k of L: contiguous in col-major
#pragma unroll
        for (int q = 0; q < 8; ++q) {
            float4 v4 = *(const float4*)(lt + k*32 + 4*q);
            Lc[4*q] = v4.x; Lc[4*q+1] = v4.y; Lc[4*q+2] = v4.z; Lc[4*q+3] = v4.w;
        }
        const float inv = 1.0f / Lc[k];
        float v1 = b1[t*DZ + k], v2 = b2[t*DZ + k];
        if (t < tS) {
            const float* ct = Cg + (size_t)(t+1) * 1024;
            float Cc[32];                     // C[j][k] = X[k][j] = ct[k*32+j], contiguous
#pragma unroll
            for (int q = 0; q < 8; ++q) {
                float4 w4 = *(const float4*)(ct + k*32 + 4*q);
                Cc[4*q] = w4.x; Cc[4*q+1] = w4.y; Cc[4*q+2] = w4.z; Cc[4*q+3] = w4.w;
            }
#pragma unroll
            for (int cc = 0; cc < DZ; ++cc) {
                float a1 = __shfl(x1p, cc), a2 = __shfl(x2p, cc);
                v1 -= Cc[cc] * a1; v2 -= Cc[cc] * a2;
            }
        }
        float x1 = 0.f, x2 = 0.f;
#pragma unroll
        for (int rr = DZ-1; rr >= 0; --rr) {
            float c1 = v1 * inv, c2 = v2 * inv;
            float xb1 = __shfl(c1, rr), xb2 = __shfl(c2, rr);
            if (k == rr) { x1 = c1; x2 = c2; }
            if (k < rr) { v1 -= Lc[rr] * xb1; v2 -= Lc[rr] * xb2; }
        }
        x1p = x1; x2p = x2;
        if (t >= own0 && h == 0) outSample[t*DZ + k] = x1 + x2;
    }
}

// ---------------- entropy ----------------
__global__ void finalize_kernel(const float* __restrict__ logsum, float* __restrict__ out)
{
    if (threadIdx.x == 0) {
        out[TT*DZ] = (logsum[0] - 2270.3016531274763f) / 409600.0f;
    }
}

// ---------------- launch ----------------
extern "C" void kernel_launch(void* const* d_in, const int* in_sizes, int n_in,
                              void* d_out, int out_size, void* d_ws, size_t ws_size,
                              hipStream_t stream)
{
    (void)in_sizes; (void)n_in; (void)out_size; (void)ws_size;
    const float* x        = (const float*)d_in[0];
    const float* norm     = (const float*)d_in[1];
    const float* A        = (const float*)d_in[2];
    const float* QinvChol = (const float*)d_in[3];
    const float* Q0invChol= (const float*)d_in[4];
    const float* Wm_in = (const float*)d_in[5];  const float* bm_in = (const float*)d_in[6];
    const float* Wm_h1 = (const float*)d_in[7];  const float* bm_h1 = (const float*)d_in[8];
    const float* Wm_h3 = (const float*)d_in[9];  const float* bm_h3 = (const float*)d_in[10];
    const float* Wm_out= (const float*)d_in[11]; const float* bm_out= (const float*)d_in[12];
    const float* Wc_in = (const float*)d_in[13]; const float* bc_in = (const float*)d_in[14];
    const float* Wc_h1 = (const float*)d_in[15]; const float* bc_h1 = (const float*)d_in[16];
    const float* Wc_h3 = (const float*)d_in[17]; const float* bc_h3 = (const float*)d_in[18];
    const float* Wc_out= (const float*)d_in[19]; const float* bc_out= (const float*)d_in[20];

    float* ws    = (float*)d_ws;
    float* out   = (float*)d_out;
    float* cw    = ws;
    float* Lbuf  = ws + OFF_ACT0;
    float* Cbuf  = ws + OFF_ACT1;
    float* covb  = ws + OFF_AAB;
    float* meanb = ws + OFF_MEANB;
    float* lamMu = ws + OFF_LAMMU;
    float* ib    = ws + OFF_IBV;
    float* logsum = ws + OFF_LOGSUM;

    unsigned short* a0h = (unsigned short*)(ws + OFF_ACT0); unsigned short* a0l = a0h + 8388608;
    unsigned short* a1h = (unsigned short*)(ws + OFF_ACT1); unsigned short* a1l = a1h + 8388608;
    unsigned short* xh  = (unsigned short*)(ws + OFF_XB);

    const long OWmi = OFF_WB;
    const long OWm1 = OWmi + 262144;
    const long OWm3 = OWm1 + 1048576;
    const long OWmo = OWm3 + 1048576;
    const long OWci = OWmo + 32768;
    const long OWc1 = OWci + 262144;
    const long OWc3 = OWc1 + 1048576;
    const long OWco = OWc3 + 1048576;
    #define WH(o) ((unsigned short*)(ws + (o)))
    #define WL(o, n) (((unsigned short*)(ws + (o))) + (n))

    setup_kernel<<<dim3(1), dim3(1024), 0, stream>>>(A, QinvChol, Q0invChol, cw);

    // fused f32 -> bf16 hi/lo conversions (1 launch for all 9 tensors)
    SplitArgs sa;
    sa.seg[0] = { x,      (unsigned short*)(ws + OFF_XB), 2097152 };
    sa.seg[1] = { Wm_in,  WH(OWmi), 262144 };
    sa.seg[2] = { Wm_h1,  WH(OWm1), 1048576 };
    sa.seg[3] = { Wm_h3,  WH(OWm3), 1048576 };
    sa.seg[4] = { Wm_out, WH(OWmo), 32768 };
    sa.seg[5] = { Wc_in,  WH(OWci), 262144 };
    sa.seg[6] = { Wc_h1,  WH(OWc1), 1048576 };
    sa.seg[7] = { Wc_h3,  WH(OWc3), 1048576 };
    sa.seg[8] = { Wc_out, WH(OWco), 1048576 };
    split_all<<<dim3(2048, 9), dim3(256), 0, stream>>>(sa);

    unsigned short* xl = xh + 2097152; (void)xl;
    const dim3 gBig(8, 64), blk(256);
    // mean MLP
    mgemm<1><<<gBig, blk, 0, stream>>>(xh, WL(OFF_XB,2097152),  WH(OWmi), WL(OWmi,262144), bm_in, nullptr, a0h, a0l, 1024, 256, 1);
    mgemm<1><<<gBig, blk, 0, stream>>>(a0h, a0l, WH(OWm1), WL(OWm1,1048576), bm_h1, nullptr, a1h, a1l, 1024, 1024, 1);
    mgemm<1><<<gBig, blk, 0, stream>>>(a1h, a1l, WH(OWm3), WL(OWm3,1048576), bm_h3, nullptr, a0h, a0l, 1024, 1024, 1);
    mgemm_small<<<dim3(512), dim3(64), 0, stream>>>(a0h, a0l, WH(OWmo), WL(OWmo,32768), bm_out, meanb, 1024);
    // cov MLP
    mgemm<1><<<gBig, blk, 0, stream>>>(xh, WL(OFF_XB,2097152),  WH(OWci), WL(OWci,262144), bc_in, nullptr, a1h, a1l, 1024, 256, 1);
    mgemm<1><<<gBig, blk, 0, stream>>>(a1h, a1l, WH(OWc1), WL(OWc1,1048576), bc_h1, nullptr, a0h, a0l, 1024, 1024, 1);
    mgemm<1><<<gBig, blk, 0, stream>>>(a0h, a0l, WH(OWc3), WL(OWc3,1048576), bc_h3, nullptr, a1h, a1l, 1024, 1024, 1);
    mgemm<0><<<gBig, blk, 0, stream>>>(a1h, a1l, WH(OWco), WL(OWco,1048576), bc_out, covb, nullptr, nullptr, 1024, 1024, 0);

    build_blocks_kernel<<<dim3(TT), dim3(256), 0, stream>>>(covb, meanb, lamMu, cw);

    // chunked scan phases (K = chunk len, W = warm-up len)
    chol_scan3<<<dim3(TT/8),  dim3(64), 0, stream>>>(covb, Lbuf, Cbuf, cw, logsum, 8, 32);
    fwd_solve_kernel<<<dim3(TT/16), dim3(64), 0, stream>>>(Lbuf, Cbuf, lamMu, ib, 16, 64);
    bwd_solve_kernel<<<dim3(TT/16), dim3(64), 0, stream>>>(Lbuf, Cbuf, ib, norm, out, 16, 64);

    finalize_kernel<<<dim3(1), dim3(64), 0, stream>>>(logsum, out);
}

// Round 4
// 1023.021 us; speedup vs baseline: 5.2078x; 1.5227x over previous
//
#include <hip/hip_runtime.h>
#include <math.h>

#define TT 8192
#define DZ 32

typedef short bf16x8 __attribute__((ext_vector_type(8)));
typedef float f32x4 __attribute__((ext_vector_type(4)));
typedef float f32x16 __attribute__((ext_vector_type(16)));
#define MFMA16(a,b,c) __builtin_amdgcn_mfma_f32_16x16x32_bf16(a,b,c,0,0,0)
#define MFMA32(a,b,c) __builtin_amdgcn_mfma_f32_32x32x16_bf16(a,b,c,0,0,0)

// ---------------- workspace layout (float units) ----------------
#define OFF_QINV   0
#define OFF_Q0INV  1024
#define OFF_AQA    2048
#define OFF_B      3072
#define OFF_P0     4096
#define OFF_PMID   5120
#define OFF_PLAST  6144
#define OFF_LOGSUM 7168
#define OFF_ACT0   8192                     // act slot0 (bf16 hi+lo) -> later L (f32, col-major per t)
#define OFF_ACT1   (OFF_ACT0 + 8388608)     // act slot1 (bf16 hi+lo) -> later C (f32, X row-major per t)
#define OFF_AAB    (OFF_ACT1 + 8388608)     // cov f32 -> AA in place
#define OFF_XB     (OFF_AAB + 8388608)      // x hi/lo bf16
#define OFF_WB     (OFF_XB + 2097152)       // weights bf16 hi/lo
#define OFF_MEANB  (OFF_WB + 5799936)
#define OFF_LAMMU  (OFF_MEANB + 262144)
#define OFF_IBV    (OFF_LAMMU + 262144)

__device__ __forceinline__ unsigned short f2bf(float f) {
    unsigned int u = __float_as_uint(f);
    u += 0x7FFFu + ((u >> 16) & 1u);
    return (unsigned short)(u >> 16);
}
__device__ __forceinline__ float bf2f(unsigned short h) {
    return __uint_as_float(((unsigned int)h) << 16);
}
__device__ __forceinline__ float rlane(float v, int l) {
    return __uint_as_float(__builtin_amdgcn_readlane(__float_as_uint(v), l));
}

// ---------------- fused f32 -> (hi,lo) bf16 split (all tensors, 1 launch) ----------------
struct SplitSeg { const float* src; unsigned short* hi; int n; };
struct SplitArgs { SplitSeg seg[9]; };

__global__ __launch_bounds__(256)
void split_all(SplitArgs a)
{
    const SplitSeg sg = a.seg[blockIdx.y];
    const int n4 = sg.n >> 2;
    int i = blockIdx.x * 256 + threadIdx.x;
    if (i >= n4) return;
    float4 v = ((const float4*)sg.src)[i];
    ushort4 hh, ll;
    hh.x = f2bf(v.x); ll.x = f2bf(v.x - bf2f(hh.x));
    hh.y = f2bf(v.y); ll.y = f2bf(v.y - bf2f(hh.y));
    hh.z = f2bf(v.z); ll.z = f2bf(v.z - bf2f(hh.z));
    hh.w = f2bf(v.w); ll.w = f2bf(v.w - bf2f(hh.w));
    ((ushort4*)sg.hi)[i] = hh;
    ((ushort4*)(sg.hi + sg.n))[i] = ll;
}

// ---------------- setup: Qinv, Q0inv, AQA, B, priors ----------------
__global__ __launch_bounds__(1024)
void setup_kernel(const float* __restrict__ A, const float* __restrict__ QinvChol,
                  const float* __restrict__ Q0invChol, float* __restrict__ cw)
{
    __shared__ float As[DZ*33], Qc[DZ*33], Q0c[DZ*33], Qi[DZ*33], T1[DZ*33];
    const int tid = threadIdx.x;
    const int i = tid >> 5, j = tid & 31;
    As[i*33+j]  = A[tid];
    Qc[i*33+j]  = QinvChol[tid];
    Q0c[i*33+j] = Q0invChol[tid];
    __syncthreads();
    float qi = 0.f, q0 = 0.f;
    for (int k = 0; k < DZ; ++k) { qi += Qc[i*33+k]*Qc[j*33+k]; q0 += Q0c[i*33+k]*Q0c[j*33+k]; }
    Qi[i*33+j] = qi;
    __syncthreads();
    float t1 = 0.f;
    for (int k = 0; k < DZ; ++k) t1 += Qi[i*33+k]*As[k*33+j];
    T1[i*33+j] = t1;
    __syncthreads();
    float aqa = 0.f, bm = 0.f;
    for (int k = 0; k < DZ; ++k) { aqa += As[k*33+i]*T1[k*33+j]; bm += As[k*33+i]*Qi[k*33+j]; }
    cw[OFF_QINV  + tid] = qi;
    cw[OFF_Q0INV + tid] = q0;
    cw[OFF_AQA   + tid] = aqa;
    cw[OFF_B     + tid] = -bm;
    cw[OFF_P0    + tid] = q0 + aqa;
    cw[OFF_PMID  + tid] = qi + aqa;
    cw[OFF_PLAST + tid] = qi;
    if (tid == 0) cw[OFF_LOGSUM] = 0.f;
}

// ---------------- split-bf16 MFMA GEMM ----------------
__device__ __forceinline__ void stage_tile(const unsigned short* src, int rowbase, int Kd,
                                           int k0, unsigned short* ldsbase, int w, int lane)
{
#pragma unroll
    for (int inst = 0; inst < 2; ++inst) {
        const int r0  = w * 32 + inst * 16;
        const int row = r0 + (lane >> 2);
        const int g   = (lane & 3) ^ ((row >> 1) & 3);
        const unsigned short* gp = src + (size_t)(rowbase + row) * Kd + k0 + g * 8;
        __builtin_amdgcn_global_load_lds(
            (const __attribute__((address_space(1))) void*)gp,
            (__attribute__((address_space(3))) void*)(ldsbase + r0 * 32),
            16, 0, 0);
    }
}

template<int OM>   // 0: f32 out, 1: (hi,lo) bf16 out
__global__ __launch_bounds__(256)
void mgemm(const unsigned short* __restrict__ Ah, const unsigned short* __restrict__ Al,
           const unsigned short* __restrict__ Wh, const unsigned short* __restrict__ Wl,
           const float* __restrict__ bias, float* __restrict__ outF,
           unsigned short* __restrict__ outH, unsigned short* __restrict__ outL,
           int N, int Kd, int relu)
{
    __shared__ unsigned short lds[2][4][4096];   // [buf][Ah,Al,Wh,Wl][128*32]
    const int tid = threadIdx.x;
    const int lane = tid & 63, w = tid >> 6;
    const int wm = w >> 1, wn = w & 1;
    const int bn = blockIdx.x, bm = blockIdx.y;
    const int ln15 = lane & 15, g4 = lane >> 4;

    f32x4 acc[4][4];
#pragma unroll
    for (int i = 0; i < 4; ++i)
#pragma unroll
        for (int j = 0; j < 4; ++j) acc[i][j] = f32x4{0.f,0.f,0.f,0.f};

    const int nt = Kd >> 5;
    stage_tile(Ah, bm*128, Kd, 0, &lds[0][0][0], w, lane);
    stage_tile(Al, bm*128, Kd, 0, &lds[0][1][0], w, lane);
    stage_tile(Wh, bn*128, Kd, 0, &lds[0][2][0], w, lane);
    stage_tile(Wl, bn*128, Kd, 0, &lds[0][3][0], w, lane);
    __syncthreads();

    int cur = 0;
    for (int t = 0; t < nt; ++t) {
        if (t + 1 < nt) {
            const int k0 = (t + 1) << 5;
            stage_tile(Ah, bm*128, Kd, k0, &lds[cur^1][0][0], w, lane);
            stage_tile(Al, bm*128, Kd, k0, &lds[cur^1][1][0], w, lane);
            stage_tile(Wh, bn*128, Kd, k0, &lds[cur^1][2][0], w, lane);
            stage_tile(Wl, bn*128, Kd, k0, &lds[cur^1][3][0], w, lane);
        }
        bf16x8 fa[4], fal[4], fwh[4], fwl[4];
#pragma unroll
        for (int fm = 0; fm < 4; ++fm) {
            const int lr = wm*64 + fm*16 + ln15;
            const int off = lr*32 + ((g4 ^ ((lr >> 1) & 3)) << 3);
            fa[fm]  = *(const bf16x8*)(&lds[cur][0][0] + off);
            fal[fm] = *(const bf16x8*)(&lds[cur][1][0] + off);
        }
#pragma unroll
        for (int fn = 0; fn < 4; ++fn) {
            const int lr = wn*64 + fn*16 + ln15;
            const int off = lr*32 + ((g4 ^ ((lr >> 1) & 3)) << 3);
            fwh[fn] = *(const bf16x8*)(&lds[cur][2][0] + off);
            fwl[fn] = *(const bf16x8*)(&lds[cur][3][0] + off);
        }
#pragma unroll
        for (int fm = 0; fm < 4; ++fm)
#pragma unroll
            for (int fn = 0; fn < 4; ++fn) {
                acc[fm][fn] = MFMA16(fa[fm],  fwh[fn], acc[fm][fn]);
                acc[fm][fn] = MFMA16(fa[fm],  fwl[fn], acc[fm][fn]);
                acc[fm][fn] = MFMA16(fal[fm], fwh[fn], acc[fm][fn]);
            }
        __syncthreads();
        cur ^= 1;
    }

#pragma unroll
    for (int fm = 0; fm < 4; ++fm)
#pragma unroll
        for (int fn = 0; fn < 4; ++fn) {
            const int col = bn*128 + wn*64 + fn*16 + ln15;
            const float bv = bias[col];
#pragma unroll
            for (int q = 0; q < 4; ++q) {
                const int row = bm*128 + wm*64 + fm*16 + g4*4 + q;
                float v = acc[fm][fn][q] + bv;
                if (relu) v = fmaxf(v, 0.f);
                if (OM == 0) {
                    outF[(size_t)row * N + col] = v;
                } else {
                    unsigned short hv = f2bf(v);
                    outH[(size_t)row * N + col] = hv;
                    outL[(size_t)row * N + col] = f2bf(v - bf2f(hv));
                }
            }
        }
}

// ---------------- small GEMM (N=32): mean = h3 @ Wm_out^T + b ----------------
__global__ __launch_bounds__(64)
void mgemm_small(const unsigned short* __restrict__ Ah, const unsigned short* __restrict__ Al,
                 const unsigned short* __restrict__ Wh, const unsigned short* __restrict__ Wl,
                 const float* __restrict__ bias, float* __restrict__ out, int Kd)
{
    const int lane = threadIdx.x;
    const int rm = blockIdx.x * 16;
    const int ln15 = lane & 15, g = lane >> 4;
    const int row = rm + ln15;
    f32x4 acc0 = {0.f,0.f,0.f,0.f}, acc1 = {0.f,0.f,0.f,0.f};
    for (int k0 = 0; k0 < Kd; k0 += 32) {
        const int k = k0 + g*8;
        bf16x8 a_h = *(const bf16x8*)(Ah + (size_t)row*Kd + k);
        bf16x8 a_l = *(const bf16x8*)(Al + (size_t)row*Kd + k);
        bf16x8 w0h = *(const bf16x8*)(Wh + (size_t)ln15*Kd + k);
        bf16x8 w0l = *(const bf16x8*)(Wl + (size_t)ln15*Kd + k);
        bf16x8 w1h = *(const bf16x8*)(Wh + (size_t)(16+ln15)*Kd + k);
        bf16x8 w1l = *(const bf16x8*)(Wl + (size_t)(16+ln15)*Kd + k);
        acc0 = MFMA16(a_h, w0h, acc0); acc0 = MFMA16(a_h, w0l, acc0); acc0 = MFMA16(a_l, w0h, acc0);
        acc1 = MFMA16(a_h, w1h, acc1); acc1 = MFMA16(a_h, w1l, acc1); acc1 = MFMA16(a_l, w1h, acc1);
    }
#pragma unroll
    for (int q = 0; q < 4; ++q) {
        const int r = rm + g*4 + q;
        out[r*DZ + ln15]      = acc0[q] + bias[ln15];
        out[r*DZ + 16 + ln15] = acc1[q] + bias[16 + ln15];
    }
}

// ---------------- build Lam, AA (in place over cov), lamMu ----------------
__global__ __launch_bounds__(256)
void build_blocks_kernel(float* __restrict__ cov, const float* __restrict__ mean,
                         float* __restrict__ lamMu, const float* __restrict__ cw)
{
    const int t = blockIdx.x, tid = threadIdx.x;
    __shared__ float R[DZ*33];
    __shared__ float Lam[DZ*33];
    __shared__ float mn[DZ];
    float* blk = cov + (size_t)t * 1024;
    {
        float4 v = ((const float4*)blk)[tid];
        const int base = tid * 4;
        const int row = base >> 5, col = base & 31;
        R[row*33 + col + 0] = v.x; R[row*33 + col + 1] = v.y;
        R[row*33 + col + 2] = v.z; R[row*33 + col + 3] = v.w;
    }
    if (tid < DZ) mn[tid] = mean[t*DZ + tid];
    __syncthreads();
    const float* P = cw + (t == 0 ? OFF_P0 : (t == TT-1 ? OFF_PLAST : OFF_PMID));
#pragma unroll
    for (int q = 0; q < 4; ++q) {
        const int idx = tid + 256*q;
        const int i = idx >> 5, j = idx & 31;
        float s = 0.f;
#pragma unroll
        for (int k = 0; k < DZ; ++k) s += R[i*33+k] * R[j*33+k];
        Lam[i*33+j] = s;
        blk[idx] = s + P[idx];
    }
    __syncthreads();
    if (tid < DZ) {
        float s = 0.f;
#pragma unroll
        for (int k = 0; k < DZ; ++k) s += Lam[tid*33+k] * mn[k];
        lamMu[t*DZ + tid] = s;
    }
}

// ---------------- chol scan v4: registers + readlane + MFMA for S -= X^T X ----------------
// Lane c (both halves duplicate state) owns column c of all 32x32 blocks.
// X^T X via mfma_f32_32x32x16_bf16: A-frag == B-frag == u[k-slice] (symmetric product).
// A layout: row=lane&31, k=8*(lane>>5)+idx;  B: col=lane&31, same k.  (mirrors verified 16x16 pattern)
// D layout: col=lane&31, row=(reg&3)+8*(reg>>2)+4*(lane>>5)  [m74/m101-verified]
__global__ __launch_bounds__(64)
void chol_scan4(const float* __restrict__ AA, float* __restrict__ Lg,
                float* __restrict__ Cg, const float* __restrict__ cw,
                float* __restrict__ logsum, int K, int W)
{
    const int lane = threadIdx.x;
    const int c = lane & 31;
    const int h = lane >> 5;
    const int own0 = blockIdx.x * K;
    const int own1 = min(TT, own0 + K);
    const int t0 = max(0, own0 - W);

    float Breg[32], Lcol[32], s[32], u[32], Apre[32];
    float invd_own = 0.f, logacc = 0.f;

#pragma unroll
    for (int i = 0; i < 32; ++i) Breg[i] = cw[OFF_B + i*32 + c];
#pragma unroll
    for (int i = 0; i < 32; ++i) Apre[i] = AA[(size_t)t0*1024 + i*32 + c];

    for (int t = t0; t < own1; ++t) {
#pragma unroll
        for (int i = 0; i < 32; ++i) s[i] = Apre[i];
        if (t + 1 < own1) {
            const float* an = AA + (size_t)(t+1)*1024;
#pragma unroll
            for (int i = 0; i < 32; ++i) Apre[i] = an[i*32 + c];
        }
        const bool doX = (t > t0);
        if (doX) {
            // forward-substitute X = Lprev^{-1} B (u = column c of X)
#pragma unroll
            for (int i = 0; i < 32; ++i) u[i] = Breg[i];
#pragma unroll
            for (int r = 0; r < 32; ++r) {
                float x = u[r] * rlane(invd_own, r);
                u[r] = x;
#pragma unroll
                for (int i = r+1; i < 32; ++i) u[i] = fmaf(-rlane(Lcol[i], r), x, u[i]);
            }
            // S -= X^T X via 6 split-bf16 MFMAs (A-frag == B-frag)
            float f0[8], f1[8];
#pragma unroll
            for (int j = 0; j < 8; ++j) {
                f0[j] = h ? u[8+j]  : u[j];
                f1[j] = h ? u[24+j] : u[16+j];
            }
            bf16x8 A0h, A0l, A1h, A1l;
#pragma unroll
            for (int j = 0; j < 8; ++j) {
                unsigned short hh0 = f2bf(f0[j]);
                A0h[j] = (short)hh0; A0l[j] = (short)f2bf(f0[j] - bf2f(hh0));
                unsigned short hh1 = f2bf(f1[j]);
                A1h[j] = (short)hh1; A1l[j] = (short)f2bf(f1[j] - bf2f(hh1));
            }
            f32x16 d;
#pragma unroll
            for (int q = 0; q < 16; ++q) d[q] = 0.f;
            d = MFMA32(A0h, A0h, d);
            d = MFMA32(A0h, A0l, d);
            d = MFMA32(A0l, A0h, d);
            d = MFMA32(A1h, A1h, d);
            d = MFMA32(A1h, A1l, d);
            d = MFMA32(A1l, A1h, d);
            float dsw[16];
#pragma unroll
            for (int q = 0; q < 16; ++q) dsw[q] = __shfl_xor(d[q], 32);
#pragma unroll
            for (int i = 0; i < 32; ++i) {
                const int q  = (i & 3) + ((i >> 3) << 2);
                const int hh = (i >> 2) & 1;
                s[i] -= (h == hh) ? d[q] : dsw[q];
            }
        }

        // Cholesky sweep; lane c's column freezes at j==c (ljc=0 for c<=j)
        float stepLog = 0.f;
#pragma unroll
        for (int j = 0; j < 32; ++j) {
            float sjj = rlane(s[j], j);
            float inv = __builtin_amdgcn_rsqf(sjj);
            stepLog += __logf(sjj);
            float inv2 = inv * inv;
            float ljc = (c > j) ? s[j] * inv2 : 0.f;
            invd_own = (c == j) ? inv : invd_own;
#pragma unroll
            for (int i = j; i < 32; ++i) s[i] = fmaf(-rlane(s[i], j), ljc, s[i]);
        }
#pragma unroll
        for (int i = 0; i < 32; ++i) Lcol[i] = s[i] * invd_own;   // valid i>=c; upper junk unread

        if (t >= own0) {
            logacc += stepLog;
            // L store: half h writes rows 16h..16h+15 of column c (col-major)
            float* lt = Lg + (size_t)t*1024 + c*32 + h*16;
#pragma unroll
            for (int q = 0; q < 4; ++q) {
                float4 v4 = make_float4(h ? Lcol[16+4*q]   : Lcol[4*q],
                                        h ? Lcol[16+4*q+1] : Lcol[4*q+1],
                                        h ? Lcol[16+4*q+2] : Lcol[4*q+2],
                                        h ? Lcol[16+4*q+3] : Lcol[4*q+3]);
                *(float4*)(lt + 4*q) = v4;
            }
            if (doX) {
                float* ct = Cg + (size_t)t*1024;
#pragma unroll
                for (int rr = 0; rr < 16; ++rr) {
                    float val = h ? u[16+rr] : u[rr];
                    ct[(h*16+rr)*32 + c] = val;
                }
            }
        }
    }
    if (lane == 0) atomicAdd(logsum, logacc * 0.5f);   // logs accumulated as log(d^2)
}

// ---------------- chunked forward bidiagonal solve (L col-major, C = X row-major) -------
__global__ __launch_bounds__(64)
void fwd_solve_kernel(const float* __restrict__ Lg, const float* __restrict__ Cg,
                      const float* __restrict__ bv, float* __restrict__ xout,
                      int K, int W)
{
    const int lane = threadIdx.x;
    const int r = lane & 31, h = lane >> 5;
    const int own0 = blockIdx.x * K;
    const int own1 = min(TT, own0 + K);
    const int t0 = max(0, own0 - W);
    float xprev = 0.f;
    for (int t = t0; t < own1; ++t) {
        const float* lt = Lg + (size_t)t * 1024;
        float Lr[32];                         // row r of L: L[r][j] = lt[j*32+r]
#pragma unroll
        for (int j = 0; j < DZ; ++j) Lr[j] = lt[j*32 + r];
        const float inv = __builtin_amdgcn_rcpf(Lr[r]);
        float v = bv[t*DZ + r];
        if (t > t0) {
            const float* ct = Cg + (size_t)t * 1024;
            float Cr[32];                     // C[r][cc] = X[cc][r] = ct[cc*32+r]
#pragma unroll
            for (int cc = 0; cc < DZ; ++cc) Cr[cc] = ct[cc*32 + r];
#pragma unroll
            for (int cc = 0; cc < DZ; ++cc) v = fmaf(-Cr[cc], __shfl(xprev, cc), v);
        }
        float xv = 0.f;
#pragma unroll
        for (int rr = 0; rr < DZ; ++rr) {
            float cand = v * inv;
            float xb = __shfl(cand, rr);
            if (r == rr) xv = cand;
            if (r > rr) v = fmaf(-Lr[rr], xb, v);
        }
        xprev = xv;
        if (t >= own0 && h == 0) xout[t*DZ + r] = xv;
    }
}

// ---------------- chunked backward solve (two RHS) + sample -----------------------------
__global__ __launch_bounds__(64)
void bwd_solve_kernel(const float* __restrict__ Lg, const float* __restrict__ Cg,
                      const float* __restrict__ b1, const float* __restrict__ b2,
                      float* __restrict__ outSample, int K, int W)
{
    const int lane = threadIdx.x;
    const int k = lane & 31, h = lane >> 5;
    const int own0 = blockIdx.x * K;
    const int own1 = min(TT, own0 + K);
    const int tS = min(TT - 1, own1 - 1 + W);
    float x1p = 0.f, x2p = 0.f;
    for (int t = tS; t >= own0; --t) {
        const float* lt = Lg + (size_t)t * 1024;
        float Lc[32];                         // column k of L: contiguous in col-major
#pragma unroll
        for (int q = 0; q < 8; ++q) {
            float4 v4 = *(const float4*)(lt + k*32 + 4*q);
            Lc[4*q] = v4.x; Lc[4*q+1] = v4.y; Lc[4*q+2] = v4.z; Lc[4*q+3] = v4.w;
        }
        const float inv = __builtin_amdgcn_rcpf(Lc[k]);
        float v1 = b1[t*DZ + k], v2 = b2[t*DZ + k];
        if (t < tS) {
            const float* ct = Cg + (size_t)(t+1) * 1024;
            float Cc[32];                     // C[j][k] = X[k][j] = ct[k*32+j], contiguous
#pragma unroll
            for (int q = 0; q < 8; ++q) {
                float4 w4 = *(const float4*)(ct + k*32 + 4*q);
                Cc[4*q] = w4.x; Cc[4*q+1] = w4.y; Cc[4*q+2] = w4.z; Cc[4*q+3] = w4.w;
            }
#pragma unroll
            for (int cc = 0; cc < DZ; ++cc) {
                float a1 = __shfl(x1p, cc), a2 = __shfl(x2p, cc);
                v1 = fmaf(-Cc[cc], a1, v1); v2 = fmaf(-Cc[cc], a2, v2);
            }
        }
        float x1 = 0.f, x2 = 0.f;
#pragma unroll
        for (int rr = DZ-1; rr >= 0; --rr) {
            float c1 = v1 * inv, c2 = v2 * inv;
            float xb1 = __shfl(c1, rr), xb2 = __shfl(c2, rr);
            if (k == rr) { x1 = c1; x2 = c2; }
            if (k < rr) { v1 = fmaf(-Lc[rr], xb1, v1); v2 = fmaf(-Lc[rr], xb2, v2); }
        }
        x1p = x1; x2p = x2;
        if (t >= own0 && h == 0) outSample[t*DZ + k] = x1 + x2;
    }
}

// ---------------- entropy ----------------
__global__ void finalize_kernel(const float* __restrict__ logsum, float* __restrict__ out)
{
    if (threadIdx.x == 0) {
        out[TT*DZ] = (logsum[0] - 2270.3016531274763f) / 409600.0f;
    }
}

// ---------------- launch ----------------
extern "C" void kernel_launch(void* const* d_in, const int* in_sizes, int n_in,
                              void* d_out, int out_size, void* d_ws, size_t ws_size,
                              hipStream_t stream)
{
    (void)in_sizes; (void)n_in; (void)out_size; (void)ws_size;
    const float* x        = (const float*)d_in[0];
    const float* norm     = (const float*)d_in[1];
    const float* A        = (const float*)d_in[2];
    const float* QinvChol = (const float*)d_in[3];
    const float* Q0invChol= (const float*)d_in[4];
    const float* Wm_in = (const float*)d_in[5];  const float* bm_in = (const float*)d_in[6];
    const float* Wm_h1 = (const float*)d_in[7];  const float* bm_h1 = (const float*)d_in[8];
    const float* Wm_h3 = (const float*)d_in[9];  const float* bm_h3 = (const float*)d_in[10];
    const float* Wm_out= (const float*)d_in[11]; const float* bm_out= (const float*)d_in[12];
    const float* Wc_in = (const float*)d_in[13]; const float* bc_in = (const float*)d_in[14];
    const float* Wc_h1 = (const float*)d_in[15]; const float* bc_h1 = (const float*)d_in[16];
    const float* Wc_h3 = (const float*)d_in[17]; const float* bc_h3 = (const float*)d_in[18];
    const float* Wc_out= (const float*)d_in[19]; const float* bc_out= (const float*)d_in[20];

    float* ws    = (float*)d_ws;
    float* out   = (float*)d_out;
    float* cw    = ws;
    float* Lbuf  = ws + OFF_ACT0;
    float* Cbuf  = ws + OFF_ACT1;
    float* covb  = ws + OFF_AAB;
    float* meanb = ws + OFF_MEANB;
    float* lamMu = ws + OFF_LAMMU;
    float* ib    = ws + OFF_IBV;
    float* logsum = ws + OFF_LOGSUM;

    unsigned short* a0h = (unsigned short*)(ws + OFF_ACT0); unsigned short* a0l = a0h + 8388608;
    unsigned short* a1h = (unsigned short*)(ws + OFF_ACT1); unsigned short* a1l = a1h + 8388608;
    unsigned short* xh  = (unsigned short*)(ws + OFF_XB);

    const long OWmi = OFF_WB;
    const long OWm1 = OWmi + 262144;
    const long OWm3 = OWm1 + 1048576;
    const long OWmo = OWm3 + 1048576;
    const long OWci = OWmo + 32768;
    const long OWc1 = OWci + 262144;
    const long OWc3 = OWc1 + 1048576;
    const long OWco = OWc3 + 1048576;
    #define WH(o) ((unsigned short*)(ws + (o)))
    #define WL(o, n) (((unsigned short*)(ws + (o))) + (n))

    setup_kernel<<<dim3(1), dim3(1024), 0, stream>>>(A, QinvChol, Q0invChol, cw);

    SplitArgs sa;
    sa.seg[0] = { x,      (unsigned short*)(ws + OFF_XB), 2097152 };
    sa.seg[1] = { Wm_in,  WH(OWmi), 262144 };
    sa.seg[2] = { Wm_h1,  WH(OWm1), 1048576 };
    sa.seg[3] = { Wm_h3,  WH(OWm3), 1048576 };
    sa.seg[4] = { Wm_out, WH(OWmo), 32768 };
    sa.seg[5] = { Wc_in,  WH(OWci), 262144 };
    sa.seg[6] = { Wc_h1,  WH(OWc1), 1048576 };
    sa.seg[7] = { Wc_h3,  WH(OWc3), 1048576 };
    sa.seg[8] = { Wc_out, WH(OWco), 1048576 };
    split_all<<<dim3(2048, 9), dim3(256), 0, stream>>>(sa);

    const dim3 gBig(8, 64), blk(256);
    // mean MLP
    mgemm<1><<<gBig, blk, 0, stream>>>(xh, WL(OFF_XB,2097152),  WH(OWmi), WL(OWmi,262144), bm_in, nullptr, a0h, a0l, 1024, 256, 1);
    mgemm<1><<<gBig, blk, 0, stream>>>(a0h, a0l, WH(OWm1), WL(OWm1,1048576), bm_h1, nullptr, a1h, a1l, 1024, 1024, 1);
    mgemm<1><<<gBig, blk, 0, stream>>>(a1h, a1l, WH(OWm3), WL(OWm3,1048576), bm_h3, nullptr, a0h, a0l, 1024, 1024, 1);
    mgemm_small<<<dim3(512), dim3(64), 0, stream>>>(a0h, a0l, WH(OWmo), WL(OWmo,32768), bm_out, meanb, 1024);
    // cov MLP
    mgemm<1><<<gBig, blk, 0, stream>>>(xh, WL(OFF_XB,2097152),  WH(OWci), WL(OWci,262144), bc_in, nullptr, a1h, a1l, 1024, 256, 1);
    mgemm<1><<<gBig, blk, 0, stream>>>(a1h, a1l, WH(OWc1), WL(OWc1,1048576), bc_h1, nullptr, a0h, a0l, 1024, 1024, 1);
    mgemm<1><<<gBig, blk, 0, stream>>>(a0h, a0l, WH(OWc3), WL(OWc3,1048576), bc_h3, nullptr, a1h, a1l, 1024, 1024, 1);
    mgemm<0><<<gBig, blk, 0, stream>>>(a1h, a1l, WH(OWco), WL(OWco,1048576), bc_out, covb, nullptr, nullptr, 1024, 1024, 0);

    build_blocks_kernel<<<dim3(TT), dim3(256), 0, stream>>>(covb, meanb, lamMu, cw);

    // chunked scan phases (K = chunk len, W = warm-up len)
    chol_scan4<<<dim3(TT/8),  dim3(64), 0, stream>>>(covb, Lbuf, Cbuf, cw, logsum, 8, 24);
    fwd_solve_kernel<<<dim3(TT/16), dim3(64), 0, stream>>>(Lbuf, Cbuf, lamMu, ib, 16, 48);
    bwd_solve_kernel<<<dim3(TT/16), dim3(64), 0, stream>>>(Lbuf, Cbuf, ib, norm, out, 16, 48);

    finalize_kernel<<<dim3(1), dim3(64), 0, stream>>>(logsum, out);
}

// Round 5
// 832.868 us; speedup vs baseline: 6.3968x; 1.2283x over previous
//
#include <hip/hip_runtime.h>
#include <math.h>

#define TT 8192
#define DZ 32

typedef short bf16x8 __attribute__((ext_vector_type(8)));
typedef float f32x4 __attribute__((ext_vector_type(4)));
typedef float f32x16 __attribute__((ext_vector_type(16)));
#define MFMA16(a,b,c) __builtin_amdgcn_mfma_f32_16x16x32_bf16(a,b,c,0,0,0)
#define MFMA32(a,b,c) __builtin_amdgcn_mfma_f32_32x32x16_bf16(a,b,c,0,0,0)

// ---------------- workspace layout (float units) ----------------
#define OFF_QINV   0
#define OFF_Q0INV  1024
#define OFF_AQA    2048
#define OFF_B      3072
#define OFF_P0     4096
#define OFF_PMID   5120
#define OFF_PLAST  6144
#define OFF_LOGSUM 7168
#define OFF_ACT0   8192                     // act slot0 (bf16 hi+lo) -> later L (f32, col-major per t)
#define OFF_ACT1   (OFF_ACT0 + 8388608)     // act slot1 (bf16 hi+lo) -> later C (f32, X row-major per t)
#define OFF_AAB    (OFF_ACT1 + 8388608)     // cov f32 -> AA in place
#define OFF_XB     (OFF_AAB + 8388608)      // x hi/lo bf16
#define OFF_WB     (OFF_XB + 2097152)       // weights bf16 hi/lo
#define OFF_MEANB  (OFF_WB + 5799936)
#define OFF_LAMMU  (OFF_MEANB + 262144)
#define OFF_IBV    (OFF_LAMMU + 262144)

__device__ __forceinline__ unsigned short f2bf(float f) {
    unsigned int u = __float_as_uint(f);
    u += 0x7FFFu + ((u >> 16) & 1u);
    return (unsigned short)(u >> 16);
}
__device__ __forceinline__ float bf2f(unsigned short h) {
    return __uint_as_float(((unsigned int)h) << 16);
}
__device__ __forceinline__ float rlane(float v, int l) {
    return __uint_as_float(__builtin_amdgcn_readlane(__float_as_uint(v), l));
}

// ---------------- fused f32 -> (hi,lo) bf16 split (all tensors, 1 launch) ----------------
struct SplitSeg { const float* src; unsigned short* hi; int n; };
struct SplitArgs { SplitSeg seg[9]; };

__global__ __launch_bounds__(256)
void split_all(SplitArgs a)
{
    const SplitSeg sg = a.seg[blockIdx.y];
    const int n4 = sg.n >> 2;
    int i = blockIdx.x * 256 + threadIdx.x;
    if (i >= n4) return;
    float4 v = ((const float4*)sg.src)[i];
    ushort4 hh, ll;
    hh.x = f2bf(v.x); ll.x = f2bf(v.x - bf2f(hh.x));
    hh.y = f2bf(v.y); ll.y = f2bf(v.y - bf2f(hh.y));
    hh.z = f2bf(v.z); ll.z = f2bf(v.z - bf2f(hh.z));
    hh.w = f2bf(v.w); ll.w = f2bf(v.w - bf2f(hh.w));
    ((ushort4*)sg.hi)[i] = hh;
    ((ushort4*)(sg.hi + sg.n))[i] = ll;
}

// ---------------- setup: Qinv, Q0inv, AQA, B, priors ----------------
__global__ __launch_bounds__(1024)
void setup_kernel(const float* __restrict__ A, const float* __restrict__ QinvChol,
                  const float* __restrict__ Q0invChol, float* __restrict__ cw)
{
    __shared__ float As[DZ*33], Qc[DZ*33], Q0c[DZ*33], Qi[DZ*33], T1[DZ*33];
    const int tid = threadIdx.x;
    const int i = tid >> 5, j = tid & 31;
    As[i*33+j]  = A[tid];
    Qc[i*33+j]  = QinvChol[tid];
    Q0c[i*33+j] = Q0invChol[tid];
    __syncthreads();
    float qi = 0.f, q0 = 0.f;
    for (int k = 0; k < DZ; ++k) { qi += Qc[i*33+k]*Qc[j*33+k]; q0 += Q0c[i*33+k]*Q0c[j*33+k]; }
    Qi[i*33+j] = qi;
    __syncthreads();
    float t1 = 0.f;
    for (int k = 0; k < DZ; ++k) t1 += Qi[i*33+k]*As[k*33+j];
    T1[i*33+j] = t1;
    __syncthreads();
    float aqa = 0.f, bm = 0.f;
    for (int k = 0; k < DZ; ++k) { aqa += As[k*33+i]*T1[k*33+j]; bm += As[k*33+i]*Qi[k*33+j]; }
    cw[OFF_QINV  + tid] = qi;
    cw[OFF_Q0INV + tid] = q0;
    cw[OFF_AQA   + tid] = aqa;
    cw[OFF_B     + tid] = -bm;
    cw[OFF_P0    + tid] = q0 + aqa;
    cw[OFF_PMID  + tid] = qi + aqa;
    cw[OFF_PLAST + tid] = qi;
    if (tid == 0) cw[OFF_LOGSUM] = 0.f;
}

// ---------------- split-bf16 MFMA GEMM ----------------
__device__ __forceinline__ void stage_tile(const unsigned short* src, int rowbase, int Kd,
                                           int k0, unsigned short* ldsbase, int w, int lane)
{
#pragma unroll
    for (int inst = 0; inst < 2; ++inst) {
        const int r0  = w * 32 + inst * 16;
        const int row = r0 + (lane >> 2);
        const int g   = (lane & 3) ^ ((row >> 1) & 3);
        const unsigned short* gp = src + (size_t)(rowbase + row) * Kd + k0 + g * 8;
        __builtin_amdgcn_global_load_lds(
            (const __attribute__((address_space(1))) void*)gp,
            (__attribute__((address_space(3))) void*)(ldsbase + r0 * 32),
            16, 0, 0);
    }
}

template<int OM>   // 0: f32 out, 1: (hi,lo) bf16 out
__global__ __launch_bounds__(256)
void mgemm(const unsigned short* __restrict__ Ah, const unsigned short* __restrict__ Al,
           const unsigned short* __restrict__ Wh, const unsigned short* __restrict__ Wl,
           const float* __restrict__ bias, float* __restrict__ outF,
           unsigned short* __restrict__ outH, unsigned short* __restrict__ outL,
           int N, int Kd, int relu)
{
    __shared__ unsigned short lds[2][4][4096];   // [buf][Ah,Al,Wh,Wl][128*32]
    const int tid = threadIdx.x;
    const int lane = tid & 63, w = tid >> 6;
    const int wm = w >> 1, wn = w & 1;
    const int bn = blockIdx.x, bm = blockIdx.y;
    const int ln15 = lane & 15, g4 = lane >> 4;

    f32x4 acc[4][4];
#pragma unroll
    for (int i = 0; i < 4; ++i)
#pragma unroll
        for (int j = 0; j < 4; ++j) acc[i][j] = f32x4{0.f,0.f,0.f,0.f};

    const int nt = Kd >> 5;
    stage_tile(Ah, bm*128, Kd, 0, &lds[0][0][0], w, lane);
    stage_tile(Al, bm*128, Kd, 0, &lds[0][1][0], w, lane);
    stage_tile(Wh, bn*128, Kd, 0, &lds[0][2][0], w, lane);
    stage_tile(Wl, bn*128, Kd, 0, &lds[0][3][0], w, lane);
    __syncthreads();

    int cur = 0;
    for (int t = 0; t < nt; ++t) {
        if (t + 1 < nt) {
            const int k0 = (t + 1) << 5;
            stage_tile(Ah, bm*128, Kd, k0, &lds[cur^1][0][0], w, lane);
            stage_tile(Al, bm*128, Kd, k0, &lds[cur^1][1][0], w, lane);
            stage_tile(Wh, bn*128, Kd, k0, &lds[cur^1][2][0], w, lane);
            stage_tile(Wl, bn*128, Kd, k0, &lds[cur^1][3][0], w, lane);
        }
        bf16x8 fa[4], fal[4], fwh[4], fwl[4];
#pragma unroll
        for (int fm = 0; fm < 4; ++fm) {
            const int lr = wm*64 + fm*16 + ln15;
            const int off = lr*32 + ((g4 ^ ((lr >> 1) & 3)) << 3);
            fa[fm]  = *(const bf16x8*)(&lds[cur][0][0] + off);
            fal[fm] = *(const bf16x8*)(&lds[cur][1][0] + off);
        }
#pragma unroll
        for (int fn = 0; fn < 4; ++fn) {
            const int lr = wn*64 + fn*16 + ln15;
            const int off = lr*32 + ((g4 ^ ((lr >> 1) & 3)) << 3);
            fwh[fn] = *(const bf16x8*)(&lds[cur][2][0] + off);
            fwl[fn] = *(const bf16x8*)(&lds[cur][3][0] + off);
        }
#pragma unroll
        for (int fm = 0; fm < 4; ++fm)
#pragma unroll
            for (int fn = 0; fn < 4; ++fn) {
                acc[fm][fn] = MFMA16(fa[fm],  fwh[fn], acc[fm][fn]);
                acc[fm][fn] = MFMA16(fa[fm],  fwl[fn], acc[fm][fn]);
                acc[fm][fn] = MFMA16(fal[fm], fwh[fn], acc[fm][fn]);
            }
        __syncthreads();
        cur ^= 1;
    }

#pragma unroll
    for (int fm = 0; fm < 4; ++fm)
#pragma unroll
        for (int fn = 0; fn < 4; ++fn) {
            const int col = bn*128 + wn*64 + fn*16 + ln15;
            const float bv = bias[col];
#pragma unroll
            for (int q = 0; q < 4; ++q) {
                const int row = bm*128 + wm*64 + fm*16 + g4*4 + q;
                float v = acc[fm][fn][q] + bv;
                if (relu) v = fmaxf(v, 0.f);
                if (OM == 0) {
                    outF[(size_t)row * N + col] = v;
                } else {
                    unsigned short hv = f2bf(v);
                    outH[(size_t)row * N + col] = hv;
                    outL[(size_t)row * N + col] = f2bf(v - bf2f(hv));
                }
            }
        }
}

// ---------------- small GEMM (N=32): mean = h3 @ Wm_out^T + b ----------------
__global__ __launch_bounds__(64)
void mgemm_small(const unsigned short* __restrict__ Ah, const unsigned short* __restrict__ Al,
                 const unsigned short* __restrict__ Wh, const unsigned short* __restrict__ Wl,
                 const float* __restrict__ bias, float* __restrict__ out, int Kd)
{
    const int lane = threadIdx.x;
    const int rm = blockIdx.x * 16;
    const int ln15 = lane & 15, g = lane >> 4;
    const int row = rm + ln15;
    f32x4 acc0 = {0.f,0.f,0.f,0.f}, acc1 = {0.f,0.f,0.f,0.f};
    for (int k0 = 0; k0 < Kd; k0 += 32) {
        const int k = k0 + g*8;
        bf16x8 a_h = *(const bf16x8*)(Ah + (size_t)row*Kd + k);
        bf16x8 a_l = *(const bf16x8*)(Al + (size_t)row*Kd + k);
        bf16x8 w0h = *(const bf16x8*)(Wh + (size_t)ln15*Kd + k);
        bf16x8 w0l = *(const bf16x8*)(Wl + (size_t)ln15*Kd + k);
        bf16x8 w1h = *(const bf16x8*)(Wh + (size_t)(16+ln15)*Kd + k);
        bf16x8 w1l = *(const bf16x8*)(Wl + (size_t)(16+ln15)*Kd + k);
        acc0 = MFMA16(a_h, w0h, acc0); acc0 = MFMA16(a_h, w0l, acc0); acc0 = MFMA16(a_l, w0h, acc0);
        acc1 = MFMA16(a_h, w1h, acc1); acc1 = MFMA16(a_h, w1l, acc1); acc1 = MFMA16(a_l, w1h, acc1);
    }
#pragma unroll
    for (int q = 0; q < 4; ++q) {
        const int r = rm + g*4 + q;
        out[r*DZ + ln15]      = acc0[q] + bias[ln15];
        out[r*DZ + 16 + ln15] = acc1[q] + bias[16 + ln15];
    }
}

// ---------------- build Lam, AA (in place over cov), lamMu ----------------
__global__ __launch_bounds__(256)
void build_blocks_kernel(float* __restrict__ cov, const float* __restrict__ mean,
                         float* __restrict__ lamMu, const float* __restrict__ cw)
{
    const int t = blockIdx.x, tid = threadIdx.x;
    __shared__ float R[DZ*33];
    __shared__ float Lam[DZ*33];
    __shared__ float mn[DZ];
    float* blk = cov + (size_t)t * 1024;
    {
        float4 v = ((const float4*)blk)[tid];
        const int base = tid * 4;
        const int row = base >> 5, col = base & 31;
        R[row*33 + col + 0] = v.x; R[row*33 + col + 1] = v.y;
        R[row*33 + col + 2] = v.z; R[row*33 + col + 3] = v.w;
    }
    if (tid < DZ) mn[tid] = mean[t*DZ + tid];
    __syncthreads();
    const float* P = cw + (t == 0 ? OFF_P0 : (t == TT-1 ? OFF_PLAST : OFF_PMID));
#pragma unroll
    for (int q = 0; q < 4; ++q) {
        const int idx = tid + 256*q;
        const int i = idx >> 5, j = idx & 31;
        float s = 0.f;
#pragma unroll
        for (int k = 0; k < DZ; ++k) s += R[i*33+k] * R[j*33+k];
        Lam[i*33+j] = s;
        blk[idx] = s + P[idx];
    }
    __syncthreads();
    if (tid < DZ) {
        float s = 0.f;
#pragma unroll
        for (int k = 0; k < DZ; ++k) s += Lam[tid*33+k] * mn[k];
        lamMu[t*DZ + tid] = s;
    }
}

// ---------------- chol scan v5: v4 + 2 waves/SIMD (K=4) + warm-up skips logf ----------------
// Lane c (both halves duplicate) owns column c. X^T X via 6 split-bf16 MFMA32 (A==B frag).
// D layout: col=lane&31, row=(reg&3)+8*(reg>>2)+4*(lane>>5)  [m74/m101-verified]
#define CHOL_STEP(OWNED)                                                          \
    {                                                                             \
        _Pragma("unroll")                                                         \
        for (int i = 0; i < 32; ++i) s[i] = Apre[i];                              \
        if (t + 1 < own1) {                                                       \
            const float* an = AA + (size_t)(t+1)*1024;                            \
            _Pragma("unroll")                                                     \
            for (int i = 0; i < 32; ++i) Apre[i] = an[i*32 + c];                  \
        }                                                                         \
        const bool doX = (t > t0);                                                \
        if (doX) {                                                                \
            _Pragma("unroll")                                                     \
            for (int i = 0; i < 32; ++i) u[i] = Breg[i];                          \
            _Pragma("unroll")                                                     \
            for (int r = 0; r < 32; ++r) {                                        \
                float x = u[r] * rlane(invd_own, r);                              \
                u[r] = x;                                                         \
                _Pragma("unroll")                                                 \
                for (int i = r+1; i < 32; ++i)                                    \
                    u[i] = fmaf(-rlane(Lcol[i], r), x, u[i]);                     \
            }                                                                     \
            float f0[8], f1[8];                                                   \
            _Pragma("unroll")                                                     \
            for (int j = 0; j < 8; ++j) {                                         \
                f0[j] = h ? u[8+j]  : u[j];                                       \
                f1[j] = h ? u[24+j] : u[16+j];                                    \
            }                                                                     \
            bf16x8 A0h, A0l, A1h, A1l;                                            \
            _Pragma("unroll")                                                     \
            for (int j = 0; j < 8; ++j) {                                         \
                unsigned short hh0 = f2bf(f0[j]);                                 \
                A0h[j] = (short)hh0; A0l[j] = (short)f2bf(f0[j] - bf2f(hh0));     \
                unsigned short hh1 = f2bf(f1[j]);                                 \
                A1h[j] = (short)hh1; A1l[j] = (short)f2bf(f1[j] - bf2f(hh1));     \
            }                                                                     \
            f32x16 d;                                                             \
            _Pragma("unroll")                                                     \
            for (int q = 0; q < 16; ++q) d[q] = 0.f;                              \
            d = MFMA32(A0h, A0h, d);                                              \
            d = MFMA32(A0h, A0l, d);                                              \
            d = MFMA32(A0l, A0h, d);                                              \
            d = MFMA32(A1h, A1h, d);                                              \
            d = MFMA32(A1h, A1l, d);                                              \
            d = MFMA32(A1l, A1h, d);                                              \
            float dsw[16];                                                        \
            _Pragma("unroll")                                                     \
            for (int q = 0; q < 16; ++q) dsw[q] = __shfl_xor(d[q], 32);           \
            _Pragma("unroll")                                                     \
            for (int i = 0; i < 32; ++i) {                                        \
                const int q  = (i & 3) + ((i >> 3) << 2);                         \
                const int hh = (i >> 2) & 1;                                      \
                s[i] -= (h == hh) ? d[q] : dsw[q];                                \
            }                                                                     \
        }                                                                         \
        _Pragma("unroll")                                                         \
        for (int j = 0; j < 32; ++j) {                                            \
            float sjj = rlane(s[j], j);                                           \
            float inv = __builtin_amdgcn_rsqf(sjj);                               \
            if (OWNED) logacc += __logf(sjj);                                     \
            float inv2 = inv * inv;                                               \
            float ljc = (c > j) ? s[j] * inv2 : 0.f;                              \
            invd_own = (c == j) ? inv : invd_own;                                 \
            _Pragma("unroll")                                                     \
            for (int i = j; i < 32; ++i) s[i] = fmaf(-rlane(s[i], j), ljc, s[i]); \
        }                                                                         \
        _Pragma("unroll")                                                         \
        for (int i = 0; i < 32; ++i) Lcol[i] = s[i] * invd_own;                   \
        if (OWNED) {                                                              \
            float* lt = Lg + (size_t)t*1024 + c*32 + h*16;                        \
            _Pragma("unroll")                                                     \
            for (int q = 0; q < 4; ++q) {                                         \
                float4 v4 = make_float4(h ? Lcol[16+4*q]   : Lcol[4*q],           \
                                        h ? Lcol[16+4*q+1] : Lcol[4*q+1],         \
                                        h ? Lcol[16+4*q+2] : Lcol[4*q+2],         \
                                        h ? Lcol[16+4*q+3] : Lcol[4*q+3]);        \
                *(float4*)(lt + 4*q) = v4;                                        \
            }                                                                     \
            if (doX) {                                                            \
                float* ct = Cg + (size_t)t*1024;                                  \
                _Pragma("unroll")                                                 \
                for (int rr = 0; rr < 16; ++rr) {                                 \
                    float val = h ? u[16+rr] : u[rr];                             \
                    ct[(h*16+rr)*32 + c] = val;                                   \
                }                                                                 \
            }                                                                     \
        }                                                                         \
    }

__global__ __launch_bounds__(64)
void chol_scan5(const float* __restrict__ AA, float* __restrict__ Lg,
                float* __restrict__ Cg, const float* __restrict__ cw,
                float* __restrict__ logsum, int K, int W)
{
    const int lane = threadIdx.x;
    const int c = lane & 31;
    const int h = lane >> 5;
    const int own0 = blockIdx.x * K;
    const int own1 = min(TT, own0 + K);
    const int t0 = max(0, own0 - W);

    float Breg[32], Lcol[32], s[32], u[32], Apre[32];
    float invd_own = 0.f, logacc = 0.f;

#pragma unroll
    for (int i = 0; i < 32; ++i) Breg[i] = cw[OFF_B + i*32 + c];
#pragma unroll
    for (int i = 0; i < 32; ++i) Apre[i] = AA[(size_t)t0*1024 + i*32 + c];

    for (int t = t0; t < own0; ++t) CHOL_STEP(false)    // warm-up: no logs, no stores
    for (int t = own0; t < own1; ++t) CHOL_STEP(true)   // owned steps

    if (lane == 0) atomicAdd(logsum, logacc * 0.5f);    // logs accumulated as log(d^2)
}

// ---------------- chunked forward bidiagonal solve (L col-major, C = X row-major) -------
__global__ __launch_bounds__(64)
void fwd_solve_kernel(const float* __restrict__ Lg, const float* __restrict__ Cg,
                      const float* __restrict__ bv, float* __restrict__ xout,
                      int K, int W)
{
    const int lane = threadIdx.x;
    const int r = lane & 31, h = lane >> 5;
    const int own0 = blockIdx.x * K;
    const int own1 = min(TT, own0 + K);
    const int t0 = max(0, own0 - W);
    float xprev = 0.f;
    for (int t = t0; t < own1; ++t) {
        const float* lt = Lg + (size_t)t * 1024;
        float Lr[32];                         // row r of L: L[r][j] = lt[j*32+r]
#pragma unroll
        for (int j = 0; j < DZ; ++j) Lr[j] = lt[j*32 + r];
        const float inv = __builtin_amdgcn_rcpf(Lr[r]);
        float v = bv[t*DZ + r];
        if (t > t0) {
            const float* ct = Cg + (size_t)t * 1024;
            float Cr[32];                     // C[r][cc] = X[cc][r] = ct[cc*32+r]
#pragma unroll
            for (int cc = 0; cc < DZ; ++cc) Cr[cc] = ct[cc*32 + r];
#pragma unroll
            for (int cc = 0; cc < DZ; ++cc) v = fmaf(-Cr[cc], __shfl(xprev, cc), v);
        }
        float xv = 0.f;
#pragma unroll
        for (int rr = 0; rr < DZ; ++rr) {
            float cand = v * inv;
            float xb = __shfl(cand, rr);
            if (r == rr) xv = cand;
            if (r > rr) v = fmaf(-Lr[rr], xb, v);
        }
        xprev = xv;
        if (t >= own0 && h == 0) xout[t*DZ + r] = xv;
    }
}

// ---------------- chunked backward solve (two RHS) + sample -----------------------------
__global__ __launch_bounds__(64)
void bwd_solve_kernel(const float* __restrict__ Lg, const float* __restrict__ Cg,
                      const float* __restrict__ b1, const float* __restrict__ b2,
                      float* __restrict__ outSample, int K, int W)
{
    const int lane = threadIdx.x;
    const int k = lane & 31, h = lane >> 5;
    const int own0 = blockIdx.x * K;
    const int own1 = min(TT, own0 + K);
    const int tS = min(TT - 1, own1 - 1 + W);
    float x1p = 0.f, x2p = 0.f;
    for (int t = tS; t >= own0; --t) {
        const float* lt = Lg + (size_t)t * 1024;
        float Lc[32];                         // column k of L: contiguous in col-major
#pragma unroll
        for (int q = 0; q < 8; ++q) {
            float4 v4 = *(const float4*)(lt + k*32 + 4*q);
            Lc[4*q] = v4.x; Lc[4*q+1] = v4.y; Lc[4*q+2] = v4.z; Lc[4*q+3] = v4.w;
        }
        const float inv = __builtin_amdgcn_rcpf(Lc[k]);
        float v1 = b1[t*DZ + k], v2 = b2[t*DZ + k];
        if (t < tS) {
            const float* ct = Cg + (size_t)(t+1) * 1024;
            float Cc[32];                     // C[j][k] = X[k][j] = ct[k*32+j], contiguous
#pragma unroll
            for (int q = 0; q < 8; ++q) {
                float4 w4 = *(const float4*)(ct + k*32 + 4*q);
                Cc[4*q] = w4.x; Cc[4*q+1] = w4.y; Cc[4*q+2] = w4.z; Cc[4*q+3] = w4.w;
            }
#pragma unroll
            for (int cc = 0; cc < DZ; ++cc) {
                float a1 = __shfl(x1p, cc), a2 = __shfl(x2p, cc);
                v1 = fmaf(-Cc[cc], a1, v1); v2 = fmaf(-Cc[cc], a2, v2);
            }
        }
        float x1 = 0.f, x2 = 0.f;
#pragma unroll
        for (int rr = DZ-1; rr >= 0; --rr) {
            float c1 = v1 * inv, c2 = v2 * inv;
            float xb1 = __shfl(c1, rr), xb2 = __shfl(c2, rr);
            if (k == rr) { x1 = c1; x2 = c2; }
            if (k < rr) { v1 = fmaf(-Lc[rr], xb1, v1); v2 = fmaf(-Lc[rr], xb2, v2); }
        }
        x1p = x1; x2p = x2;
        if (t >= own0 && h == 0) outSample[t*DZ + k] = x1 + x2;
    }
}

// ---------------- entropy ----------------
__global__ void finalize_kernel(const float* __restrict__ logsum, float* __restrict__ out)
{
    if (threadIdx.x == 0) {
        out[TT*DZ] = (logsum[0] - 2270.3016531274763f) / 409600.0f;
    }
}

// ---------------- launch ----------------
extern "C" void kernel_launch(void* const* d_in, const int* in_sizes, int n_in,
                              void* d_out, int out_size, void* d_ws, size_t ws_size,
                              hipStream_t stream)
{
    (void)in_sizes; (void)n_in; (void)out_size; (void)ws_size;
    const float* x        = (const float*)d_in[0];
    const float* norm     = (const float*)d_in[1];
    const float* A        = (const float*)d_in[2];
    const float* QinvChol = (const float*)d_in[3];
    const float* Q0invChol= (const float*)d_in[4];
    const float* Wm_in = (const float*)d_in[5];  const float* bm_in = (const float*)d_in[6];
    const float* Wm_h1 = (const float*)d_in[7];  const float* bm_h1 = (const float*)d_in[8];
    const float* Wm_h3 = (const float*)d_in[9];  const float* bm_h3 = (const float*)d_in[10];
    const float* Wm_out= (const float*)d_in[11]; const float* bm_out= (const float*)d_in[12];
    const float* Wc_in = (const float*)d_in[13]; const float* bc_in = (const float*)d_in[14];
    const float* Wc_h1 = (const float*)d_in[15]; const float* bc_h1 = (const float*)d_in[16];
    const float* Wc_h3 = (const float*)d_in[17]; const float* bc_h3 = (const float*)d_in[18];
    const float* Wc_out= (const float*)d_in[19]; const float* bc_out= (const float*)d_in[20];

    float* ws    = (float*)d_ws;
    float* out   = (float*)d_out;
    float* cw    = ws;
    float* Lbuf  = ws + OFF_ACT0;
    float* Cbuf  = ws + OFF_ACT1;
    float* covb  = ws + OFF_AAB;
    float* meanb = ws + OFF_MEANB;
    float* lamMu = ws + OFF_LAMMU;
    float* ib    = ws + OFF_IBV;
    float* logsum = ws + OFF_LOGSUM;

    unsigned short* a0h = (unsigned short*)(ws + OFF_ACT0); unsigned short* a0l = a0h + 8388608;
    unsigned short* a1h = (unsigned short*)(ws + OFF_ACT1); unsigned short* a1l = a1h + 8388608;
    unsigned short* xh  = (unsigned short*)(ws + OFF_XB);

    const long OWmi = OFF_WB;
    const long OWm1 = OWmi + 262144;
    const long OWm3 = OWm1 + 1048576;
    const long OWmo = OWm3 + 1048576;
    const long OWci = OWmo + 32768;
    const long OWc1 = OWci + 262144;
    const long OWc3 = OWc1 + 1048576;
    const long OWco = OWc3 + 1048576;
    #define WH(o) ((unsigned short*)(ws + (o)))
    #define WL(o, n) (((unsigned short*)(ws + (o))) + (n))

    setup_kernel<<<dim3(1), dim3(1024), 0, stream>>>(A, QinvChol, Q0invChol, cw);

    SplitArgs sa;
    sa.seg[0] = { x,      (unsigned short*)(ws + OFF_XB), 2097152 };
    sa.seg[1] = { Wm_in,  WH(OWmi), 262144 };
    sa.seg[2] = { Wm_h1,  WH(OWm1), 1048576 };
    sa.seg[3] = { Wm_h3,  WH(OWm3), 1048576 };
    sa.seg[4] = { Wm_out, WH(OWmo), 32768 };
    sa.seg[5] = { Wc_in,  WH(OWci), 262144 };
    sa.seg[6] = { Wc_h1,  WH(OWc1), 1048576 };
    sa.seg[7] = { Wc_h3,  WH(OWc3), 1048576 };
    sa.seg[8] = { Wc_out, WH(OWco), 1048576 };
    split_all<<<dim3(2048, 9), dim3(256), 0, stream>>>(sa);

    const dim3 gBig(8, 64), blk(256);
    // mean MLP
    mgemm<1><<<gBig, blk, 0, stream>>>(xh, WL(OFF_XB,2097152),  WH(OWmi), WL(OWmi,262144), bm_in, nullptr, a0h, a0l, 1024, 256, 1);
    mgemm<1><<<gBig, blk, 0, stream>>>(a0h, a0l, WH(OWm1), WL(OWm1,1048576), bm_h1, nullptr, a1h, a1l, 1024, 1024, 1);
    mgemm<1><<<gBig, blk, 0, stream>>>(a1h, a1l, WH(OWm3), WL(OWm3,1048576), bm_h3, nullptr, a0h, a0l, 1024, 1024, 1);
    mgemm_small<<<dim3(512), dim3(64), 0, stream>>>(a0h, a0l, WH(OWmo), WL(OWmo,32768), bm_out, meanb, 1024);
    // cov MLP
    mgemm<1><<<gBig, blk, 0, stream>>>(xh, WL(OFF_XB,2097152),  WH(OWci), WL(OWci,262144), bc_in, nullptr, a1h, a1l, 1024, 256, 1);
    mgemm<1><<<gBig, blk, 0, stream>>>(a1h, a1l, WH(OWc1), WL(OWc1,1048576), bc_h1, nullptr, a0h, a0l, 1024, 1024, 1);
    mgemm<1><<<gBig, blk, 0, stream>>>(a0h, a0l, WH(OWc3), WL(OWc3,1048576), bc_h3, nullptr, a1h, a1l, 1024, 1024, 1);
    mgemm<0><<<gBig, blk, 0, stream>>>(a1h, a1l, WH(OWco), WL(OWco,1048576), bc_out, covb, nullptr, nullptr, 1024, 1024, 0);

    build_blocks_kernel<<<dim3(TT), dim3(256), 0, stream>>>(covb, meanb, lamMu, cw);

    // chunked scan phases (K = chunk len, W = warm-up len)
    chol_scan5<<<dim3(TT/4), dim3(64), 0, stream>>>(covb, Lbuf, Cbuf, cw, logsum, 4, 16);
    fwd_solve_kernel<<<dim3(TT/4), dim3(64), 0, stream>>>(Lbuf, Cbuf, lamMu, ib, 4, 32);
    bwd_solve_kernel<<<dim3(TT/4), dim3(64), 0, stream>>>(Lbuf, Cbuf, ib, norm, out, 4, 32);

    finalize_kernel<<<dim3(1), dim3(64), 0, stream>>>(logsum, out);
}

// Round 6
// 733.988 us; speedup vs baseline: 7.2585x; 1.1347x over previous
//
#include <hip/hip_runtime.h>
#include <math.h>

#define TT 8192
#define DZ 32

typedef short bf16x8 __attribute__((ext_vector_type(8)));
typedef _Float16 f16x8 __attribute__((ext_vector_type(8)));
typedef _Float16 f16x4 __attribute__((ext_vector_type(4)));
typedef float f32x4 __attribute__((ext_vector_type(4)));
typedef float f32x16 __attribute__((ext_vector_type(16)));
#define MFMA16F(a,b,c) __builtin_amdgcn_mfma_f32_16x16x32_f16(a,b,c,0,0,0)
#define MFMA32(a,b,c) __builtin_amdgcn_mfma_f32_32x32x16_bf16(a,b,c,0,0,0)

// ---------------- workspace layout (float units) ----------------
#define OFF_QINV   0
#define OFF_Q0INV  1024
#define OFF_AQA    2048
#define OFF_B      3072
#define OFF_P0     4096
#define OFF_PMID   5120
#define OFF_PLAST  6144
#define OFF_LOGSUM 7168
#define OFF_ACT0   8192                     // act slot0 (f16) -> later L (f32, col-major per t)
#define OFF_ACT1   (OFF_ACT0 + 8388608)     // act slot1 (f16) -> later C (f32, X row-major per t)
#define OFF_AAB    (OFF_ACT1 + 8388608)     // cov f32 -> AA in place
#define OFF_XB     (OFF_AAB + 8388608)      // x f16
#define OFF_WB     (OFF_XB + 2097152)       // weights f16 (hi, lo*2^10)
#define OFF_MEANB  (OFF_WB + 5799936)
#define OFF_LAMMU  (OFF_MEANB + 262144)
#define OFF_IBV    (OFF_LAMMU + 262144)

__device__ __forceinline__ unsigned short f2bf(float f) {
    unsigned int u = __float_as_uint(f);
    u += 0x7FFFu + ((u >> 16) & 1u);
    return (unsigned short)(u >> 16);
}
__device__ __forceinline__ float bf2f(unsigned short h) {
    return __uint_as_float(((unsigned int)h) << 16);
}
__device__ __forceinline__ float rlane(float v, int l) {
    return __uint_as_float(__builtin_amdgcn_readlane(__float_as_uint(v), l));
}

// ---------------- fused f32 -> f16 (acts) / f16-pair with scaled lo (weights) ----------------
struct SplitSeg { const float* src; _Float16* hi; _Float16* lo; int n; };
struct SplitArgs { SplitSeg seg[9]; };

__global__ __launch_bounds__(256)
void split_all(SplitArgs a)
{
    const SplitSeg sg = a.seg[blockIdx.y];
    const int n4 = sg.n >> 2;
    int i = blockIdx.x * 256 + threadIdx.x;
    if (i >= n4) return;
    float4 v = ((const float4*)sg.src)[i];
    f16x4 hh;
    hh[0] = (_Float16)v.x; hh[1] = (_Float16)v.y;
    hh[2] = (_Float16)v.z; hh[3] = (_Float16)v.w;
    ((f16x4*)sg.hi)[i] = hh;
    if (sg.lo) {
        f16x4 ll;
        ll[0] = (_Float16)((v.x - (float)hh[0]) * 1024.f);
        ll[1] = (_Float16)((v.y - (float)hh[1]) * 1024.f);
        ll[2] = (_Float16)((v.z - (float)hh[2]) * 1024.f);
        ll[3] = (_Float16)((v.w - (float)hh[3]) * 1024.f);
        ((f16x4*)sg.lo)[i] = ll;
    }
}

// ---------------- setup: Qinv, Q0inv, AQA, B, priors ----------------
__global__ __launch_bounds__(1024)
void setup_kernel(const float* __restrict__ A, const float* __restrict__ QinvChol,
                  const float* __restrict__ Q0invChol, float* __restrict__ cw)
{
    __shared__ float As[DZ*33], Qc[DZ*33], Q0c[DZ*33], Qi[DZ*33], T1[DZ*33];
    const int tid = threadIdx.x;
    const int i = tid >> 5, j = tid & 31;
    As[i*33+j]  = A[tid];
    Qc[i*33+j]  = QinvChol[tid];
    Q0c[i*33+j] = Q0invChol[tid];
    __syncthreads();
    float qi = 0.f, q0 = 0.f;
    for (int k = 0; k < DZ; ++k) { qi += Qc[i*33+k]*Qc[j*33+k]; q0 += Q0c[i*33+k]*Q0c[j*33+k]; }
    Qi[i*33+j] = qi;
    __syncthreads();
    float t1 = 0.f;
    for (int k = 0; k < DZ; ++k) t1 += Qi[i*33+k]*As[k*33+j];
    T1[i*33+j] = t1;
    __syncthreads();
    float aqa = 0.f, bm = 0.f;
    for (int k = 0; k < DZ; ++k) { aqa += As[k*33+i]*T1[k*33+j]; bm += As[k*33+i]*Qi[k*33+j]; }
    cw[OFF_QINV  + tid] = qi;
    cw[OFF_Q0INV + tid] = q0;
    cw[OFF_AQA   + tid] = aqa;
    cw[OFF_B     + tid] = -bm;
    cw[OFF_P0    + tid] = q0 + aqa;
    cw[OFF_PMID  + tid] = qi + aqa;
    cw[OFF_PLAST + tid] = qi;
    if (tid == 0) cw[OFF_LOGSUM] = 0.f;
}

// ---------------- split-f16 MFMA GEMM: C = act(A @ W^T + b) ----------------
// A single f16 (rel err 2^-12); W = wh + wl'*2^-10 (wl' normal-range f16).
// acc = mfma(a, wh) + mfma(a*2^-10, wl')  -- 2 MFMAs, one accumulator.
__device__ __forceinline__ void stage_tile(const _Float16* src, int rowbase, int Kd,
                                           int k0, _Float16* ldsbase, int w, int lane)
{
#pragma unroll
    for (int inst = 0; inst < 2; ++inst) {
        const int r0  = w * 32 + inst * 16;
        const int row = r0 + (lane >> 2);
        const int g   = (lane & 3) ^ ((row >> 1) & 3);
        const _Float16* gp = src + (size_t)(rowbase + row) * Kd + k0 + g * 8;
        __builtin_amdgcn_global_load_lds(
            (const __attribute__((address_space(1))) void*)gp,
            (__attribute__((address_space(3))) void*)(ldsbase + r0 * 32),
            16, 0, 0);
    }
}

template<int OM>   // 0: f32 out, 1: f16 out
__global__ __launch_bounds__(256)
void mgemm(const _Float16* __restrict__ Ah, const _Float16* __restrict__ Wh,
           const _Float16* __restrict__ Wl, const float* __restrict__ bias,
           float* __restrict__ outF, _Float16* __restrict__ outH,
           int N, int Kd, int relu)
{
    __shared__ _Float16 lds[2][3][4096];   // [buf][Ah,Wh,Wl][128*32]  (48 KB -> 3 blocks/CU)
    const int tid = threadIdx.x;
    const int lane = tid & 63, w = tid >> 6;
    const int wm = w >> 1, wn = w & 1;
    const int bn = blockIdx.x, bm = blockIdx.y;
    const int ln15 = lane & 15, g4 = lane >> 4;

    f32x4 acc[4][4];
#pragma unroll
    for (int i = 0; i < 4; ++i)
#pragma unroll
        for (int j = 0; j < 4; ++j) acc[i][j] = f32x4{0.f,0.f,0.f,0.f};

    const int nt = Kd >> 5;
    stage_tile(Ah, bm*128, Kd, 0, &lds[0][0][0], w, lane);
    stage_tile(Wh, bn*128, Kd, 0, &lds[0][1][0], w, lane);
    stage_tile(Wl, bn*128, Kd, 0, &lds[0][2][0], w, lane);
    __syncthreads();

    const _Float16 sc = (_Float16)0.0009765625f;   // 2^-10
    int cur = 0;
    for (int t = 0; t < nt; ++t) {
        if (t + 1 < nt) {
            const int k0 = (t + 1) << 5;
            stage_tile(Ah, bm*128, Kd, k0, &lds[cur^1][0][0], w, lane);
            stage_tile(Wh, bn*128, Kd, k0, &lds[cur^1][1][0], w, lane);
            stage_tile(Wl, bn*128, Kd, k0, &lds[cur^1][2][0], w, lane);
        }
        f16x8 fa[4], fas[4], fwh[4], fwl[4];
#pragma unroll
        for (int fm = 0; fm < 4; ++fm) {
            const int lr = wm*64 + fm*16 + ln15;
            const int off = lr*32 + ((g4 ^ ((lr >> 1) & 3)) << 3);
            fa[fm]  = *(const f16x8*)(&lds[cur][0][0] + off);
            fas[fm] = fa[fm] * sc;
        }
#pragma unroll
        for (int fn = 0; fn < 4; ++fn) {
            const int lr = wn*64 + fn*16 + ln15;
            const int off = lr*32 + ((g4 ^ ((lr >> 1) & 3)) << 3);
            fwh[fn] = *(const f16x8*)(&lds[cur][1][0] + off);
            fwl[fn] = *(const f16x8*)(&lds[cur][2][0] + off);
        }
#pragma unroll
        for (int fm = 0; fm < 4; ++fm)
#pragma unroll
            for (int fn = 0; fn < 4; ++fn) {
                acc[fm][fn] = MFMA16F(fa[fm],  fwh[fn], acc[fm][fn]);
                acc[fm][fn] = MFMA16F(fas[fm], fwl[fn], acc[fm][fn]);
            }
        __syncthreads();
        cur ^= 1;
    }

    // epilogue: C/D layout col=lane&15, row=(lane>>4)*4+q  [m89-verified]
#pragma unroll
    for (int fm = 0; fm < 4; ++fm)
#pragma unroll
        for (int fn = 0; fn < 4; ++fn) {
            const int col = bn*128 + wn*64 + fn*16 + ln15;
            const float bv = bias[col];
#pragma unroll
            for (int q = 0; q < 4; ++q) {
                const int row = bm*128 + wm*64 + fm*16 + g4*4 + q;
                float v = acc[fm][fn][q] + bv;
                if (relu) v = fmaxf(v, 0.f);
                if (OM == 0) outF[(size_t)row * N + col] = v;
                else         outH[(size_t)row * N + col] = (_Float16)v;
            }
        }
}

// ---------------- small GEMM (N=32): mean = h3 @ Wm_out^T + b ----------------
__global__ __launch_bounds__(64)
void mgemm_small(const _Float16* __restrict__ Ah, const _Float16* __restrict__ Wh,
                 const _Float16* __restrict__ Wl, const float* __restrict__ bias,
                 float* __restrict__ out, int Kd)
{
    const int lane = threadIdx.x;
    const int rm = blockIdx.x * 16;
    const int ln15 = lane & 15, g = lane >> 4;
    const int row = rm + ln15;
    const _Float16 sc = (_Float16)0.0009765625f;
    f32x4 acc0 = {0.f,0.f,0.f,0.f}, acc1 = {0.f,0.f,0.f,0.f};
    for (int k0 = 0; k0 < Kd; k0 += 32) {
        const int k = k0 + g*8;
        f16x8 a  = *(const f16x8*)(Ah + (size_t)row*Kd + k);
        f16x8 as = a * sc;
        f16x8 w0h = *(const f16x8*)(Wh + (size_t)ln15*Kd + k);
        f16x8 w0l = *(const f16x8*)(Wl + (size_t)ln15*Kd + k);
        f16x8 w1h = *(const f16x8*)(Wh + (size_t)(16+ln15)*Kd + k);
        f16x8 w1l = *(const f16x8*)(Wl + (size_t)(16+ln15)*Kd + k);
        acc0 = MFMA16F(a, w0h, acc0); acc0 = MFMA16F(as, w0l, acc0);
        acc1 = MFMA16F(a, w1h, acc1); acc1 = MFMA16F(as, w1l, acc1);
    }
#pragma unroll
    for (int q = 0; q < 4; ++q) {
        const int r = rm + g*4 + q;
        out[r*DZ + ln15]      = acc0[q] + bias[ln15];
        out[r*DZ + 16 + ln15] = acc1[q] + bias[16 + ln15];
    }
}

// ---------------- build Lam, AA (in place over cov), lamMu ----------------
__global__ __launch_bounds__(256)
void build_blocks_kernel(float* __restrict__ cov, const float* __restrict__ mean,
                         float* __restrict__ lamMu, const float* __restrict__ cw)
{
    const int t = blockIdx.x, tid = threadIdx.x;
    __shared__ float R[DZ*33];
    __shared__ float Lam[DZ*33];
    __shared__ float mn[DZ];
    float* blk = cov + (size_t)t * 1024;
    {
        float4 v = ((const float4*)blk)[tid];
        const int base = tid * 4;
        const int row = base >> 5, col = base & 31;
        R[row*33 + col + 0] = v.x; R[row*33 + col + 1] = v.y;
        R[row*33 + col + 2] = v.z; R[row*33 + col + 3] = v.w;
    }
    if (tid < DZ) mn[tid] = mean[t*DZ + tid];
    __syncthreads();
    const float* P = cw + (t == 0 ? OFF_P0 : (t == TT-1 ? OFF_PLAST : OFF_PMID));
#pragma unroll
    for (int q = 0; q < 4; ++q) {
        const int idx = tid + 256*q;
        const int i = idx >> 5, j = idx & 31;
        float s = 0.f;
#pragma unroll
        for (int k = 0; k < DZ; ++k) s += R[i*33+k] * R[j*33+k];
        Lam[i*33+j] = s;
        blk[idx] = s + P[idx];
    }
    __syncthreads();
    if (tid < DZ) {
        float s = 0.f;
#pragma unroll
        for (int k = 0; k < DZ; ++k) s += Lam[tid*33+k] * mn[k];
        lamMu[t*DZ + tid] = s;
    }
}

// ---------------- chol scan v5 (unchanged): registers + readlane + MFMA32 X^T X ----------
__device__ __forceinline__ unsigned short f2bf_c(float f) { return f2bf(f); }

#define CHOL_STEP(OWNED)                                                          \
    {                                                                             \
        _Pragma("unroll")                                                         \
        for (int i = 0; i < 32; ++i) s[i] = Apre[i];                              \
        if (t + 1 < own1) {                                                       \
            const float* an = AA + (size_t)(t+1)*1024;                            \
            _Pragma("unroll")                                                     \
            for (int i = 0; i < 32; ++i) Apre[i] = an[i*32 + c];                  \
        }                                                                         \
        const bool doX = (t > t0);                                                \
        if (doX) {                                                                \
            _Pragma("unroll")                                                     \
            for (int i = 0; i < 32; ++i) u[i] = Breg[i];                          \
            _Pragma("unroll")                                                     \
            for (int r = 0; r < 32; ++r) {                                        \
                float x = u[r] * rlane(invd_own, r);                              \
                u[r] = x;                                                         \
                _Pragma("unroll")                                                 \
                for (int i = r+1; i < 32; ++i)                                    \
                    u[i] = fmaf(-rlane(Lcol[i], r), x, u[i]);                     \
            }                                                                     \
            float f0[8], f1[8];                                                   \
            _Pragma("unroll")                                                     \
            for (int j = 0; j < 8; ++j) {                                         \
                f0[j] = h ? u[8+j]  : u[j];                                       \
                f1[j] = h ? u[24+j] : u[16+j];                                    \
            }                                                                     \
            bf16x8 A0h, A0l, A1h, A1l;                                            \
            _Pragma("unroll")                                                     \
            for (int j = 0; j < 8; ++j) {                                         \
                unsigned short hh0 = f2bf_c(f0[j]);                               \
                A0h[j] = (short)hh0; A0l[j] = (short)f2bf_c(f0[j] - bf2f(hh0));   \
                unsigned short hh1 = f2bf_c(f1[j]);                               \
                A1h[j] = (short)hh1; A1l[j] = (short)f2bf_c(f1[j] - bf2f(hh1));   \
            }                                                                     \
            f32x16 d;                                                             \
            _Pragma("unroll")                                                     \
            for (int q = 0; q < 16; ++q) d[q] = 0.f;                              \
            d = MFMA32(A0h, A0h, d);                                              \
            d = MFMA32(A0h, A0l, d);                                              \
            d = MFMA32(A0l, A0h, d);                                              \
            d = MFMA32(A1h, A1h, d);                                              \
            d = MFMA32(A1h, A1l, d);                                              \
            d = MFMA32(A1l, A1h, d);                                              \
            float dsw[16];                                                        \
            _Pragma("unroll")                                                     \
            for (int q = 0; q < 16; ++q) dsw[q] = __shfl_xor(d[q], 32);           \
            _Pragma("unroll")                                                     \
            for (int i = 0; i < 32; ++i) {                                        \
                const int q  = (i & 3) + ((i >> 3) << 2);                         \
                const int hh = (i >> 2) & 1;                                      \
                s[i] -= (h == hh) ? d[q] : dsw[q];                                \
            }                                                                     \
        }                                                                         \
        _Pragma("unroll")                                                         \
        for (int j = 0; j < 32; ++j) {                                            \
            float sjj = rlane(s[j], j);                                           \
            float inv = __builtin_amdgcn_rsqf(sjj);                               \
            if (OWNED) logacc += __logf(sjj);                                     \
            float inv2 = inv * inv;                                               \
            float ljc = (c > j) ? s[j] * inv2 : 0.f;                              \
            invd_own = (c == j) ? inv : invd_own;                                 \
            _Pragma("unroll")                                                     \
            for (int i = j; i < 32; ++i) s[i] = fmaf(-rlane(s[i], j), ljc, s[i]); \
        }                                                                         \
        _Pragma("unroll")                                                         \
        for (int i = 0; i < 32; ++i) Lcol[i] = s[i] * invd_own;                   \
        if (OWNED) {                                                              \
            float* lt = Lg + (size_t)t*1024 + c*32 + h*16;                        \
            _Pragma("unroll")                                                     \
            for (int q = 0; q < 4; ++q) {                                         \
                float4 v4 = make_float4(h ? Lcol[16+4*q]   : Lcol[4*q],           \
                                        h ? Lcol[16+4*q+1] : Lcol[4*q+1],         \
                                        h ? Lcol[16+4*q+2] : Lcol[4*q+2],         \
                                        h ? Lcol[16+4*q+3] : Lcol[4*q+3]);        \
                *(float4*)(lt + 4*q) = v4;                                        \
            }                                                                     \
            if (doX) {                                                            \
                float* ct = Cg + (size_t)t*1024;                                  \
                _Pragma("unroll")                                                 \
                for (int rr = 0; rr < 16; ++rr) {                                 \
                    float val = h ? u[16+rr] : u[rr];                             \
                    ct[(h*16+rr)*32 + c] = val;                                   \
                }                                                                 \
            }                                                                     \
        }                                                                         \
    }

__global__ __launch_bounds__(64)
void chol_scan5(const float* __restrict__ AA, float* __restrict__ Lg,
                float* __restrict__ Cg, const float* __restrict__ cw,
                float* __restrict__ logsum, int K, int W)
{
    const int lane = threadIdx.x;
    const int c = lane & 31;
    const int h = lane >> 5;
    const int own0 = blockIdx.x * K;
    const int own1 = min(TT, own0 + K);
    const int t0 = max(0, own0 - W);

    float Breg[32], Lcol[32], s[32], u[32], Apre[32];
    float invd_own = 0.f, logacc = 0.f;

#pragma unroll
    for (int i = 0; i < 32; ++i) Breg[i] = cw[OFF_B + i*32 + c];
#pragma unroll
    for (int i = 0; i < 32; ++i) Apre[i] = AA[(size_t)t0*1024 + i*32 + c];

    for (int t = t0; t < own0; ++t) CHOL_STEP(false)
    for (int t = own0; t < own1; ++t) CHOL_STEP(true)

    if (lane == 0) atomicAdd(logsum, logacc * 0.5f);
}

// ---------------- chunked forward bidiagonal solve (L col-major, C = X row-major) -------
__global__ __launch_bounds__(64)
void fwd_solve_kernel(const float* __restrict__ Lg, const float* __restrict__ Cg,
                      const float* __restrict__ bv, float* __restrict__ xout,
                      int K, int W)
{
    const int lane = threadIdx.x;
    const int r = lane & 31, h = lane >> 5;
    const int own0 = blockIdx.x * K;
    const int own1 = min(TT, own0 + K);
    const int t0 = max(0, own0 - W);
    float xprev = 0.f;
    for (int t = t0; t < own1; ++t) {
        const float* lt = Lg + (size_t)t * 1024;
        float Lr[32];
#pragma unroll
        for (int j = 0; j < DZ; ++j) Lr[j] = lt[j*32 + r];
        const float inv = __builtin_amdgcn_rcpf(Lr[r]);
        float v = bv[t*DZ + r];
        if (t > t0) {
            const float* ct = Cg + (size_t)t * 1024;
            float Cr[32];
#pragma unroll
            for (int cc = 0; cc < DZ; ++cc) Cr[cc] = ct[cc*32 + r];
#pragma unroll
            for (int cc = 0; cc < DZ; ++cc) v = fmaf(-Cr[cc], __shfl(xprev, cc), v);
        }
        float xv = 0.f;
#pragma unroll
        for (int rr = 0; rr < DZ; ++rr) {
            float cand = v * inv;
            float xb = __shfl(cand, rr);
            if (r == rr) xv = cand;
            if (r > rr) v = fmaf(-Lr[rr], xb, v);
        }
        xprev = xv;
        if (t >= own0 && h == 0) xout[t*DZ + r] = xv;
    }
}

// ---------------- chunked backward solve (two RHS) + sample -----------------------------
__global__ __launch_bounds__(64)
void bwd_solve_kernel(const float* __restrict__ Lg, const float* __restrict__ Cg,
                      const float* __restrict__ b1, const float* __restrict__ b2,
                      float* __restrict__ outSample, int K, int W)
{
    const int lane = threadIdx.x;
    const int k = lane & 31, h = lane >> 5;
    const int own0 = blockIdx.x * K;
    const int own1 = min(TT, own0 + K);
    const int tS = min(TT - 1, own1 - 1 + W);
    float x1p = 0.f, x2p = 0.f;
    for (int t = tS; t >= own0; --t) {
        const float* lt = Lg + (size_t)t * 1024;
        float Lc[32];
#pragma unroll
        for (int q = 0; q < 8; ++q) {
            float4 v4 = *(const float4*)(lt + k*32 + 4*q);
            Lc[4*q] = v4.x; Lc[4*q+1] = v4.y; Lc[4*q+2] = v4.z; Lc[4*q+3] = v4.w;
        }
        const float inv = __builtin_amdgcn_rcpf(Lc[k]);
        float v1 = b1[t*DZ + k], v2 = b2[t*DZ + k];
        if (t < tS) {
            const float* ct = Cg + (size_t)(t+1) * 1024;
            float Cc[32];
#pragma unroll
            for (int q = 0; q < 8; ++q) {
                float4 w4 = *(const float4*)(ct + k*32 + 4*q);
                Cc[4*q] = w4.x; Cc[4*q+1] = w4.y; Cc[4*q+2] = w4.z; Cc[4*q+3] = w4.w;
            }
#pragma unroll
            for (int cc = 0; cc < DZ; ++cc) {
                float a1 = __shfl(x1p, cc), a2 = __shfl(x2p, cc);
                v1 = fmaf(-Cc[cc], a1, v1); v2 = fmaf(-Cc[cc], a2, v2);
            }
        }
        float x1 = 0.f, x2 = 0.f;
#pragma unroll
        for (int rr = DZ-1; rr >= 0; --rr) {
            float c1 = v1 * inv, c2 = v2 * inv;
            float xb1 = __shfl(c1, rr), xb2 = __shfl(c2, rr);
            if (k == rr) { x1 = c1; x2 = c2; }
            if (k < rr) { v1 = fmaf(-Lc[rr], xb1, v1); v2 = fmaf(-Lc[rr], xb2, v2); }
        }
        x1p = x1; x2p = x2;
        if (t >= own0 && h == 0) outSample[t*DZ + k] = x1 + x2;
    }
}

// ---------------- entropy ----------------
__global__ void finalize_kernel(const float* __restrict__ logsum, float* __restrict__ out)
{
    if (threadIdx.x == 0) {
        out[TT*DZ] = (logsum[0] - 2270.3016531274763f) / 409600.0f;
    }
}

// ---------------- launch ----------------
extern "C" void kernel_launch(void* const* d_in, const int* in_sizes, int n_in,
                              void* d_out, int out_size, void* d_ws, size_t ws_size,
                              hipStream_t stream)
{
    (void)in_sizes; (void)n_in; (void)out_size; (void)ws_size;
    const float* x        = (const float*)d_in[0];
    const float* norm     = (const float*)d_in[1];
    const float* A        = (const float*)d_in[2];
    const float* QinvChol = (const float*)d_in[3];
    const float* Q0invChol= (const float*)d_in[4];
    const float* Wm_in = (const float*)d_in[5];  const float* bm_in = (const float*)d_in[6];
    const float* Wm_h1 = (const float*)d_in[7];  const float* bm_h1 = (const float*)d_in[8];
    const float* Wm_h3 = (const float*)d_in[9];  const float* bm_h3 = (const float*)d_in[10];
    const float* Wm_out= (const float*)d_in[11]; const float* bm_out= (const float*)d_in[12];
    const float* Wc_in = (const float*)d_in[13]; const float* bc_in = (const float*)d_in[14];
    const float* Wc_h1 = (const float*)d_in[15]; const float* bc_h1 = (const float*)d_in[16];
    const float* Wc_h3 = (const float*)d_in[17]; const float* bc_h3 = (const float*)d_in[18];
    const float* Wc_out= (const float*)d_in[19]; const float* bc_out= (const float*)d_in[20];

    float* ws    = (float*)d_ws;
    float* out   = (float*)d_out;
    float* cw    = ws;
    float* Lbuf  = ws + OFF_ACT0;
    float* Cbuf  = ws + OFF_ACT1;
    float* covb  = ws + OFF_AAB;
    float* meanb = ws + OFF_MEANB;
    float* lamMu = ws + OFF_LAMMU;
    float* ib    = ws + OFF_IBV;
    float* logsum = ws + OFF_LOGSUM;

    _Float16* a0h = (_Float16*)(ws + OFF_ACT0);
    _Float16* a1h = (_Float16*)(ws + OFF_ACT1);
    _Float16* xh  = (_Float16*)(ws + OFF_XB);

    const long OWmi = OFF_WB;
    const long OWm1 = OWmi + 262144;
    const long OWm3 = OWm1 + 1048576;
    const long OWmo = OWm3 + 1048576;
    const long OWci = OWmo + 32768;
    const long OWc1 = OWci + 262144;
    const long OWc3 = OWc1 + 1048576;
    const long OWco = OWc3 + 1048576;
    #define WH(o) ((_Float16*)(ws + (o)))
    #define WL(o, n) (((_Float16*)(ws + (o))) + (n))

    setup_kernel<<<dim3(1), dim3(1024), 0, stream>>>(A, QinvChol, Q0invChol, cw);

    SplitArgs sa;
    sa.seg[0] = { x,      xh,       nullptr,            2097152 };
    sa.seg[1] = { Wm_in,  WH(OWmi), WL(OWmi,262144),    262144 };
    sa.seg[2] = { Wm_h1,  WH(OWm1), WL(OWm1,1048576),   1048576 };
    sa.seg[3] = { Wm_h3,  WH(OWm3), WL(OWm3,1048576),   1048576 };
    sa.seg[4] = { Wm_out, WH(OWmo), WL(OWmo,32768),     32768 };
    sa.seg[5] = { Wc_in,  WH(OWci), WL(OWci,262144),    262144 };
    sa.seg[6] = { Wc_h1,  WH(OWc1), WL(OWc1,1048576),   1048576 };
    sa.seg[7] = { Wc_h3,  WH(OWc3), WL(OWc3,1048576),   1048576 };
    sa.seg[8] = { Wc_out, WH(OWco), WL(OWco,1048576),   1048576 };
    split_all<<<dim3(2048, 9), dim3(256), 0, stream>>>(sa);

    const dim3 gBig(8, 64), blk(256);
    // mean MLP
    mgemm<1><<<gBig, blk, 0, stream>>>(xh,  WH(OWmi), WL(OWmi,262144),  bm_in, nullptr, a0h, 1024, 256, 1);
    mgemm<1><<<gBig, blk, 0, stream>>>(a0h, WH(OWm1), WL(OWm1,1048576), bm_h1, nullptr, a1h, 1024, 1024, 1);
    mgemm<1><<<gBig, blk, 0, stream>>>(a1h, WH(OWm3), WL(OWm3,1048576), bm_h3, nullptr, a0h, 1024, 1024, 1);
    mgemm_small<<<dim3(512), dim3(64), 0, stream>>>(a0h, WH(OWmo), WL(OWmo,32768), bm_out, meanb, 1024);
    // cov MLP
    mgemm<1><<<gBig, blk, 0, stream>>>(xh,  WH(OWci), WL(OWci,262144),  bc_in, nullptr, a1h, 1024, 256, 1);
    mgemm<1><<<gBig, blk, 0, stream>>>(a1h, WH(OWc1), WL(OWc1,1048576), bc_h1, nullptr, a0h, 1024, 1024, 1);
    mgemm<1><<<gBig, blk, 0, stream>>>(a0h, WH(OWc3), WL(OWc3,1048576), bc_h3, nullptr, a1h, 1024, 1024, 1);
    mgemm<0><<<gBig, blk, 0, stream>>>(a1h, WH(OWco), WL(OWco,1048576), bc_out, covb, nullptr, 1024, 1024, 0);

    build_blocks_kernel<<<dim3(TT), dim3(256), 0, stream>>>(covb, meanb, lamMu, cw);

    chol_scan5<<<dim3(TT/4), dim3(64), 0, stream>>>(covb, Lbuf, Cbuf, cw, logsum, 4, 16);
    fwd_solve_kernel<<<dim3(TT/4), dim3(64), 0, stream>>>(Lbuf, Cbuf, lamMu, ib, 4, 32);
    bwd_solve_kernel<<<dim3(TT/4), dim3(64), 0, stream>>>(Lbuf, Cbuf, ib, norm, out, 4, 32);

    finalize_kernel<<<dim3(1), dim3(64), 0, stream>>>(logsum, out);
}

// Round 7
// 526.573 us; speedup vs baseline: 10.1176x; 1.3939x over previous
//
#include <hip/hip_runtime.h>
#include <math.h>

#define TT 8192
#define DZ 32

typedef short bf16x8 __attribute__((ext_vector_type(8)));
typedef _Float16 f16x8 __attribute__((ext_vector_type(8)));
typedef _Float16 f16x4 __attribute__((ext_vector_type(4)));
typedef float f32x4 __attribute__((ext_vector_type(4)));
typedef float f32x16 __attribute__((ext_vector_type(16)));
#define MFMA16F(a,b,c) __builtin_amdgcn_mfma_f32_16x16x32_f16(a,b,c,0,0,0)
#define MFMA32(a,b,c) __builtin_amdgcn_mfma_f32_32x32x16_bf16(a,b,c,0,0,0)

// ---------------- workspace layout (float units) ----------------
#define OFF_QINV   0
#define OFF_Q0INV  1024
#define OFF_AQA    2048
#define OFF_B      3072
#define OFF_P0     4096
#define OFF_PMID   5120
#define OFF_PLAST  6144
#define OFF_LOGSUM 7168
#define OFF_ACT0   8192                     // act slot0 (f16) -> later L (f32, col-major per t)
#define OFF_ACT1   (OFF_ACT0 + 8388608)     // act slot1 (f16) -> later C (f32, X row-major per t)
#define OFF_AAB    (OFF_ACT1 + 8388608)     // cov f32 -> AA in place
#define OFF_XB     (OFF_AAB + 8388608)      // x f16
#define OFF_WB     (OFF_XB + 2097152)       // weights f16
#define OFF_MEANB  (OFF_WB + 5799936)
#define OFF_LAMMU  (OFF_MEANB + 262144)
#define OFF_IBV    (OFF_LAMMU + 262144)

__device__ __forceinline__ unsigned short f2bf(float f) {
    unsigned int u = __float_as_uint(f);
    u += 0x7FFFu + ((u >> 16) & 1u);
    return (unsigned short)(u >> 16);
}
__device__ __forceinline__ float bf2f(unsigned short h) {
    return __uint_as_float(((unsigned int)h) << 16);
}
__device__ __forceinline__ float rlane(float v, int l) {
    return __uint_as_float(__builtin_amdgcn_readlane(__float_as_uint(v), l));
}

// ---------------- fused f32 -> f16 conversion (all tensors, 1 launch) ----------------
struct SplitSeg { const float* src; _Float16* hi; int n; };
struct SplitArgs { SplitSeg seg[9]; };

__global__ __launch_bounds__(256)
void split_all(SplitArgs a)
{
    const SplitSeg sg = a.seg[blockIdx.y];
    const int n4 = sg.n >> 2;
    int i = blockIdx.x * 256 + threadIdx.x;
    if (i >= n4) return;
    float4 v = ((const float4*)sg.src)[i];
    f16x4 hh;
    hh[0] = (_Float16)v.x; hh[1] = (_Float16)v.y;
    hh[2] = (_Float16)v.z; hh[3] = (_Float16)v.w;
    ((f16x4*)sg.hi)[i] = hh;
}

// ---------------- setup: Qinv, Q0inv, AQA, B, priors ----------------
__global__ __launch_bounds__(1024)
void setup_kernel(const float* __restrict__ A, const float* __restrict__ QinvChol,
                  const float* __restrict__ Q0invChol, float* __restrict__ cw)
{
    __shared__ float As[DZ*33], Qc[DZ*33], Q0c[DZ*33], Qi[DZ*33], T1[DZ*33];
    const int tid = threadIdx.x;
    const int i = tid >> 5, j = tid & 31;
    As[i*33+j]  = A[tid];
    Qc[i*33+j]  = QinvChol[tid];
    Q0c[i*33+j] = Q0invChol[tid];
    __syncthreads();
    float qi = 0.f, q0 = 0.f;
    for (int k = 0; k < DZ; ++k) { qi += Qc[i*33+k]*Qc[j*33+k]; q0 += Q0c[i*33+k]*Q0c[j*33+k]; }
    Qi[i*33+j] = qi;
    __syncthreads();
    float t1 = 0.f;
    for (int k = 0; k < DZ; ++k) t1 += Qi[i*33+k]*As[k*33+j];
    T1[i*33+j] = t1;
    __syncthreads();
    float aqa = 0.f, bm = 0.f;
    for (int k = 0; k < DZ; ++k) { aqa += As[k*33+i]*T1[k*33+j]; bm += As[k*33+i]*Qi[k*33+j]; }
    cw[OFF_QINV  + tid] = qi;
    cw[OFF_Q0INV + tid] = q0;
    cw[OFF_AQA   + tid] = aqa;
    cw[OFF_B     + tid] = -bm;
    cw[OFF_P0    + tid] = q0 + aqa;
    cw[OFF_PMID  + tid] = qi + aqa;
    cw[OFF_PLAST + tid] = qi;
    if (tid == 0) cw[OFF_LOGSUM] = 0.f;
}

// ---------------- f16 MFMA GEMM: C = act(A @ W^T + b) ----------------
__device__ __forceinline__ void stage_tile(const _Float16* src, int rowbase, int Kd,
                                           int k0, _Float16* ldsbase, int w, int lane)
{
#pragma unroll
    for (int inst = 0; inst < 2; ++inst) {
        const int r0  = w * 32 + inst * 16;
        const int row = r0 + (lane >> 2);
        const int g   = (lane & 3) ^ ((row >> 1) & 3);
        const _Float16* gp = src + (size_t)(rowbase + row) * Kd + k0 + g * 8;
        __builtin_amdgcn_global_load_lds(
            (const __attribute__((address_space(1))) void*)gp,
            (__attribute__((address_space(3))) void*)(ldsbase + r0 * 32),
            16, 0, 0);
    }
}

template<int OM>   // 0: f32 out, 1: f16 out
__global__ __launch_bounds__(256)
void mgemm(const _Float16* __restrict__ Ah, const _Float16* __restrict__ Wh,
           const float* __restrict__ bias, float* __restrict__ outF,
           _Float16* __restrict__ outH, int N, int Kd, int relu)
{
    __shared__ _Float16 lds[2][2][4096];   // [buf][Ah,Wh][128*32]  (32 KB)
    const int tid = threadIdx.x;
    const int lane = tid & 63, w = tid >> 6;
    const int wm = w >> 1, wn = w & 1;
    const int bn = blockIdx.x, bm = blockIdx.y;
    const int ln15 = lane & 15, g4 = lane >> 4;

    f32x4 acc[4][4];
#pragma unroll
    for (int i = 0; i < 4; ++i)
#pragma unroll
        for (int j = 0; j < 4; ++j) acc[i][j] = f32x4{0.f,0.f,0.f,0.f};

    const int nt = Kd >> 5;
    stage_tile(Ah, bm*128, Kd, 0, &lds[0][0][0], w, lane);
    stage_tile(Wh, bn*128, Kd, 0, &lds[0][1][0], w, lane);
    __syncthreads();

    int cur = 0;
    for (int t = 0; t < nt; ++t) {
        if (t + 1 < nt) {
            const int k0 = (t + 1) << 5;
            stage_tile(Ah, bm*128, Kd, k0, &lds[cur^1][0][0], w, lane);
            stage_tile(Wh, bn*128, Kd, k0, &lds[cur^1][1][0], w, lane);
        }
        f16x8 fa[4], fwh[4];
#pragma unroll
        for (int fm = 0; fm < 4; ++fm) {
            const int lr = wm*64 + fm*16 + ln15;
            const int off = lr*32 + ((g4 ^ ((lr >> 1) & 3)) << 3);
            fa[fm]  = *(const f16x8*)(&lds[cur][0][0] + off);
        }
#pragma unroll
        for (int fn = 0; fn < 4; ++fn) {
            const int lr = wn*64 + fn*16 + ln15;
            const int off = lr*32 + ((g4 ^ ((lr >> 1) & 3)) << 3);
            fwh[fn] = *(const f16x8*)(&lds[cur][1][0] + off);
        }
#pragma unroll
        for (int fm = 0; fm < 4; ++fm)
#pragma unroll
            for (int fn = 0; fn < 4; ++fn)
                acc[fm][fn] = MFMA16F(fa[fm], fwh[fn], acc[fm][fn]);
        __syncthreads();
        cur ^= 1;
    }

    // epilogue: C/D layout col=lane&15, row=(lane>>4)*4+q  [m89-verified]
#pragma unroll
    for (int fm = 0; fm < 4; ++fm)
#pragma unroll
        for (int fn = 0; fn < 4; ++fn) {
            const int col = bn*128 + wn*64 + fn*16 + ln15;
            const float bv = bias[col];
#pragma unroll
            for (int q = 0; q < 4; ++q) {
                const int row = bm*128 + wm*64 + fm*16 + g4*4 + q;
                float v = acc[fm][fn][q] + bv;
                if (relu) v = fmaxf(v, 0.f);
                if (OM == 0) outF[(size_t)row * N + col] = v;
                else         outH[(size_t)row * N + col] = (_Float16)v;
            }
        }
}

// ---------------- small GEMM (N=32): mean = h3 @ Wm_out^T + b ----------------
__global__ __launch_bounds__(64)
void mgemm_small(const _Float16* __restrict__ Ah, const _Float16* __restrict__ Wh,
                 const float* __restrict__ bias, float* __restrict__ out, int Kd)
{
    const int lane = threadIdx.x;
    const int rm = blockIdx.x * 16;
    const int ln15 = lane & 15, g = lane >> 4;
    const int row = rm + ln15;
    f32x4 acc0 = {0.f,0.f,0.f,0.f}, acc1 = {0.f,0.f,0.f,0.f};
    for (int k0 = 0; k0 < Kd; k0 += 32) {
        const int k = k0 + g*8;
        f16x8 a  = *(const f16x8*)(Ah + (size_t)row*Kd + k);
        f16x8 w0h = *(const f16x8*)(Wh + (size_t)ln15*Kd + k);
        f16x8 w1h = *(const f16x8*)(Wh + (size_t)(16+ln15)*Kd + k);
        acc0 = MFMA16F(a, w0h, acc0);
        acc1 = MFMA16F(a, w1h, acc1);
    }
#pragma unroll
    for (int q = 0; q < 4; ++q) {
        const int r = rm + g*4 + q;
        out[r*DZ + ln15]      = acc0[q] + bias[ln15];
        out[r*DZ + 16 + ln15] = acc1[q] + bias[16 + ln15];
    }
}

// ---------------- build Lam, AA (in place over cov), lamMu ----------------
__global__ __launch_bounds__(256)
void build_blocks_kernel(float* __restrict__ cov, const float* __restrict__ mean,
                         float* __restrict__ lamMu, const float* __restrict__ cw)
{
    const int t = blockIdx.x, tid = threadIdx.x;
    __shared__ float R[DZ*33];
    __shared__ float Lam[DZ*33];
    __shared__ float mn[DZ];
    float* blk = cov + (size_t)t * 1024;
    {
        float4 v = ((const float4*)blk)[tid];
        const int base = tid * 4;
        const int row = base >> 5, col = base & 31;
        R[row*33 + col + 0] = v.x; R[row*33 + col + 1] = v.y;
        R[row*33 + col + 2] = v.z; R[row*33 + col + 3] = v.w;
    }
    if (tid < DZ) mn[tid] = mean[t*DZ + tid];
    __syncthreads();
    const float* P = cw + (t == 0 ? OFF_P0 : (t == TT-1 ? OFF_PLAST : OFF_PMID));
#pragma unroll
    for (int q = 0; q < 4; ++q) {
        const int idx = tid + 256*q;
        const int i = idx >> 5, j = idx & 31;
        float s = 0.f;
#pragma unroll
        for (int k = 0; k < DZ; ++k) s += R[i*33+k] * R[j*33+k];
        Lam[i*33+j] = s;
        blk[idx] = s + P[idx];
    }
    __syncthreads();
    if (tid < DZ) {
        float s = 0.f;
#pragma unroll
        for (int k = 0; k < DZ; ++k) s += Lam[tid*33+k] * mn[k];
        lamMu[t*DZ + tid] = s;
    }
}

// ---------------- chol scan v5: registers + readlane + MFMA32 X^T X ----------
__device__ __forceinline__ unsigned short f2bf_c(float f) { return f2bf(f); }

#define CHOL_STEP(OWNED)                                                          \
    {                                                                             \
        _Pragma("unroll")                                                         \
        for (int i = 0; i < 32; ++i) s[i] = Apre[i];                              \
        if (t + 1 < own1) {                                                       \
            const float* an = AA + (size_t)(t+1)*1024;                            \
            _Pragma("unroll")                                                     \
            for (int i = 0; i < 32; ++i) Apre[i] = an[i*32 + c];                  \
        }                                                                         \
        const bool doX = (t > t0);                                                \
        if (doX) {                                                                \
            _Pragma("unroll")                                                     \
            for (int i = 0; i < 32; ++i) u[i] = Breg[i];                          \
            _Pragma("unroll")                                                     \
            for (int r = 0; r < 32; ++r) {                                        \
                float x = u[r] * rlane(invd_own, r);                              \
                u[r] = x;                                                         \
                _Pragma("unroll")                                                 \
                for (int i = r+1; i < 32; ++i)                                    \
                    u[i] = fmaf(-rlane(Lcol[i], r), x, u[i]);                     \
            }                                                                     \
            float f0[8], f1[8];                                                   \
            _Pragma("unroll")                                                     \
            for (int j = 0; j < 8; ++j) {                                         \
                f0[j] = h ? u[8+j]  : u[j];                                       \
                f1[j] = h ? u[24+j] : u[16+j];                                    \
            }                                                                     \
            bf16x8 A0h, A0l, A1h, A1l;                                            \
            _Pragma("unroll")                                                     \
            for (int j = 0; j < 8; ++j) {                                         \
                unsigned short hh0 = f2bf_c(f0[j]);                               \
                A0h[j] = (short)hh0; A0l[j] = (short)f2bf_c(f0[j] - bf2f(hh0));   \
                unsigned short hh1 = f2bf_c(f1[j]);                               \
                A1h[j] = (short)hh1; A1l[j] = (short)f2bf_c(f1[j] - bf2f(hh1));   \
            }                                                                     \
            f32x16 d;                                                             \
            _Pragma("unroll")                                                     \
            for (int q = 0; q < 16; ++q) d[q] = 0.f;                              \
            d = MFMA32(A0h, A0h, d);                                              \
            d = MFMA32(A0h, A0l, d);                                              \
            d = MFMA32(A0l, A0h, d);                                              \
            d = MFMA32(A1h, A1h, d);                                              \
            d = MFMA32(A1h, A1l, d);                                              \
            d = MFMA32(A1l, A1h, d);                                              \
            float dsw[16];                                                        \
            _Pragma("unroll")                                                     \
            for (int q = 0; q < 16; ++q) dsw[q] = __shfl_xor(d[q], 32);           \
            _Pragma("unroll")                                                     \
            for (int i = 0; i < 32; ++i) {                                        \
                const int q  = (i & 3) + ((i >> 3) << 2);                         \
                const int hh = (i >> 2) & 1;                                      \
                s[i] -= (h == hh) ? d[q] : dsw[q];                                \
            }                                                                     \
        }                                                                         \
        _Pragma("unroll")                                                         \
        for (int j = 0; j < 32; ++j) {                                            \
            float sjj = rlane(s[j], j);                                           \
            float inv = __builtin_amdgcn_rsqf(sjj);                               \
            if (OWNED) logacc += __logf(sjj);                                     \
            float inv2 = inv * inv;                                               \
            float ljc = (c > j) ? s[j] * inv2 : 0.f;                              \
            invd_own = (c == j) ? inv : invd_own;                                 \
            _Pragma("unroll")                                                     \
            for (int i = j; i < 32; ++i) s[i] = fmaf(-rlane(s[i], j), ljc, s[i]); \
        }                                                                         \
        _Pragma("unroll")                                                         \
        for (int i = 0; i < 32; ++i) Lcol[i] = s[i] * invd_own;                   \
        if (OWNED) {                                                              \
            float* lt = Lg + (size_t)t*1024 + c*32 + h*16;                        \
            _Pragma("unroll")                                                     \
            for (int q = 0; q < 4; ++q) {                                         \
                float4 v4 = make_float4(h ? Lcol[16+4*q]   : Lcol[4*q],           \
                                        h ? Lcol[16+4*q+1] : Lcol[4*q+1],         \
                                        h ? Lcol[16+4*q+2] : Lcol[4*q+2],         \
                                        h ? Lcol[16+4*q+3] : Lcol[4*q+3]);        \
                *(float4*)(lt + 4*q) = v4;                                        \
            }                                                                     \
            if (doX) {                                                            \
                float* ct = Cg + (size_t)t*1024;                                  \
                _Pragma("unroll")                                                 \
                for (int rr = 0; rr < 16; ++rr) {                                 \
                    float val = h ? u[16+rr] : u[rr];                             \
                    ct[(h*16+rr)*32 + c] = val;                                   \
                }                                                                 \
            }                                                                     \
        }                                                                         \
    }

__global__ __launch_bounds__(64)
void chol_scan5(const float* __restrict__ AA, float* __restrict__ Lg,
                float* __restrict__ Cg, const float* __restrict__ cw,
                float* __restrict__ logsum, int K, int W)
{
    const int lane = threadIdx.x;
    const int c = lane & 31;
    const int h = lane >> 5;
    const int own0 = blockIdx.x * K;
    const int own1 = min(TT, own0 + K);
    const int t0 = max(0, own0 - W);

    float Breg[32], Lcol[32], s[32], u[32], Apre[32];
    float invd_own = 0.f, logacc = 0.f;

#pragma unroll
    for (int i = 0; i < 32; ++i) Breg[i] = cw[OFF_B + i*32 + c];
#pragma unroll
    for (int i = 0; i < 32; ++i) Apre[i] = AA[(size_t)t0*1024 + i*32 + c];

    for (int t = t0; t < own0; ++t) CHOL_STEP(false)
    for (int t = own0; t < own1; ++t) CHOL_STEP(true)

    if (lane == 0) atomicAdd(logsum, logacc * 0.5f);
}

// ---------------- chunked forward bidiagonal solve (L col-major, C = X row-major) -------
__global__ __launch_bounds__(64)
void fwd_solve_kernel(const float* __restrict__ Lg, const float* __restrict__ Cg,
                      const float* __restrict__ bv, float* __restrict__ xout,
                      int K, int W)
{
    const int lane = threadIdx.x;
    const int r = lane & 31, h = lane >> 5;
    const int own0 = blockIdx.x * K;
    const int own1 = min(TT, own0 + K);
    const int t0 = max(0, own0 - W);
    float xprev = 0.f;
    for (int t = t0; t < own1; ++t) {
        const float* lt = Lg + (size_t)t * 1024;
        float Lr[32];
#pragma unroll
        for (int j = 0; j < DZ; ++j) Lr[j] = lt[j*32 + r];
        const float inv = __builtin_amdgcn_rcpf(Lr[r]);
        float v = bv[t*DZ + r];
        if (t > t0) {
            const float* ct = Cg + (size_t)t * 1024;
            float Cr[32];
#pragma unroll
            for (int cc = 0; cc < DZ; ++cc) Cr[cc] = ct[cc*32 + r];
#pragma unroll
            for (int cc = 0; cc < DZ; ++cc) v = fmaf(-Cr[cc], __shfl(xprev, cc), v);
        }
        float xv = 0.f;
#pragma unroll
        for (int rr = 0; rr < DZ; ++rr) {
            float cand = v * inv;
            float xb = __shfl(cand, rr);
            if (r == rr) xv = cand;
            if (r > rr) v = fmaf(-Lr[rr], xb, v);
        }
        xprev = xv;
        if (t >= own0 && h == 0) xout[t*DZ + r] = xv;
    }
}

// ---------------- chunked backward solve (two RHS) + sample -----------------------------
__global__ __launch_bounds__(64)
void bwd_solve_kernel(const float* __restrict__ Lg, const float* __restrict__ Cg,
                      const float* __restrict__ b1, const float* __restrict__ b2,
                      float* __restrict__ outSample, int K, int W)
{
    const int lane = threadIdx.x;
    const int k = lane & 31, h = lane >> 5;
    const int own0 = blockIdx.x * K;
    const int own1 = min(TT, own0 + K);
    const int tS = min(TT - 1, own1 - 1 + W);
    float x1p = 0.f, x2p = 0.f;
    for (int t = tS; t >= own0; --t) {
        const float* lt = Lg + (size_t)t * 1024;
        float Lc[32];
#pragma unroll
        for (int q = 0; q < 8; ++q) {
            float4 v4 = *(const float4*)(lt + k*32 + 4*q);
            Lc[4*q] = v4.x; Lc[4*q+1] = v4.y; Lc[4*q+2] = v4.z; Lc[4*q+3] = v4.w;
        }
        const float inv = __builtin_amdgcn_rcpf(Lc[k]);
        float v1 = b1[t*DZ + k], v2 = b2[t*DZ + k];
        if (t < tS) {
            const float* ct = Cg + (size_t)(t+1) * 1024;
            float Cc[32];
#pragma unroll
            for (int q = 0; q < 8; ++q) {
                float4 w4 = *(const float4*)(ct + k*32 + 4*q);
                Cc[4*q] = w4.x; Cc[4*q+1] = w4.y; Cc[4*q+2] = w4.z; Cc[4*q+3] = w4.w;
            }
#pragma unroll
            for (int cc = 0; cc < DZ; ++cc) {
                float a1 = __shfl(x1p, cc), a2 = __shfl(x2p, cc);
                v1 = fmaf(-Cc[cc], a1, v1); v2 = fmaf(-Cc[cc], a2, v2);
            }
        }
        float x1 = 0.f, x2 = 0.f;
#pragma unroll
        for (int rr = DZ-1; rr >= 0; --rr) {
            float c1 = v1 * inv, c2 = v2 * inv;
            float xb1 = __shfl(c1, rr), xb2 = __shfl(c2, rr);
            if (k == rr) { x1 = c1; x2 = c2; }
            if (k < rr) { v1 = fmaf(-Lc[rr], xb1, v1); v2 = fmaf(-Lc[rr], xb2, v2); }
        }
        x1p = x1; x2p = x2;
        if (t >= own0 && h == 0) outSample[t*DZ + k] = x1 + x2;
    }
}

// ---------------- entropy ----------------
__global__ void finalize_kernel(const float* __restrict__ logsum, float* __restrict__ out)
{
    if (threadIdx.x == 0) {
        out[TT*DZ] = (logsum[0] - 2270.3016531274763f) / 409600.0f;
    }
}

// ---------------- launch ----------------
extern "C" void kernel_launch(void* const* d_in, const int* in_sizes, int n_in,
                              void* d_out, int out_size, void* d_ws, size_t ws_size,
                              hipStream_t stream)
{
    (void)in_sizes; (void)n_in; (void)out_size; (void)ws_size;
    const float* x        = (const float*)d_in[0];
    const float* norm     = (const float*)d_in[1];
    const float* A        = (const float*)d_in[2];
    const float* QinvChol = (const float*)d_in[3];
    const float* Q0invChol= (const float*)d_in[4];
    const float* Wm_in = (const float*)d_in[5];  const float* bm_in = (const float*)d_in[6];
    const float* Wm_h1 = (const float*)d_in[7];  const float* bm_h1 = (const float*)d_in[8];
    const float* Wm_h3 = (const float*)d_in[9];  const float* bm_h3 = (const float*)d_in[10];
    const float* Wm_out= (const float*)d_in[11]; const float* bm_out= (const float*)d_in[12];
    const float* Wc_in = (const float*)d_in[13]; const float* bc_in = (const float*)d_in[14];
    const float* Wc_h1 = (const float*)d_in[15]; const float* bc_h1 = (const float*)d_in[16];
    const float* Wc_h3 = (const float*)d_in[17]; const float* bc_h3 = (const float*)d_in[18];
    const float* Wc_out= (const float*)d_in[19]; const float* bc_out= (const float*)d_in[20];

    float* ws    = (float*)d_ws;
    float* out   = (float*)d_out;
    float* cw    = ws;
    float* Lbuf  = ws + OFF_ACT0;
    float* Cbuf  = ws + OFF_ACT1;
    float* covb  = ws + OFF_AAB;
    float* meanb = ws + OFF_MEANB;
    float* lamMu = ws + OFF_LAMMU;
    float* ib    = ws + OFF_IBV;
    float* logsum = ws + OFF_LOGSUM;

    _Float16* a0h = (_Float16*)(ws + OFF_ACT0);
    _Float16* a1h = (_Float16*)(ws + OFF_ACT1);
    _Float16* xh  = (_Float16*)(ws + OFF_XB);

    const long OWmi = OFF_WB;
    const long OWm1 = OWmi + 262144;
    const long OWm3 = OWm1 + 1048576;
    const long OWmo = OWm3 + 1048576;
    const long OWci = OWmo + 32768;
    const long OWc1 = OWci + 262144;
    const long OWc3 = OWc1 + 1048576;
    const long OWco = OWc3 + 1048576;
    #define WH(o) ((_Float16*)(ws + (o)))

    setup_kernel<<<dim3(1), dim3(1024), 0, stream>>>(A, QinvChol, Q0invChol, cw);

    SplitArgs sa;
    sa.seg[0] = { x,      xh,       2097152 };
    sa.seg[1] = { Wm_in,  WH(OWmi), 262144 };
    sa.seg[2] = { Wm_h1,  WH(OWm1), 1048576 };
    sa.seg[3] = { Wm_h3,  WH(OWm3), 1048576 };
    sa.seg[4] = { Wm_out, WH(OWmo), 32768 };
    sa.seg[5] = { Wc_in,  WH(OWci), 262144 };
    sa.seg[6] = { Wc_h1,  WH(OWc1), 1048576 };
    sa.seg[7] = { Wc_h3,  WH(OWc3), 1048576 };
    sa.seg[8] = { Wc_out, WH(OWco), 1048576 };
    split_all<<<dim3(2048, 9), dim3(256), 0, stream>>>(sa);

    const dim3 gBig(8, 64), blk(256);
    // mean MLP
    mgemm<1><<<gBig, blk, 0, stream>>>(xh,  WH(OWmi), bm_in, nullptr, a0h, 1024, 256, 1);
    mgemm<1><<<gBig, blk, 0, stream>>>(a0h, WH(OWm1), bm_h1, nullptr, a1h, 1024, 1024, 1);
    mgemm<1><<<gBig, blk, 0, stream>>>(a1h, WH(OWm3), bm_h3, nullptr, a0h, 1024, 1024, 1);
    mgemm_small<<<dim3(512), dim3(64), 0, stream>>>(a0h, WH(OWmo), bm_out, meanb, 1024);
    // cov MLP
    mgemm<1><<<gBig, blk, 0, stream>>>(xh,  WH(OWci), bc_in, nullptr, a1h, 1024, 256, 1);
    mgemm<1><<<gBig, blk, 0, stream>>>(a1h, WH(OWc1), bc_h1, nullptr, a0h, 1024, 1024, 1);
    mgemm<1><<<gBig, blk, 0, stream>>>(a0h, WH(OWc3), bc_h3, nullptr, a1h, 1024, 1024, 1);
    mgemm<0><<<gBig, blk, 0, stream>>>(a1h, WH(OWco), bc_out, covb, nullptr, 1024, 1024, 0);

    build_blocks_kernel<<<dim3(TT), dim3(256), 0, stream>>>(covb, meanb, lamMu, cw);

    chol_scan5<<<dim3(TT/4), dim3(64), 0, stream>>>(covb, Lbuf, Cbuf, cw, logsum, 4, 8);
    fwd_solve_kernel<<<dim3(TT/4), dim3(64), 0, stream>>>(Lbuf, Cbuf, lamMu, ib, 4, 20);
    bwd_solve_kernel<<<dim3(TT/4), dim3(64), 0, stream>>>(Lbuf, Cbuf, ib, norm, out, 4, 20);

    finalize_kernel<<<dim3(1), dim3(64), 0, stream>>>(logsum, out);
}

// Round 8
// 455.053 us; speedup vs baseline: 11.7078x; 1.1572x over previous
//
#include <hip/hip_runtime.h>
#include <math.h>

#define TT 8192
#define DZ 32

typedef short bf16x8 __attribute__((ext_vector_type(8)));
typedef _Float16 f16x8 __attribute__((ext_vector_type(8)));
typedef _Float16 f16x4 __attribute__((ext_vector_type(4)));
typedef float f32x4 __attribute__((ext_vector_type(4)));
typedef float f32x16 __attribute__((ext_vector_type(16)));
#define MFMA16F(a,b,c) __builtin_amdgcn_mfma_f32_16x16x32_f16(a,b,c,0,0,0)
#define MFMA32(a,b,c) __builtin_amdgcn_mfma_f32_32x32x16_bf16(a,b,c,0,0,0)

// ---------------- workspace layout (float units) ----------------
#define OFF_QINV   0
#define OFF_Q0INV  1024
#define OFF_AQA    2048
#define OFF_B      3072
#define OFF_P0     4096
#define OFF_PMID   5120
#define OFF_PLAST  6144
#define OFF_LOGSUM 7168
#define OFF_ACT0   8192                     // 2 f16 act slots -> later L (f32, col-major per t)
#define OFF_ACT1   (OFF_ACT0 + 8388608)     // 2 f16 act slots -> later C (f32, X row-major per t)
#define OFF_AAB    (OFF_ACT1 + 8388608)     // cov f32 -> AA in place
#define OFF_XB     (OFF_AAB + 8388608)      // x f16
#define OFF_WB     (OFF_XB + 2097152)       // weights f16
#define OFF_MEANB  (OFF_WB + 5799936)
#define OFF_LAMMU  (OFF_MEANB + 262144)
#define OFF_IBV    (OFF_LAMMU + 262144)

#define ACT_HALF 4194304                    // 4.2M floats-worth? (f16 elems: 8192*1024 = 8.4M f16 = 4.2M floats)

__device__ __forceinline__ unsigned short f2bf(float f) {
    unsigned int u = __float_as_uint(f);
    u += 0x7FFFu + ((u >> 16) & 1u);
    return (unsigned short)(u >> 16);
}
__device__ __forceinline__ float bf2f(unsigned short h) {
    return __uint_as_float(((unsigned int)h) << 16);
}
__device__ __forceinline__ float rlane(float v, int l) {
    return __uint_as_float(__builtin_amdgcn_readlane(__float_as_uint(v), l));
}

// ---------------- fused f32 -> f16 conversion (all tensors, 1 launch) ----------------
struct SplitSeg { const float* src; _Float16* hi; int n; };
struct SplitArgs { SplitSeg seg[9]; };

__global__ __launch_bounds__(256)
void split_all(SplitArgs a)
{
    const SplitSeg sg = a.seg[blockIdx.y];
    const int n4 = sg.n >> 2;
    int i = blockIdx.x * 256 + threadIdx.x;
    if (i >= n4) return;
    float4 v = ((const float4*)sg.src)[i];
    f16x4 hh;
    hh[0] = (_Float16)v.x; hh[1] = (_Float16)v.y;
    hh[2] = (_Float16)v.z; hh[3] = (_Float16)v.w;
    ((f16x4*)sg.hi)[i] = hh;
}

// ---------------- setup: Qinv, Q0inv, AQA, B, priors ----------------
__global__ __launch_bounds__(1024)
void setup_kernel(const float* __restrict__ A, const float* __restrict__ QinvChol,
                  const float* __restrict__ Q0invChol, float* __restrict__ cw)
{
    __shared__ float As[DZ*33], Qc[DZ*33], Q0c[DZ*33], Qi[DZ*33], T1[DZ*33];
    const int tid = threadIdx.x;
    const int i = tid >> 5, j = tid & 31;
    As[i*33+j]  = A[tid];
    Qc[i*33+j]  = QinvChol[tid];
    Q0c[i*33+j] = Q0invChol[tid];
    __syncthreads();
    float qi = 0.f, q0 = 0.f;
    for (int k = 0; k < DZ; ++k) { qi += Qc[i*33+k]*Qc[j*33+k]; q0 += Q0c[i*33+k]*Q0c[j*33+k]; }
    Qi[i*33+j] = qi;
    __syncthreads();
    float t1 = 0.f;
    for (int k = 0; k < DZ; ++k) t1 += Qi[i*33+k]*As[k*33+j];
    T1[i*33+j] = t1;
    __syncthreads();
    float aqa = 0.f, bm = 0.f;
    for (int k = 0; k < DZ; ++k) { aqa += As[k*33+i]*T1[k*33+j]; bm += As[k*33+i]*Qi[k*33+j]; }
    cw[OFF_QINV  + tid] = qi;
    cw[OFF_Q0INV + tid] = q0;
    cw[OFF_AQA   + tid] = aqa;
    cw[OFF_B     + tid] = -bm;
    cw[OFF_P0    + tid] = q0 + aqa;
    cw[OFF_PMID  + tid] = qi + aqa;
    cw[OFF_PLAST + tid] = qi;
    if (tid == 0) cw[OFF_LOGSUM] = 0.f;
}

// ---------------- f16 MFMA GEMM ----------------
__device__ __forceinline__ void stage_tile(const _Float16* src, int rowbase, int Kd,
                                           int k0, _Float16* ldsbase, int w, int lane)
{
#pragma unroll
    for (int inst = 0; inst < 2; ++inst) {
        const int r0  = w * 32 + inst * 16;
        const int row = r0 + (lane >> 2);
        const int g   = (lane & 3) ^ ((row >> 1) & 3);
        const _Float16* gp = src + (size_t)(rowbase + row) * Kd + k0 + g * 8;
        __builtin_amdgcn_global_load_lds(
            (const __attribute__((address_space(1))) void*)gp,
            (__attribute__((address_space(3))) void*)(ldsbase + r0 * 32),
            16, 0, 0);
    }
}

// GEMM body: C = act(A @ W^T + b). OM: 0 f32 out, 1 f16 out.
template<int OM>
__device__ __forceinline__ void mgemm_body(const _Float16* Ah, const _Float16* Wh,
                                           const float* bias, float* outF,
                                           _Float16* outH, int N, int Kd, int relu,
                                           int bn, int bm, _Float16 (*lds)[2][4096])
{
    const int tid = threadIdx.x;
    const int lane = tid & 63, w = tid >> 6;
    const int wm = w >> 1, wn = w & 1;
    const int ln15 = lane & 15, g4 = lane >> 4;

    f32x4 acc[4][4];
#pragma unroll
    for (int i = 0; i < 4; ++i)
#pragma unroll
        for (int j = 0; j < 4; ++j) acc[i][j] = f32x4{0.f,0.f,0.f,0.f};

    const int nt = Kd >> 5;
    stage_tile(Ah, bm*128, Kd, 0, &lds[0][0][0], w, lane);
    stage_tile(Wh, bn*128, Kd, 0, &lds[0][1][0], w, lane);
    __syncthreads();

    int cur = 0;
    for (int t = 0; t < nt; ++t) {
        if (t + 1 < nt) {
            const int k0 = (t + 1) << 5;
            stage_tile(Ah, bm*128, Kd, k0, &lds[cur^1][0][0], w, lane);
            stage_tile(Wh, bn*128, Kd, k0, &lds[cur^1][1][0], w, lane);
        }
        f16x8 fa[4], fwh[4];
#pragma unroll
        for (int fm = 0; fm < 4; ++fm) {
            const int lr = wm*64 + fm*16 + ln15;
            const int off = lr*32 + ((g4 ^ ((lr >> 1) & 3)) << 3);
            fa[fm]  = *(const f16x8*)(&lds[cur][0][0] + off);
        }
#pragma unroll
        for (int fn = 0; fn < 4; ++fn) {
            const int lr = wn*64 + fn*16 + ln15;
            const int off = lr*32 + ((g4 ^ ((lr >> 1) & 3)) << 3);
            fwh[fn] = *(const f16x8*)(&lds[cur][1][0] + off);
        }
#pragma unroll
        for (int fm = 0; fm < 4; ++fm)
#pragma unroll
            for (int fn = 0; fn < 4; ++fn)
                acc[fm][fn] = MFMA16F(fa[fm], fwh[fn], acc[fm][fn]);
        __syncthreads();
        cur ^= 1;
    }

    // epilogue: C/D layout col=lane&15, row=(lane>>4)*4+q  [m89-verified]
#pragma unroll
    for (int fm = 0; fm < 4; ++fm)
#pragma unroll
        for (int fn = 0; fn < 4; ++fn) {
            const int col = bn*128 + wn*64 + fn*16 + ln15;
            const float bv = bias[col];
#pragma unroll
            for (int q = 0; q < 4; ++q) {
                const int row = bm*128 + wm*64 + fm*16 + g4*4 + q;
                float v = acc[fm][fn][q] + bv;
                if (relu) v = fmaxf(v, 0.f);
                if (OM == 0) outF[(size_t)row * N + col] = v;
                else         outH[(size_t)row * N + col] = (_Float16)v;
            }
        }
}

// single-chain GEMM (final cov layer, f32 out)
__global__ __launch_bounds__(256)
void mgemm_f32(const _Float16* __restrict__ Ah, const _Float16* __restrict__ Wh,
               const float* __restrict__ bias, float* __restrict__ outF,
               int N, int Kd)
{
    __shared__ _Float16 lds[2][2][4096];
    mgemm_body<0>(Ah, Wh, bias, outF, nullptr, N, Kd, 0, blockIdx.x, blockIdx.y, lds);
}

// merged mean/cov GEMM: blockIdx.z selects chain (both f16 out, relu)
__global__ __launch_bounds__(256)
void mgemm2(const _Float16* __restrict__ A0, const _Float16* __restrict__ A1,
            const _Float16* __restrict__ W0, const _Float16* __restrict__ W1,
            const float* __restrict__ b0, const float* __restrict__ b1,
            _Float16* __restrict__ o0, _Float16* __restrict__ o1,
            int N, int Kd)
{
    __shared__ _Float16 lds[2][2][4096];
    const int z = blockIdx.z;
    const _Float16* Ah = z ? A1 : A0;
    const _Float16* Wh = z ? W1 : W0;
    const float* bias  = z ? b1 : b0;
    _Float16* outH     = z ? o1 : o0;
    mgemm_body<1>(Ah, Wh, bias, nullptr, outH, N, Kd, 1, blockIdx.x, blockIdx.y, lds);
}

// ---------------- small GEMM (N=32): mean = h3 @ Wm_out^T + b ----------------
__global__ __launch_bounds__(64)
void mgemm_small(const _Float16* __restrict__ Ah, const _Float16* __restrict__ Wh,
                 const float* __restrict__ bias, float* __restrict__ out, int Kd)
{
    const int lane = threadIdx.x;
    const int rm = blockIdx.x * 16;
    const int ln15 = lane & 15, g = lane >> 4;
    const int row = rm + ln15;
    f32x4 acc0 = {0.f,0.f,0.f,0.f}, acc1 = {0.f,0.f,0.f,0.f};
    for (int k0 = 0; k0 < Kd; k0 += 32) {
        const int k = k0 + g*8;
        f16x8 a  = *(const f16x8*)(Ah + (size_t)row*Kd + k);
        f16x8 w0h = *(const f16x8*)(Wh + (size_t)ln15*Kd + k);
        f16x8 w1h = *(const f16x8*)(Wh + (size_t)(16+ln15)*Kd + k);
        acc0 = MFMA16F(a, w0h, acc0);
        acc1 = MFMA16F(a, w1h, acc1);
    }
#pragma unroll
    for (int q = 0; q < 4; ++q) {
        const int r = rm + g*4 + q;
        out[r*DZ + ln15]      = acc0[q] + bias[ln15];
        out[r*DZ + 16 + ln15] = acc1[q] + bias[16 + ln15];
    }
}

// ---------------- build Lam, AA (in place over cov), lamMu ----------------
__global__ __launch_bounds__(256)
void build_blocks_kernel(float* __restrict__ cov, const float* __restrict__ mean,
                         float* __restrict__ lamMu, const float* __restrict__ cw)
{
    const int t = blockIdx.x, tid = threadIdx.x;
    __shared__ float R[DZ*33];
    __shared__ float Lam[DZ*33];
    __shared__ float mn[DZ];
    float* blk = cov + (size_t)t * 1024;
    {
        float4 v = ((const float4*)blk)[tid];
        const int base = tid * 4;
        const int row = base >> 5, col = base & 31;
        R[row*33 + col + 0] = v.x; R[row*33 + col + 1] = v.y;
        R[row*33 + col + 2] = v.z; R[row*33 + col + 3] = v.w;
    }
    if (tid < DZ) mn[tid] = mean[t*DZ + tid];
    __syncthreads();
    const float* P = cw + (t == 0 ? OFF_P0 : (t == TT-1 ? OFF_PLAST : OFF_PMID));
#pragma unroll
    for (int q = 0; q < 4; ++q) {
        const int idx = tid + 256*q;
        const int i = idx >> 5, j = idx & 31;
        float s = 0.f;
#pragma unroll
        for (int k = 0; k < DZ; ++k) s += R[i*33+k] * R[j*33+k];
        Lam[i*33+j] = s;
        blk[idx] = s + P[idx];
    }
    __syncthreads();
    if (tid < DZ) {
        float s = 0.f;
#pragma unroll
        for (int k = 0; k < DZ; ++k) s += Lam[tid*33+k] * mn[k];
        lamMu[t*DZ + tid] = s;
    }
}

// ---------------- chol scan v5: registers + readlane + MFMA32 X^T X ----------
__device__ __forceinline__ unsigned short f2bf_c(float f) { return f2bf(f); }

#define CHOL_STEP(OWNED)                                                          \
    {                                                                             \
        _Pragma("unroll")                                                         \
        for (int i = 0; i < 32; ++i) s[i] = Apre[i];                              \
        if (t + 1 < own1) {                                                       \
            const float* an = AA + (size_t)(t+1)*1024;                            \
            _Pragma("unroll")                                                     \
            for (int i = 0; i < 32; ++i) Apre[i] = an[i*32 + c];                  \
        }                                                                         \
        const bool doX = (t > t0);                                                \
        if (doX) {                                                                \
            _Pragma("unroll")                                                     \
            for (int i = 0; i < 32; ++i) u[i] = Breg[i];                          \
            _Pragma("unroll")                                                     \
            for (int r = 0; r < 32; ++r) {                                        \
                float x = u[r] * rlane(invd_own, r);                              \
                u[r] = x;                                                         \
                _Pragma("unroll")                                                 \
                for (int i = r+1; i < 32; ++i)                                    \
                    u[i] = fmaf(-rlane(Lcol[i], r), x, u[i]);                     \
            }                                                                     \
            float f0[8], f1[8];                                                   \
            _Pragma("unroll")                                                     \
            for (int j = 0; j < 8; ++j) {                                         \
                f0[j] = h ? u[8+j]  : u[j];                                       \
                f1[j] = h ? u[24+j] : u[16+j];                                    \
            }                                                                     \
            bf16x8 A0h, A0l, A1h, A1l;                                            \
            _Pragma("unroll")                                                     \
            for (int j = 0; j < 8; ++j) {                                         \
                unsigned short hh0 = f2bf_c(f0[j]);                               \
                A0h[j] = (short)hh0; A0l[j] = (short)f2bf_c(f0[j] - bf2f(hh0));   \
                unsigned short hh1 = f2bf_c(f1[j]);                               \
                A1h[j] = (short)hh1; A1l[j] = (short)f2bf_c(f1[j] - bf2f(hh1));   \
            }                                                                     \
            f32x16 d;                                                             \
            _Pragma("unroll")                                                     \
            for (int q = 0; q < 16; ++q) d[q] = 0.f;                              \
            d = MFMA32(A0h, A0h, d);                                              \
            d = MFMA32(A0h, A0l, d);                                              \
            d = MFMA32(A0l, A0h, d);                                              \
            d = MFMA32(A1h, A1h, d);                                              \
            d = MFMA32(A1h, A1l, d);                                              \
            d = MFMA32(A1l, A1h, d);                                              \
            float dsw[16];                                                        \
            _Pragma("unroll")                                                     \
            for (int q = 0; q < 16; ++q) dsw[q] = __shfl_xor(d[q], 32);           \
            _Pragma("unroll")                                                     \
            for (int i = 0; i < 32; ++i) {                                        \
                const int q  = (i & 3) + ((i >> 3) << 2);                         \
                const int hh = (i >> 2) & 1;                                      \
                s[i] -= (h == hh) ? d[q] : dsw[q];                                \
            }                                                                     \
        }                                                                         \
        _Pragma("unroll")                                                         \
        for (int j = 0; j < 32; ++j) {                                            \
            float sjj = rlane(s[j], j);                                           \
            float inv = __builtin_amdgcn_rsqf(sjj);                               \
            if (OWNED) logacc += __logf(sjj);                                     \
            float inv2 = inv * inv;                                               \
            float ljc = (c > j) ? s[j] * inv2 : 0.f;                              \
            invd_own = (c == j) ? inv : invd_own;                                 \
            _Pragma("unroll")                                                     \
            for (int i = j; i < 32; ++i) s[i] = fmaf(-rlane(s[i], j), ljc, s[i]); \
        }                                                                         \
        _Pragma("unroll")                                                         \
        for (int i = 0; i < 32; ++i) Lcol[i] = s[i] * invd_own;                   \
        if (OWNED) {                                                              \
            float* lt = Lg + (size_t)t*1024 + c*32 + h*16;                        \
            _Pragma("unroll")                                                     \
            for (int q = 0; q < 4; ++q) {                                         \
                float4 v4 = make_float4(h ? Lcol[16+4*q]   : Lcol[4*q],           \
                                        h ? Lcol[16+4*q+1] : Lcol[4*q+1],         \
                                        h ? Lcol[16+4*q+2] : Lcol[4*q+2],         \
                                        h ? Lcol[16+4*q+3] : Lcol[4*q+3]);        \
                *(float4*)(lt + 4*q) = v4;                                        \
            }                                                                     \
            if (doX) {                                                            \
                float* ct = Cg + (size_t)t*1024;                                  \
                _Pragma("unroll")                                                 \
                for (int rr = 0; rr < 16; ++rr) {                                 \
                    float val = h ? u[16+rr] : u[rr];                             \
                    ct[(h*16+rr)*32 + c] = val;                                   \
                }                                                                 \
            }                                                                     \
        }                                                                         \
    }

__global__ __launch_bounds__(64)
void chol_scan5(const float* __restrict__ AA, float* __restrict__ Lg,
                float* __restrict__ Cg, const float* __restrict__ cw,
                float* __restrict__ logsum, int K, int W)
{
    const int lane = threadIdx.x;
    const int c = lane & 31;
    const int h = lane >> 5;
    const int own0 = blockIdx.x * K;
    const int own1 = min(TT, own0 + K);
    const int t0 = max(0, own0 - W);

    float Breg[32], Lcol[32], s[32], u[32], Apre[32];
    float invd_own = 0.f, logacc = 0.f;

#pragma unroll
    for (int i = 0; i < 32; ++i) Breg[i] = cw[OFF_B + i*32 + c];
#pragma unroll
    for (int i = 0; i < 32; ++i) Apre[i] = AA[(size_t)t0*1024 + i*32 + c];

    for (int t = t0; t < own0; ++t) CHOL_STEP(false)
    for (int t = own0; t < own1; ++t) CHOL_STEP(true)

    if (lane == 0) atomicAdd(logsum, logacc * 0.5f);
}

// ---------------- chunked forward bidiagonal solve (L col-major, C = X row-major) -------
__global__ __launch_bounds__(64)
void fwd_solve_kernel(const float* __restrict__ Lg, const float* __restrict__ Cg,
                      const float* __restrict__ bv, float* __restrict__ xout,
                      int K, int W)
{
    const int lane = threadIdx.x;
    const int r = lane & 31, h = lane >> 5;
    const int own0 = blockIdx.x * K;
    const int own1 = min(TT, own0 + K);
    const int t0 = max(0, own0 - W);
    float xprev = 0.f;
    for (int t = t0; t < own1; ++t) {
        const float* lt = Lg + (size_t)t * 1024;
        float Lr[32];
#pragma unroll
        for (int j = 0; j < DZ; ++j) Lr[j] = lt[j*32 + r];
        const float inv = __builtin_amdgcn_rcpf(Lr[r]);
        float v = bv[t*DZ + r];
        if (t > t0) {
            const float* ct = Cg + (size_t)t * 1024;
            float Cr[32];
#pragma unroll
            for (int cc = 0; cc < DZ; ++cc) Cr[cc] = ct[cc*32 + r];
#pragma unroll
            for (int cc = 0; cc < DZ; ++cc) v = fmaf(-Cr[cc], __shfl(xprev, cc), v);
        }
        float xv = 0.f;
#pragma unroll
        for (int rr = 0; rr < DZ; ++rr) {
            float cand = v * inv;
            float xb = __shfl(cand, rr);
            if (r == rr) xv = cand;
            if (r > rr) v = fmaf(-Lr[rr], xb, v);
        }
        xprev = xv;
        if (t >= own0 && h == 0) xout[t*DZ + r] = xv;
    }
}

// ---------------- chunked backward solve (two RHS) + sample -----------------------------
__global__ __launch_bounds__(64)
void bwd_solve_kernel(const float* __restrict__ Lg, const float* __restrict__ Cg,
                      const float* __restrict__ b1, const float* __restrict__ b2,
                      float* __restrict__ outSample, int K, int W)
{
    const int lane = threadIdx.x;
    const int k = lane & 31, h = lane >> 5;
    const int own0 = blockIdx.x * K;
    const int own1 = min(TT, own0 + K);
    const int tS = min(TT - 1, own1 - 1 + W);
    float x1p = 0.f, x2p = 0.f;
    for (int t = tS; t >= own0; --t) {
        const float* lt = Lg + (size_t)t * 1024;
        float Lc[32];
#pragma unroll
        for (int q = 0; q < 8; ++q) {
            float4 v4 = *(const float4*)(lt + k*32 + 4*q);
            Lc[4*q] = v4.x; Lc[4*q+1] = v4.y; Lc[4*q+2] = v4.z; Lc[4*q+3] = v4.w;
        }
        const float inv = __builtin_amdgcn_rcpf(Lc[k]);
        float v1 = b1[t*DZ + k], v2 = b2[t*DZ + k];
        if (t < tS) {
            const float* ct = Cg + (size_t)(t+1) * 1024;
            float Cc[32];
#pragma unroll
            for (int q = 0; q < 8; ++q) {
                float4 w4 = *(const float4*)(ct + k*32 + 4*q);
                Cc[4*q] = w4.x; Cc[4*q+1] = w4.y; Cc[4*q+2] = w4.z; Cc[4*q+3] = w4.w;
            }
#pragma unroll
            for (int cc = 0; cc < DZ; ++cc) {
                float a1 = __shfl(x1p, cc), a2 = __shfl(x2p, cc);
                v1 = fmaf(-Cc[cc], a1, v1); v2 = fmaf(-Cc[cc], a2, v2);
            }
        }
        float x1 = 0.f, x2 = 0.f;
#pragma unroll
        for (int rr = DZ-1; rr >= 0; --rr) {
            float c1 = v1 * inv, c2 = v2 * inv;
            float xb1 = __shfl(c1, rr), xb2 = __shfl(c2, rr);
            if (k == rr) { x1 = c1; x2 = c2; }
            if (k < rr) { v1 = fmaf(-Lc[rr], xb1, v1); v2 = fmaf(-Lc[rr], xb2, v2); }
        }
        x1p = x1; x2p = x2;
        if (t >= own0 && h == 0) outSample[t*DZ + k] = x1 + x2;
    }
}

// ---------------- entropy ----------------
__global__ void finalize_kernel(const float* __restrict__ logsum, float* __restrict__ out)
{
    if (threadIdx.x == 0) {
        out[TT*DZ] = (logsum[0] - 2270.3016531274763f) / 409600.0f;
    }
}

// ---------------- launch ----------------
extern "C" void kernel_launch(void* const* d_in, const int* in_sizes, int n_in,
                              void* d_out, int out_size, void* d_ws, size_t ws_size,
                              hipStream_t stream)
{
    (void)in_sizes; (void)n_in; (void)out_size; (void)ws_size;
    const float* x        = (const float*)d_in[0];
    const float* norm     = (const float*)d_in[1];
    const float* A        = (const float*)d_in[2];
    const float* QinvChol = (const float*)d_in[3];
    const float* Q0invChol= (const float*)d_in[4];
    const float* Wm_in = (const float*)d_in[5];  const float* bm_in = (const float*)d_in[6];
    const float* Wm_h1 = (const float*)d_in[7];  const float* bm_h1 = (const float*)d_in[8];
    const float* Wm_h3 = (const float*)d_in[9];  const float* bm_h3 = (const float*)d_in[10];
    const float* Wm_out= (const float*)d_in[11]; const float* bm_out= (const float*)d_in[12];
    const float* Wc_in = (const float*)d_in[13]; const float* bc_in = (const float*)d_in[14];
    const float* Wc_h1 = (const float*)d_in[15]; const float* bc_h1 = (const float*)d_in[16];
    const float* Wc_h3 = (const float*)d_in[17]; const float* bc_h3 = (const float*)d_in[18];
    const float* Wc_out= (const float*)d_in[19]; const float* bc_out= (const float*)d_in[20];

    float* ws    = (float*)d_ws;
    float* out   = (float*)d_out;
    float* cw    = ws;
    float* Lbuf  = ws + OFF_ACT0;
    float* Cbuf  = ws + OFF_ACT1;
    float* covb  = ws + OFF_AAB;
    float* meanb = ws + OFF_MEANB;
    float* lamMu = ws + OFF_LAMMU;
    float* ib    = ws + OFF_IBV;
    float* logsum = ws + OFF_LOGSUM;

    // 4 f16 activation slots (8.4M f16 = 16.8 MB each), carved from ACT0/ACT1 regions
    _Float16* s0 = (_Float16*)(ws + OFF_ACT0);
    _Float16* s1 = s0 + 8388608;
    _Float16* s2 = (_Float16*)(ws + OFF_ACT1);
    _Float16* s3 = s2 + 8388608;
    _Float16* xh = (_Float16*)(ws + OFF_XB);

    const long OWmi = OFF_WB;
    const long OWm1 = OWmi + 262144;
    const long OWm3 = OWm1 + 1048576;
    const long OWmo = OWm3 + 1048576;
    const long OWci = OWmo + 32768;
    const long OWc1 = OWci + 262144;
    const long OWc3 = OWc1 + 1048576;
    const long OWco = OWc3 + 1048576;
    #define WH(o) ((_Float16*)(ws + (o)))

    setup_kernel<<<dim3(1), dim3(1024), 0, stream>>>(A, QinvChol, Q0invChol, cw);

    SplitArgs sa;
    sa.seg[0] = { x,      xh,       2097152 };
    sa.seg[1] = { Wm_in,  WH(OWmi), 262144 };
    sa.seg[2] = { Wm_h1,  WH(OWm1), 1048576 };
    sa.seg[3] = { Wm_h3,  WH(OWm3), 1048576 };
    sa.seg[4] = { Wm_out, WH(OWmo), 32768 };
    sa.seg[5] = { Wc_in,  WH(OWci), 262144 };
    sa.seg[6] = { Wc_h1,  WH(OWc1), 1048576 };
    sa.seg[7] = { Wc_h3,  WH(OWc3), 1048576 };
    sa.seg[8] = { Wc_out, WH(OWco), 1048576 };
    split_all<<<dim3(2048, 9), dim3(256), 0, stream>>>(sa);

    const dim3 gM(8, 64, 2), blk(256);
    // L1: x -> s0 (mean h1) / s1 (cov h1)
    mgemm2<<<gM, blk, 0, stream>>>(xh, xh, WH(OWmi), WH(OWci), bm_in, bc_in, s0, s1, 1024, 256);
    // L2: s0 -> s2 (mean h2) / s1 -> s3 (cov h2)
    mgemm2<<<gM, blk, 0, stream>>>(s0, s1, WH(OWm1), WH(OWc1), bm_h1, bc_h1, s2, s3, 1024, 1024);
    // L3: s2 -> s0 (mean h3) / s3 -> s1 (cov h3)
    mgemm2<<<gM, blk, 0, stream>>>(s2, s3, WH(OWm3), WH(OWc3), bm_h3, bc_h3, s0, s1, 1024, 1024);
    // heads
    mgemm_small<<<dim3(512), dim3(64), 0, stream>>>(s0, WH(OWmo), bm_out, meanb, 1024);
    mgemm_f32<<<dim3(8, 64), blk, 0, stream>>>(s1, WH(OWco), bc_out, covb, 1024, 1024);

    build_blocks_kernel<<<dim3(TT), dim3(256), 0, stream>>>(covb, meanb, lamMu, cw);

    chol_scan5<<<dim3(TT/4), dim3(64), 0, stream>>>(covb, Lbuf, Cbuf, cw, logsum, 4, 6);
    fwd_solve_kernel<<<dim3(TT/4), dim3(64), 0, stream>>>(Lbuf, Cbuf, lamMu, ib, 4, 12);
    bwd_solve_kernel<<<dim3(TT/4), dim3(64), 0, stream>>>(Lbuf, Cbuf, ib, norm, out, 4, 12);

    finalize_kernel<<<dim3(1), dim3(64), 0, stream>>>(logsum, out);
}

// Round 9
// 408.544 us; speedup vs baseline: 13.0406x; 1.1138x over previous
//
#include <hip/hip_runtime.h>
#include <math.h>

#define TT 8192
#define DZ 32

typedef short bf16x8 __attribute__((ext_vector_type(8)));
typedef _Float16 f16x8 __attribute__((ext_vector_type(8)));
typedef _Float16 f16x4 __attribute__((ext_vector_type(4)));
typedef float f32x4 __attribute__((ext_vector_type(4)));
typedef float f32x16 __attribute__((ext_vector_type(16)));
#define MFMA16F(a,b,c) __builtin_amdgcn_mfma_f32_16x16x32_f16(a,b,c,0,0,0)
#define MFMA32(a,b,c) __builtin_amdgcn_mfma_f32_32x32x16_bf16(a,b,c,0,0,0)

// ---------------- workspace layout (float units) ----------------
#define OFF_QINV   0
#define OFF_Q0INV  1024
#define OFF_AQA    2048
#define OFF_B      3072
#define OFF_P0     4096
#define OFF_PMID   5120
#define OFF_PLAST  6144
#define OFF_LOGSUM 7168
#define OFF_ACT0   8192                     // 2 f16 act slots -> later L (f32, col-major per t)
#define OFF_ACT1   (OFF_ACT0 + 8388608)     // 2 f16 act slots -> later C (f32, X row-major per t)
#define OFF_AAB    (OFF_ACT1 + 8388608)     // cov f32 -> AA in place
#define OFF_XB     (OFF_AAB + 8388608)      // x f16
#define OFF_WB     (OFF_XB + 2097152)       // weights f16
#define OFF_MEANB  (OFF_WB + 5799936)
#define OFF_LAMMU  (OFF_MEANB + 262144)
#define OFF_IBV    (OFF_LAMMU + 262144)

__device__ __forceinline__ unsigned short f2bf(float f) {
    unsigned int u = __float_as_uint(f);
    u += 0x7FFFu + ((u >> 16) & 1u);
    return (unsigned short)(u >> 16);
}
__device__ __forceinline__ float bf2f(unsigned short h) {
    return __uint_as_float(((unsigned int)h) << 16);
}
__device__ __forceinline__ float rlane(float v, int l) {
    return __uint_as_float(__builtin_amdgcn_readlane(__float_as_uint(v), l));
}

// ---------------- fused f32 -> f16 conversion (all tensors, 1 launch) ----------------
struct SplitSeg { const float* src; _Float16* hi; int n; };
struct SplitArgs { SplitSeg seg[9]; };

__global__ __launch_bounds__(256)
void split_all(SplitArgs a)
{
    const SplitSeg sg = a.seg[blockIdx.y];
    const int n4 = sg.n >> 2;
    int i = blockIdx.x * 256 + threadIdx.x;
    if (i >= n4) return;
    float4 v = ((const float4*)sg.src)[i];
    f16x4 hh;
    hh[0] = (_Float16)v.x; hh[1] = (_Float16)v.y;
    hh[2] = (_Float16)v.z; hh[3] = (_Float16)v.w;
    ((f16x4*)sg.hi)[i] = hh;
}

// ---------------- setup: Qinv, Q0inv, AQA, B, priors ----------------
__global__ __launch_bounds__(1024)
void setup_kernel(const float* __restrict__ A, const float* __restrict__ QinvChol,
                  const float* __restrict__ Q0invChol, float* __restrict__ cw)
{
    __shared__ float As[DZ*33], Qc[DZ*33], Q0c[DZ*33], Qi[DZ*33], T1[DZ*33];
    const int tid = threadIdx.x;
    const int i = tid >> 5, j = tid & 31;
    As[i*33+j]  = A[tid];
    Qc[i*33+j]  = QinvChol[tid];
    Q0c[i*33+j] = Q0invChol[tid];
    __syncthreads();
    float qi = 0.f, q0 = 0.f;
    for (int k = 0; k < DZ; ++k) { qi += Qc[i*33+k]*Qc[j*33+k]; q0 += Q0c[i*33+k]*Q0c[j*33+k]; }
    Qi[i*33+j] = qi;
    __syncthreads();
    float t1 = 0.f;
    for (int k = 0; k < DZ; ++k) t1 += Qi[i*33+k]*As[k*33+j];
    T1[i*33+j] = t1;
    __syncthreads();
    float aqa = 0.f, bm = 0.f;
    for (int k = 0; k < DZ; ++k) { aqa += As[k*33+i]*T1[k*33+j]; bm += As[k*33+i]*Qi[k*33+j]; }
    cw[OFF_QINV  + tid] = qi;
    cw[OFF_Q0INV + tid] = q0;
    cw[OFF_AQA   + tid] = aqa;
    cw[OFF_B     + tid] = -bm;
    cw[OFF_P0    + tid] = q0 + aqa;
    cw[OFF_PMID  + tid] = qi + aqa;
    cw[OFF_PLAST + tid] = qi;
    if (tid == 0) cw[OFF_LOGSUM] = 0.f;
}

// ---------------- f16 MFMA GEMM ----------------
__device__ __forceinline__ void stage_tile(const _Float16* src, int rowbase, int Kd,
                                           int k0, _Float16* ldsbase, int w, int lane)
{
#pragma unroll
    for (int inst = 0; inst < 2; ++inst) {
        const int r0  = w * 32 + inst * 16;
        const int row = r0 + (lane >> 2);
        const int g   = (lane & 3) ^ ((row >> 1) & 3);
        const _Float16* gp = src + (size_t)(rowbase + row) * Kd + k0 + g * 8;
        __builtin_amdgcn_global_load_lds(
            (const __attribute__((address_space(1))) void*)gp,
            (__attribute__((address_space(3))) void*)(ldsbase + r0 * 32),
            16, 0, 0);
    }
}

// GEMM body: C = act(A @ W^T + b). OM: 0 f32 out, 1 f16 out.
template<int OM>
__device__ __forceinline__ void mgemm_body(const _Float16* Ah, const _Float16* Wh,
                                           const float* bias, float* outF,
                                           _Float16* outH, int N, int Kd, int relu,
                                           int bn, int bm, _Float16 (*lds)[2][4096])
{
    const int tid = threadIdx.x;
    const int lane = tid & 63, w = tid >> 6;
    const int wm = w >> 1, wn = w & 1;
    const int ln15 = lane & 15, g4 = lane >> 4;

    f32x4 acc[4][4];
#pragma unroll
    for (int i = 0; i < 4; ++i)
#pragma unroll
        for (int j = 0; j < 4; ++j) acc[i][j] = f32x4{0.f,0.f,0.f,0.f};

    const int nt = Kd >> 5;
    stage_tile(Ah, bm*128, Kd, 0, &lds[0][0][0], w, lane);
    stage_tile(Wh, bn*128, Kd, 0, &lds[0][1][0], w, lane);
    __syncthreads();

    int cur = 0;
    for (int t = 0; t < nt; ++t) {
        if (t + 1 < nt) {
            const int k0 = (t + 1) << 5;
            stage_tile(Ah, bm*128, Kd, k0, &lds[cur^1][0][0], w, lane);
            stage_tile(Wh, bn*128, Kd, k0, &lds[cur^1][1][0], w, lane);
        }
        f16x8 fa[4], fwh[4];
#pragma unroll
        for (int fm = 0; fm < 4; ++fm) {
            const int lr = wm*64 + fm*16 + ln15;
            const int off = lr*32 + ((g4 ^ ((lr >> 1) & 3)) << 3);
            fa[fm]  = *(const f16x8*)(&lds[cur][0][0] + off);
        }
#pragma unroll
        for (int fn = 0; fn < 4; ++fn) {
            const int lr = wn*64 + fn*16 + ln15;
            const int off = lr*32 + ((g4 ^ ((lr >> 1) & 3)) << 3);
            fwh[fn] = *(const f16x8*)(&lds[cur][1][0] + off);
        }
#pragma unroll
        for (int fm = 0; fm < 4; ++fm)
#pragma unroll
            for (int fn = 0; fn < 4; ++fn)
                acc[fm][fn] = MFMA16F(fa[fm], fwh[fn], acc[fm][fn]);
        __syncthreads();
        cur ^= 1;
    }

    // epilogue: C/D layout col=lane&15, row=(lane>>4)*4+q  [m89-verified]
#pragma unroll
    for (int fm = 0; fm < 4; ++fm)
#pragma unroll
        for (int fn = 0; fn < 4; ++fn) {
            const int col = bn*128 + wn*64 + fn*16 + ln15;
            const float bv = bias[col];
#pragma unroll
            for (int q = 0; q < 4; ++q) {
                const int row = bm*128 + wm*64 + fm*16 + g4*4 + q;
                float v = acc[fm][fn][q] + bv;
                if (relu) v = fmaxf(v, 0.f);
                if (OM == 0) outF[(size_t)row * N + col] = v;
                else         outH[(size_t)row * N + col] = (_Float16)v;
            }
        }
}

// single-chain GEMM (final cov layer, f32 out)
__global__ __launch_bounds__(256)
void mgemm_f32(const _Float16* __restrict__ Ah, const _Float16* __restrict__ Wh,
               const float* __restrict__ bias, float* __restrict__ outF,
               int N, int Kd)
{
    __shared__ _Float16 lds[2][2][4096];
    mgemm_body<0>(Ah, Wh, bias, outF, nullptr, N, Kd, 0, blockIdx.x, blockIdx.y, lds);
}

// merged mean/cov GEMM: blockIdx.z selects chain (both f16 out, relu)
__global__ __launch_bounds__(256)
void mgemm2(const _Float16* __restrict__ A0, const _Float16* __restrict__ A1,
            const _Float16* __restrict__ W0, const _Float16* __restrict__ W1,
            const float* __restrict__ b0, const float* __restrict__ b1,
            _Float16* __restrict__ o0, _Float16* __restrict__ o1,
            int N, int Kd)
{
    __shared__ _Float16 lds[2][2][4096];
    const int z = blockIdx.z;
    const _Float16* Ah = z ? A1 : A0;
    const _Float16* Wh = z ? W1 : W0;
    const float* bias  = z ? b1 : b0;
    _Float16* outH     = z ? o1 : o0;
    mgemm_body<1>(Ah, Wh, bias, nullptr, outH, N, Kd, 1, blockIdx.x, blockIdx.y, lds);
}

// ---------------- small GEMM (N=32): mean = h3 @ Wm_out^T + b ----------------
__global__ __launch_bounds__(64)
void mgemm_small(const _Float16* __restrict__ Ah, const _Float16* __restrict__ Wh,
                 const float* __restrict__ bias, float* __restrict__ out, int Kd)
{
    const int lane = threadIdx.x;
    const int rm = blockIdx.x * 16;
    const int ln15 = lane & 15, g = lane >> 4;
    const int row = rm + ln15;
    f32x4 acc0 = {0.f,0.f,0.f,0.f}, acc1 = {0.f,0.f,0.f,0.f};
    for (int k0 = 0; k0 < Kd; k0 += 32) {
        const int k = k0 + g*8;
        f16x8 a  = *(const f16x8*)(Ah + (size_t)row*Kd + k);
        f16x8 w0h = *(const f16x8*)(Wh + (size_t)ln15*Kd + k);
        f16x8 w1h = *(const f16x8*)(Wh + (size_t)(16+ln15)*Kd + k);
        acc0 = MFMA16F(a, w0h, acc0);
        acc1 = MFMA16F(a, w1h, acc1);
    }
#pragma unroll
    for (int q = 0; q < 4; ++q) {
        const int r = rm + g*4 + q;
        out[r*DZ + ln15]      = acc0[q] + bias[ln15];
        out[r*DZ + 16 + ln15] = acc1[q] + bias[16 + ln15];
    }
}

// ---------------- build Lam, AA (in place over cov), lamMu ----------------
__global__ __launch_bounds__(256)
void build_blocks_kernel(float* __restrict__ cov, const float* __restrict__ mean,
                         float* __restrict__ lamMu, const float* __restrict__ cw)
{
    const int t = blockIdx.x, tid = threadIdx.x;
    __shared__ float R[DZ*33];
    __shared__ float Lam[DZ*33];
    __shared__ float mn[DZ];
    float* blk = cov + (size_t)t * 1024;
    {
        float4 v = ((const float4*)blk)[tid];
        const int base = tid * 4;
        const int row = base >> 5, col = base & 31;
        R[row*33 + col + 0] = v.x; R[row*33 + col + 1] = v.y;
        R[row*33 + col + 2] = v.z; R[row*33 + col + 3] = v.w;
    }
    if (tid < DZ) mn[tid] = mean[t*DZ + tid];
    __syncthreads();
    const float* P = cw + (t == 0 ? OFF_P0 : (t == TT-1 ? OFF_PLAST : OFF_PMID));
#pragma unroll
    for (int q = 0; q < 4; ++q) {
        const int idx = tid + 256*q;
        const int i = idx >> 5, j = idx & 31;
        float s = 0.f;
#pragma unroll
        for (int k = 0; k < DZ; ++k) s += R[i*33+k] * R[j*33+k];
        Lam[i*33+j] = s;
        blk[idx] = s + P[idx];
    }
    __syncthreads();
    if (tid < DZ) {
        float s = 0.f;
#pragma unroll
        for (int k = 0; k < DZ; ++k) s += Lam[tid*33+k] * mn[k];
        lamMu[t*DZ + tid] = s;
    }
}

// ---------------- chol scan v6: v5 + single-logf pivot tracking ----------
__device__ __forceinline__ unsigned short f2bf_c(float f) { return f2bf(f); }

#define CHOL_STEP(OWNED)                                                          \
    {                                                                             \
        _Pragma("unroll")                                                         \
        for (int i = 0; i < 32; ++i) s[i] = Apre[i];                              \
        if (t + 1 < own1) {                                                       \
            const float* an = AA + (size_t)(t+1)*1024;                            \
            _Pragma("unroll")                                                     \
            for (int i = 0; i < 32; ++i) Apre[i] = an[i*32 + c];                  \
        }                                                                         \
        const bool doX = (t > t0);                                                \
        if (doX) {                                                                \
            _Pragma("unroll")                                                     \
            for (int i = 0; i < 32; ++i) u[i] = Breg[i];                          \
            _Pragma("unroll")                                                     \
            for (int r = 0; r < 32; ++r) {                                        \
                float x = u[r] * rlane(invd_own, r);                              \
                u[r] = x;                                                         \
                _Pragma("unroll")                                                 \
                for (int i = r+1; i < 32; ++i)                                    \
                    u[i] = fmaf(-rlane(Lcol[i], r), x, u[i]);                     \
            }                                                                     \
            float f0[8], f1[8];                                                   \
            _Pragma("unroll")                                                     \
            for (int j = 0; j < 8; ++j) {                                         \
                f0[j] = h ? u[8+j]  : u[j];                                       \
                f1[j] = h ? u[24+j] : u[16+j];                                    \
            }                                                                     \
            bf16x8 A0h, A0l, A1h, A1l;                                            \
            _Pragma("unroll")                                                     \
            for (int j = 0; j < 8; ++j) {                                         \
                unsigned short hh0 = f2bf_c(f0[j]);                               \
                A0h[j] = (short)hh0; A0l[j] = (short)f2bf_c(f0[j] - bf2f(hh0));   \
                unsigned short hh1 = f2bf_c(f1[j]);                               \
                A1h[j] = (short)hh1; A1l[j] = (short)f2bf_c(f1[j] - bf2f(hh1));   \
            }                                                                     \
            f32x16 d;                                                             \
            _Pragma("unroll")                                                     \
            for (int q = 0; q < 16; ++q) d[q] = 0.f;                              \
            d = MFMA32(A0h, A0h, d);                                              \
            d = MFMA32(A0h, A0l, d);                                              \
            d = MFMA32(A0l, A0h, d);                                              \
            d = MFMA32(A1h, A1h, d);                                              \
            d = MFMA32(A1h, A1l, d);                                              \
            d = MFMA32(A1l, A1h, d);                                              \
            float dsw[16];                                                        \
            _Pragma("unroll")                                                     \
            for (int q = 0; q < 16; ++q) dsw[q] = __shfl_xor(d[q], 32);           \
            _Pragma("unroll")                                                     \
            for (int i = 0; i < 32; ++i) {                                        \
                const int q  = (i & 3) + ((i >> 3) << 2);                         \
                const int hh = (i >> 2) & 1;                                      \
                s[i] -= (h == hh) ? d[q] : dsw[q];                                \
            }                                                                     \
        }                                                                         \
        float pivk = 1.f;                                                         \
        _Pragma("unroll")                                                         \
        for (int j = 0; j < 32; ++j) {                                            \
            float sjj = rlane(s[j], j);                                           \
            float inv = __builtin_amdgcn_rsqf(sjj);                               \
            pivk = (c == j) ? sjj : pivk;                                         \
            float inv2 = inv * inv;                                               \
            float ljc = (c > j) ? s[j] * inv2 : 0.f;                              \
            invd_own = (c == j) ? inv : invd_own;                                 \
            _Pragma("unroll")                                                     \
            for (int i = j; i < 32; ++i) s[i] = fmaf(-rlane(s[i], j), ljc, s[i]); \
        }                                                                         \
        if (OWNED) logacc += __logf(pivk);                                        \
        _Pragma("unroll")                                                         \
        for (int i = 0; i < 32; ++i) Lcol[i] = s[i] * invd_own;                   \
        if (OWNED) {                                                              \
            float* lt = Lg + (size_t)t*1024 + c*32 + h*16;                        \
            _Pragma("unroll")                                                     \
            for (int q = 0; q < 4; ++q) {                                         \
                float4 v4 = make_float4(h ? Lcol[16+4*q]   : Lcol[4*q],           \
                                        h ? Lcol[16+4*q+1] : Lcol[4*q+1],         \
                                        h ? Lcol[16+4*q+2] : Lcol[4*q+2],         \
                                        h ? Lcol[16+4*q+3] : Lcol[4*q+3]);        \
                *(float4*)(lt + 4*q) = v4;                                        \
            }                                                                     \
            if (doX) {                                                            \
                float* ct = Cg + (size_t)t*1024;                                  \
                _Pragma("unroll")                                                 \
                for (int rr = 0; rr < 16; ++rr) {                                 \
                    float val = h ? u[16+rr] : u[rr];                             \
                    ct[(h*16+rr)*32 + c] = val;                                   \
                }                                                                 \
            }                                                                     \
        }                                                                         \
    }

__global__ __launch_bounds__(64)
void chol_scan6(const float* __restrict__ AA, float* __restrict__ Lg,
                float* __restrict__ Cg, const float* __restrict__ cw,
                float* __restrict__ logsum, int K, int W)
{
    const int lane = threadIdx.x;
    const int c = lane & 31;
    const int h = lane >> 5;
    const int own0 = blockIdx.x * K;
    const int own1 = min(TT, own0 + K);
    const int t0 = max(0, own0 - W);

    float Breg[32], Lcol[32], s[32], u[32], Apre[32];
    float invd_own = 0.f, logacc = 0.f;

#pragma unroll
    for (int i = 0; i < 32; ++i) Breg[i] = cw[OFF_B + i*32 + c];
#pragma unroll
    for (int i = 0; i < 32; ++i) Apre[i] = AA[(size_t)t0*1024 + i*32 + c];

    for (int t = t0; t < own0; ++t) CHOL_STEP(false)
    for (int t = own0; t < own1; ++t) CHOL_STEP(true)

    // lane c holds sum over owned steps of log(pivot_c); reduce across the 32 columns
    // (lanes 32-63 duplicate lanes 0-31 -> butterfly within 32 only)
#pragma unroll
    for (int sft = 16; sft > 0; sft >>= 1) logacc += __shfl_xor(logacc, sft);
    if (lane == 0) atomicAdd(logsum, logacc * 0.5f);
}

// ---------------- chunked forward bidiagonal solve (L col-major, C = X row-major) -------
__global__ __launch_bounds__(64)
void fwd_solve_kernel(const float* __restrict__ Lg, const float* __restrict__ Cg,
                      const float* __restrict__ bv, float* __restrict__ xout,
                      int K, int W)
{
    const int lane = threadIdx.x;
    const int r = lane & 31, h = lane >> 5;
    const int own0 = blockIdx.x * K;
    const int own1 = min(TT, own0 + K);
    const int t0 = max(0, own0 - W);
    float xprev = 0.f;
    for (int t = t0; t < own1; ++t) {
        const float* lt = Lg + (size_t)t * 1024;
        float Lr[32];
#pragma unroll
        for (int j = 0; j < DZ; ++j) Lr[j] = lt[j*32 + r];
        const float inv = __builtin_amdgcn_rcpf(Lr[r]);
        float v = bv[t*DZ + r];
        if (t > t0) {
            const float* ct = Cg + (size_t)t * 1024;
            float Cr[32];
#pragma unroll
            for (int cc = 0; cc < DZ; ++cc) Cr[cc] = ct[cc*32 + r];
#pragma unroll
            for (int cc = 0; cc < DZ; ++cc) v = fmaf(-Cr[cc], __shfl(xprev, cc), v);
        }
        float xv = 0.f;
#pragma unroll
        for (int rr = 0; rr < DZ; ++rr) {
            float cand = v * inv;
            float xb = __shfl(cand, rr);
            if (r == rr) xv = cand;
            if (r > rr) v = fmaf(-Lr[rr], xb, v);
        }
        xprev = xv;
        if (t >= own0 && h == 0) xout[t*DZ + r] = xv;
    }
}

// ---------------- chunked backward solve (two RHS) + sample -----------------------------
__global__ __launch_bounds__(64)
void bwd_solve_kernel(const float* __restrict__ Lg, const float* __restrict__ Cg,
                      const float* __restrict__ b1, const float* __restrict__ b2,
                      float* __restrict__ outSample, int K, int W)
{
    const int lane = threadIdx.x;
    const int k = lane & 31, h = lane >> 5;
    const int own0 = blockIdx.x * K;
    const int own1 = min(TT, own0 + K);
    const int tS = min(TT - 1, own1 - 1 + W);
    float x1p = 0.f, x2p = 0.f;
    for (int t = tS; t >= own0; --t) {
        const float* lt = Lg + (size_t)t * 1024;
        float Lc[32];
#pragma unroll
        for (int q = 0; q < 8; ++q) {
            float4 v4 = *(const float4*)(lt + k*32 + 4*q);
            Lc[4*q] = v4.x; Lc[4*q+1] = v4.y; Lc[4*q+2] = v4.z; Lc[4*q+3] = v4.w;
        }
        const float inv = __builtin_amdgcn_rcpf(Lc[k]);
        float v1 = b1[t*DZ + k], v2 = b2[t*DZ + k];
        if (t < tS) {
            const float* ct = Cg + (size_t)(t+1) * 1024;
            float Cc[32];
#pragma unroll
            for (int q = 0; q < 8; ++q) {
                float4 w4 = *(const float4*)(ct + k*32 + 4*q);
                Cc[4*q] = w4.x; Cc[4*q+1] = w4.y; Cc[4*q+2] = w4.z; Cc[4*q+3] = w4.w;
            }
#pragma unroll
            for (int cc = 0; cc < DZ; ++cc) {
                float a1 = __shfl(x1p, cc), a2 = __shfl(x2p, cc);
                v1 = fmaf(-Cc[cc], a1, v1); v2 = fmaf(-Cc[cc], a2, v2);
            }
        }
        float x1 = 0.f, x2 = 0.f;
#pragma unroll
        for (int rr = DZ-1; rr >= 0; --rr) {
            float c1 = v1 * inv, c2 = v2 * inv;
            float xb1 = __shfl(c1, rr), xb2 = __shfl(c2, rr);
            if (k == rr) { x1 = c1; x2 = c2; }
            if (k < rr) { v1 = fmaf(-Lc[rr], xb1, v1); v2 = fmaf(-Lc[rr], xb2, v2); }
        }
        x1p = x1; x2p = x2;
        if (t >= own0 && h == 0) outSample[t*DZ + k] = x1 + x2;
    }
}

// ---------------- entropy ----------------
__global__ void finalize_kernel(const float* __restrict__ logsum, float* __restrict__ out)
{
    if (threadIdx.x == 0) {
        out[TT*DZ] = (logsum[0] - 2270.3016531274763f) / 409600.0f;
    }
}

// ---------------- launch ----------------
extern "C" void kernel_launch(void* const* d_in, const int* in_sizes, int n_in,
                              void* d_out, int out_size, void* d_ws, size_t ws_size,
                              hipStream_t stream)
{
    (void)in_sizes; (void)n_in; (void)out_size; (void)ws_size;
    const float* x        = (const float*)d_in[0];
    const float* norm     = (const float*)d_in[1];
    const float* A        = (const float*)d_in[2];
    const float* QinvChol = (const float*)d_in[3];
    const float* Q0invChol= (const float*)d_in[4];
    const float* Wm_in = (const float*)d_in[5];  const float* bm_in = (const float*)d_in[6];
    const float* Wm_h1 = (const float*)d_in[7];  const float* bm_h1 = (const float*)d_in[8];
    const float* Wm_h3 = (const float*)d_in[9];  const float* bm_h3 = (const float*)d_in[10];
    const float* Wm_out= (const float*)d_in[11]; const float* bm_out= (const float*)d_in[12];
    const float* Wc_in = (const float*)d_in[13]; const float* bc_in = (const float*)d_in[14];
    const float* Wc_h1 = (const float*)d_in[15]; const float* bc_h1 = (const float*)d_in[16];
    const float* Wc_h3 = (const float*)d_in[17]; const float* bc_h3 = (const float*)d_in[18];
    const float* Wc_out= (const float*)d_in[19]; const float* bc_out= (const float*)d_in[20];

    float* ws    = (float*)d_ws;
    float* out   = (float*)d_out;
    float* cw    = ws;
    float* Lbuf  = ws + OFF_ACT0;
    float* Cbuf  = ws + OFF_ACT1;
    float* covb  = ws + OFF_AAB;
    float* meanb = ws + OFF_MEANB;
    float* lamMu = ws + OFF_LAMMU;
    float* ib    = ws + OFF_IBV;
    float* logsum = ws + OFF_LOGSUM;

    // 4 f16 activation slots, carved from ACT0/ACT1 regions
    _Float16* s0 = (_Float16*)(ws + OFF_ACT0);
    _Float16* s1 = s0 + 8388608;
    _Float16* s2 = (_Float16*)(ws + OFF_ACT1);
    _Float16* s3 = s2 + 8388608;
    _Float16* xh = (_Float16*)(ws + OFF_XB);

    const long OWmi = OFF_WB;
    const long OWm1 = OWmi + 262144;
    const long OWm3 = OWm1 + 1048576;
    const long OWmo = OWm3 + 1048576;
    const long OWci = OWmo + 32768;
    const long OWc1 = OWci + 262144;
    const long OWc3 = OWc1 + 1048576;
    const long OWco = OWc3 + 1048576;
    #define WH(o) ((_Float16*)(ws + (o)))

    setup_kernel<<<dim3(1), dim3(1024), 0, stream>>>(A, QinvChol, Q0invChol, cw);

    SplitArgs sa;
    sa.seg[0] = { x,      xh,       2097152 };
    sa.seg[1] = { Wm_in,  WH(OWmi), 262144 };
    sa.seg[2] = { Wm_h1,  WH(OWm1), 1048576 };
    sa.seg[3] = { Wm_h3,  WH(OWm3), 1048576 };
    sa.seg[4] = { Wm_out, WH(OWmo), 32768 };
    sa.seg[5] = { Wc_in,  WH(OWci), 262144 };
    sa.seg[6] = { Wc_h1,  WH(OWc1), 1048576 };
    sa.seg[7] = { Wc_h3,  WH(OWc3), 1048576 };
    sa.seg[8] = { Wc_out, WH(OWco), 1048576 };
    split_all<<<dim3(2048, 9), dim3(256), 0, stream>>>(sa);

    const dim3 gM(8, 64, 2), blk(256);
    // L1: x -> s0 (mean h1) / s1 (cov h1)
    mgemm2<<<gM, blk, 0, stream>>>(xh, xh, WH(OWmi), WH(OWci), bm_in, bc_in, s0, s1, 1024, 256);
    // L2: s0 -> s2 / s1 -> s3
    mgemm2<<<gM, blk, 0, stream>>>(s0, s1, WH(OWm1), WH(OWc1), bm_h1, bc_h1, s2, s3, 1024, 1024);
    // L3: s2 -> s0 / s3 -> s1
    mgemm2<<<gM, blk, 0, stream>>>(s2, s3, WH(OWm3), WH(OWc3), bm_h3, bc_h3, s0, s1, 1024, 1024);
    // heads
    mgemm_small<<<dim3(512), dim3(64), 0, stream>>>(s0, WH(OWmo), bm_out, meanb, 1024);
    mgemm_f32<<<dim3(8, 64), blk, 0, stream>>>(s1, WH(OWco), bc_out, covb, 1024, 1024);

    build_blocks_kernel<<<dim3(TT), dim3(256), 0, stream>>>(covb, meanb, lamMu, cw);

    chol_scan6<<<dim3(TT/4), dim3(64), 0, stream>>>(covb, Lbuf, Cbuf, cw, logsum, 4, 4);
    fwd_solve_kernel<<<dim3(TT/4), dim3(64), 0, stream>>>(Lbuf, Cbuf, lamMu, ib, 4, 8);
    bwd_solve_kernel<<<dim3(TT/4), dim3(64), 0, stream>>>(Lbuf, Cbuf, ib, norm, out, 4, 8);

    finalize_kernel<<<dim3(1), dim3(64), 0, stream>>>(logsum, out);
}